// Round 2
// baseline (9141.840 us; speedup 1.0000x reference)
//
#include <hip/hip_runtime.h>
#include <math.h>

#define NODES 50000
#define NEDGES 800000
#define ETOT (NEDGES + NODES)
#define FIN 16
#define PRE 32
#define C 128
#define GH 32
#define LAYERS 5
#define NPB 16

__device__ __forceinline__ float sigmoidf_(float x) { return 1.0f / (1.0f + __expf(-x)); }

// deg[col] += 1 for real edges (self loops handled as +1 in k_dis)
__global__ void k_degree(const int* __restrict__ col, float* __restrict__ deg) {
    int e = blockIdx.x * blockDim.x + threadIdx.x;
    if (e < NEDGES) atomicAdd(&deg[col[e]], 1.0f);
}

__global__ void k_dis(float* __restrict__ deg_dis) {
    int i = blockIdx.x * blockDim.x + threadIdx.x;
    if (i < NODES) deg_dis[i] = rsqrtf(deg_dis[i] + 1.0f);
}

// h = relu(x@W_pre+b_pre); h0 = relu(h@W_init+b_init); thread per node
__global__ __launch_bounds__(256) void k_preproc(
    const float* __restrict__ x, const float* __restrict__ Wpre, const float* __restrict__ bpre,
    const float* __restrict__ Winit, const float* __restrict__ binit,
    float* __restrict__ h0, float* __restrict__ h) {
    __shared__ float sWpre[FIN * PRE], sbpre[PRE], sWinit[PRE * C], sbinit[C];
    for (int i = threadIdx.x; i < FIN * PRE; i += blockDim.x) sWpre[i] = Wpre[i];
    for (int i = threadIdx.x; i < PRE; i += blockDim.x) sbpre[i] = bpre[i];
    for (int i = threadIdx.x; i < PRE * C; i += blockDim.x) sWinit[i] = Winit[i];
    for (int i = threadIdx.x; i < C; i += blockDim.x) sbinit[i] = binit[i];
    __syncthreads();
    int n = blockIdx.x * blockDim.x + threadIdx.x;
    if (n >= NODES) return;
    float xv[FIN];
#pragma unroll
    for (int i = 0; i < FIN; i++) xv[i] = x[n * FIN + i];
    float pre[PRE];
#pragma unroll
    for (int k = 0; k < PRE; k++) {
        float a = sbpre[k];
#pragma unroll
        for (int i = 0; i < FIN; i++) a = fmaf(xv[i], sWpre[i * PRE + k], a);
        pre[k] = fmaxf(a, 0.0f);
    }
    for (int k = 0; k < C; k++) {
        float a = sbinit[k];
#pragma unroll
        for (int j = 0; j < PRE; j++) a = fmaf(pre[j], sWinit[j * C + k], a);
        a = fmaxf(a, 0.0f);
        h0[n * C + k] = a;
        h[n * C + k] = a;
    }
}

// A = h @ Wg1[0:128,:], B = h @ Wg1[128:256,:]  (no bias). One wave per node.
__global__ __launch_bounds__(256) void k_gateAB(
    const float* __restrict__ h, const float* __restrict__ Wg1,
    float* __restrict__ A, float* __restrict__ B) {
    int wave = (blockIdx.x * blockDim.x + threadIdx.x) >> 6;
    int lane = threadIdx.x & 63;
    if (wave >= NODES) return;
    int k = lane & 31;
    const float* W = Wg1 + ((lane < 32) ? 0 : C * GH);
    const float* hrow = h + wave * C;
    float acc = 0.0f;
#pragma unroll 8
    for (int c = 0; c < C; c++) acc = fmaf(hrow[c], W[c * GH + k], acc);
    if (lane < 32) A[wave * GH + k] = acc;
    else           B[wave * GH + k] = acc;
}

// per edge (32 threads): gate = sigmoid(relu(A[col]+B[row]+ea*w+b1)@Wg2+b2)
// then aggr[col] += gate*dis[row]*dis[col]*h[row]
__global__ __launch_bounds__(256) void k_edge(
    const int* __restrict__ eidx, const float* __restrict__ eattr,
    const float* __restrict__ dis, const float* __restrict__ A, const float* __restrict__ Bm,
    const float* __restrict__ Wg1, const float* __restrict__ bg1,
    const float* __restrict__ Wg2, const float* __restrict__ bg2,
    const float* __restrict__ h, float* __restrict__ aggr) {
    const int* rowi = eidx;           // source (x_j)
    const int* coli = eidx + NEDGES;  // target (x_i), aggregation index
    long long gid = (long long)blockIdx.x * blockDim.x + threadIdx.x;
    int e = (int)(gid >> 5);
    int k = threadIdx.x & 31;
    if (e >= ETOT) return;
    int r, ci; float ea;
    if (e < NEDGES) { r = rowi[e]; ci = coli[e]; ea = eattr[e]; }
    else            { r = ci = e - NEDGES; ea = 0.0f; }
    float t = A[ci * GH + k] + Bm[r * GH + k] + ea * Wg1[2 * C * GH + k] + bg1[k];
    t = fmaxf(t, 0.0f);
    float p = t * Wg2[k];
#pragma unroll
    for (int m = 16; m > 0; m >>= 1) p += __shfl_xor(p, m, 32);
    float gate = sigmoidf_(p + bg2[0]);
    float coef = gate * dis[r] * dis[ci];
    const float4* hrow = (const float4*)(h + (size_t)r * C);
    float4 v = hrow[k];
    float* dst = aggr + (size_t)ci * C + k * 4;
    atomicAdd(dst + 0, coef * v.x);
    atomicAdd(dst + 1, coef * v.y);
    atomicAdd(dst + 2, coef * v.z);
    atomicAdd(dst + 3, coef * v.w);
}

// GRU update, 16 nodes per 256-thread block
__global__ __launch_bounds__(256) void k_update(
    float* __restrict__ h, const float* __restrict__ aggr,
    const float* __restrict__ Wz, const float* __restrict__ bz,
    const float* __restrict__ Wr, const float* __restrict__ br,
    const float* __restrict__ Wh, const float* __restrict__ bh) {
    __shared__ float hs[NPB][C + 1], as[NPB][C + 1], rs[NPB][C + 1];
    int n0 = blockIdx.x * NPB;
    for (int idx = threadIdx.x; idx < NPB * C; idx += 256) {
        int n = idx >> 7, c = idx & 127;
        int gn = n0 + n;
        float hv = 0.0f, av = 0.0f;
        if (gn < NODES) { hv = h[(size_t)gn * C + c]; av = aggr[(size_t)gn * C + c]; }
        hs[n][c] = hv; as[n][c] = av;
    }
    __syncthreads();
    int k = threadIdx.x & 127;
    int half = threadIdx.x >> 7;
    float az[8], ar[8];
#pragma unroll
    for (int i = 0; i < 8; i++) { az[i] = bz[k]; ar[i] = br[k]; }
    for (int c = 0; c < C; c++) {
        float wz = Wz[c * C + k], wr = Wr[c * C + k];
#pragma unroll
        for (int i = 0; i < 8; i++) {
            float hv = hs[half * 8 + i][c];
            az[i] = fmaf(hv, wz, az[i]);
            ar[i] = fmaf(hv, wr, ar[i]);
        }
    }
    for (int c = 0; c < C; c++) {
        float wz = Wz[(C + c) * C + k], wr = Wr[(C + c) * C + k];
#pragma unroll
        for (int i = 0; i < 8; i++) {
            float av = as[half * 8 + i][c];
            az[i] = fmaf(av, wz, az[i]);
            ar[i] = fmaf(av, wr, ar[i]);
        }
    }
#pragma unroll
    for (int i = 0; i < 8; i++) {
        az[i] = sigmoidf_(az[i]);
        ar[i] = sigmoidf_(ar[i]);
        rs[half * 8 + i][k] = ar[i];
    }
    __syncthreads();
    float ah[8];
#pragma unroll
    for (int i = 0; i < 8; i++) ah[i] = bh[k];
    for (int c = 0; c < C; c++) {
        float w1 = Wh[c * C + k], w2 = Wh[(C + c) * C + k];
#pragma unroll
        for (int i = 0; i < 8; i++) {
            int n = half * 8 + i;
            ah[i] = fmaf(rs[n][c] * hs[n][c], w1, ah[i]);
            ah[i] = fmaf(as[n][c], w2, ah[i]);
        }
    }
#pragma unroll
    for (int i = 0; i < 8; i++) {
        int n = half * 8 + i; int gn = n0 + n;
        if (gn < NODES) {
            float hc = fmaxf(ah[i], 0.0f);
            float z = az[i];
            h[(size_t)gn * C + k] = (1.0f - z) * hs[n][k] + z * hc;
        }
    }
}

// out = relu([h0,h]@Wf1+bf1)@Wf2+bf2
__global__ __launch_bounds__(256) void k_final(
    const float* __restrict__ h0, const float* __restrict__ h,
    const float* __restrict__ Wf1, const float* __restrict__ bf1,
    const float* __restrict__ Wf2, const float* __restrict__ bf2,
    float* __restrict__ out) {
    __shared__ float h0s[NPB][C + 1], hs[NPB][C + 1], fs[NPB][C + 1];
    int n0 = blockIdx.x * NPB;
    for (int idx = threadIdx.x; idx < NPB * C; idx += 256) {
        int n = idx >> 7, c = idx & 127;
        int gn = n0 + n;
        float a = 0.0f, b = 0.0f;
        if (gn < NODES) { a = h0[(size_t)gn * C + c]; b = h[(size_t)gn * C + c]; }
        h0s[n][c] = a; hs[n][c] = b;
    }
    __syncthreads();
    int k = threadIdx.x & 127;
    int half = threadIdx.x >> 7;
    float acc[8];
#pragma unroll
    for (int i = 0; i < 8; i++) acc[i] = bf1[k];
    for (int c = 0; c < C; c++) {
        float w1 = Wf1[c * C + k], w2 = Wf1[(C + c) * C + k];
#pragma unroll
        for (int i = 0; i < 8; i++) {
            int n = half * 8 + i;
            acc[i] = fmaf(h0s[n][c], w1, acc[i]);
            acc[i] = fmaf(hs[n][c], w2, acc[i]);
        }
    }
#pragma unroll
    for (int i = 0; i < 8; i++) fs[half * 8 + i][k] = fmaxf(acc[i], 0.0f);
    __syncthreads();
    if (threadIdx.x < NPB * 2) {
        int n = threadIdx.x >> 1, o = threadIdx.x & 1;
        int gn = n0 + n;
        if (gn < NODES) {
            float a = bf2[o];
#pragma unroll 16
            for (int c = 0; c < C; c++) a = fmaf(fs[n][c], Wf2[c * 2 + o], a);
            out[(size_t)gn * 2 + o] = a;
        }
    }
}

extern "C" void kernel_launch(void* const* d_in, const int* in_sizes, int n_in,
                              void* d_out, int out_size, void* d_ws, size_t ws_size,
                              hipStream_t stream) {
    const float* x    = (const float*)d_in[0];
    const int*   eidx = (const int*)d_in[1];
    const float* eattr= (const float*)d_in[2];
    const float* Wpre = (const float*)d_in[3];  const float* bpre = (const float*)d_in[4];
    const float* Winit= (const float*)d_in[5];  const float* binit= (const float*)d_in[6];
    const float* Wg1  = (const float*)d_in[7];  const float* bg1  = (const float*)d_in[8];
    const float* Wg2  = (const float*)d_in[9];  const float* bg2  = (const float*)d_in[10];
    const float* Wz   = (const float*)d_in[11]; const float* bz   = (const float*)d_in[12];
    const float* Wr   = (const float*)d_in[13]; const float* br   = (const float*)d_in[14];
    const float* Wh   = (const float*)d_in[15]; const float* bh   = (const float*)d_in[16];
    const float* Wf1  = (const float*)d_in[17]; const float* bf1  = (const float*)d_in[18];
    const float* Wf2  = (const float*)d_in[19]; const float* bf2  = (const float*)d_in[20];
    float* out = (float*)d_out;

    // workspace layout (floats)
    const size_t REQ = (size_t)NODES * (1 + 128 + 128 + 32 + 32 + 128) * sizeof(float);
    if (ws_size < REQ) return;  // fail visibly rather than corrupt memory
    float* ws  = (float*)d_ws;
    float* dis = ws;                     // N
    float* h   = dis + NODES;            // N*C
    float* h0  = h + (size_t)NODES * C;  // N*C
    float* A   = h0 + (size_t)NODES * C; // N*GH
    float* B   = A + (size_t)NODES * GH; // N*GH
    float* aggr= B + (size_t)NODES * GH; // N*C

    hipMemsetAsync(dis, 0, NODES * sizeof(float), stream);
    k_degree<<<(NEDGES + 255) / 256, 256, 0, stream>>>(eidx + NEDGES, dis);
    k_dis<<<(NODES + 255) / 256, 256, 0, stream>>>(dis);
    k_preproc<<<(NODES + 255) / 256, 256, 0, stream>>>(x, Wpre, bpre, Winit, binit, h0, h);

    for (int l = 0; l < LAYERS; l++) {
        k_gateAB<<<(NODES * 64 + 255) / 256, 256, 0, stream>>>(h, Wg1, A, B);
        hipMemsetAsync(aggr, 0, (size_t)NODES * C * sizeof(float), stream);
        k_edge<<<((long long)ETOT * 32 + 255) / 256, 256, 0, stream>>>(
            eidx, eattr, dis, A, B, Wg1, bg1, Wg2, bg2, h, aggr);
        k_update<<<(NODES + NPB - 1) / NPB, 256, 0, stream>>>(h, aggr, Wz, bz, Wr, br, Wh, bh);
    }
    k_final<<<(NODES + NPB - 1) / NPB, 256, 0, stream>>>(h0, h, Wf1, bf1, Wf2, bf2, out);
}

// Round 3
// 2884.963 us; speedup vs baseline: 3.1688x; 3.1688x over previous
//
#include <hip/hip_runtime.h>
#include <math.h>

#define NODES 50000
#define NEDGES 800000
#define ETOT (NEDGES + NODES)
#define FIN 16
#define PRE 32
#define C 128
#define GH 32
#define LAYERS 5
#define NPB 16

__device__ __forceinline__ float sigmoidf_(float x) { return 1.0f / (1.0f + __expf(-x)); }

// deg[col] += 1 for real edges (self loop handled as +1 downstream)
__global__ void k_degree(const int* __restrict__ col, float* __restrict__ deg) {
    int e = blockIdx.x * blockDim.x + threadIdx.x;
    if (e < NEDGES) atomicAdd(&deg[col[e]], 1.0f);
}

__global__ void k_dis(float* __restrict__ deg_dis) {
    int i = blockIdx.x * blockDim.x + threadIdx.x;
    if (i < NODES) deg_dis[i] = rsqrtf(deg_dis[i] + 1.0f);
}

// single-block exclusive prefix scan of (deg+1) -> start[], cursor[]
__global__ __launch_bounds__(1024) void k_scan(
    const float* __restrict__ deg, int* __restrict__ start, int* __restrict__ cursor) {
    __shared__ int chunk[1024];
    __shared__ int carry;
    if (threadIdx.x == 0) carry = 0;
    __syncthreads();
    for (int base = 0; base < NODES; base += 1024) {
        int i = base + threadIdx.x;
        int v = (i < NODES) ? (int)deg[i] + 1 : 0;
        chunk[threadIdx.x] = v;
        __syncthreads();
        for (int off = 1; off < 1024; off <<= 1) {
            int t = (threadIdx.x >= off) ? chunk[threadIdx.x - off] : 0;
            __syncthreads();
            chunk[threadIdx.x] += t;
            __syncthreads();
        }
        int incl = chunk[threadIdx.x];
        int block_total = chunk[1023];
        int s = carry + incl - v;
        if (i < NODES) { start[i] = s; cursor[i] = s; }
        __syncthreads();
        if (threadIdx.x == 0) carry += block_total;
        __syncthreads();
    }
    if (threadIdx.x == 0) start[NODES] = carry;  // == ETOT
}

// scatter all ETOT edges (real + self) into CSR slots grouped by target
__global__ __launch_bounds__(256) void k_csr(
    const int* __restrict__ eidx, const float* __restrict__ eattr,
    int* __restrict__ cursor,
    int* __restrict__ row_sorted, int* __restrict__ col_sorted, float* __restrict__ ea_sorted) {
    int e = blockIdx.x * blockDim.x + threadIdx.x;
    if (e >= ETOT) return;
    int r, ci; float ea;
    if (e < NEDGES) { r = eidx[e]; ci = eidx[NEDGES + e]; ea = eattr[e]; }
    else            { r = ci = e - NEDGES; ea = 0.0f; }
    int slot = atomicAdd(&cursor[ci], 1);
    row_sorted[slot] = r;
    col_sorted[slot] = ci;
    ea_sorted[slot] = ea;
}

// h = relu(x@W_pre+b_pre); h0 = relu(h@W_init+b_init); thread per node
__global__ __launch_bounds__(256) void k_preproc(
    const float* __restrict__ x, const float* __restrict__ Wpre, const float* __restrict__ bpre,
    const float* __restrict__ Winit, const float* __restrict__ binit,
    float* __restrict__ h0, float* __restrict__ h) {
    __shared__ float sWpre[FIN * PRE], sbpre[PRE], sWinit[PRE * C], sbinit[C];
    for (int i = threadIdx.x; i < FIN * PRE; i += blockDim.x) sWpre[i] = Wpre[i];
    for (int i = threadIdx.x; i < PRE; i += blockDim.x) sbpre[i] = bpre[i];
    for (int i = threadIdx.x; i < PRE * C; i += blockDim.x) sWinit[i] = Winit[i];
    for (int i = threadIdx.x; i < C; i += blockDim.x) sbinit[i] = binit[i];
    __syncthreads();
    int n = blockIdx.x * blockDim.x + threadIdx.x;
    if (n >= NODES) return;
    float xv[FIN];
#pragma unroll
    for (int i = 0; i < FIN; i++) xv[i] = x[n * FIN + i];
    float pre[PRE];
#pragma unroll
    for (int k = 0; k < PRE; k++) {
        float a = sbpre[k];
#pragma unroll
        for (int i = 0; i < FIN; i++) a = fmaf(xv[i], sWpre[i * PRE + k], a);
        pre[k] = fmaxf(a, 0.0f);
    }
    for (int k = 0; k < C; k++) {
        float a = sbinit[k];
#pragma unroll
        for (int j = 0; j < PRE; j++) a = fmaf(pre[j], sWinit[j * C + k], a);
        a = fmaxf(a, 0.0f);
        h0[n * C + k] = a;
        h[n * C + k] = a;
    }
}

// A = h @ Wg1[0:128,:] + bg1 (bias folded), B = h @ Wg1[128:256,:]. One wave per node.
__global__ __launch_bounds__(256) void k_gateAB(
    const float* __restrict__ h, const float* __restrict__ Wg1, const float* __restrict__ bg1,
    float* __restrict__ A, float* __restrict__ B) {
    int wave = (blockIdx.x * blockDim.x + threadIdx.x) >> 6;
    int lane = threadIdx.x & 63;
    if (wave >= NODES) return;
    int k = lane & 31;
    const float* W = Wg1 + ((lane < 32) ? 0 : C * GH);
    const float* hrow = h + wave * C;
    float acc = (lane < 32) ? bg1[k] : 0.0f;
#pragma unroll 8
    for (int c = 0; c < C; c++) acc = fmaf(hrow[c], W[c * GH + k], acc);
    if (lane < 32) A[wave * GH + k] = acc;
    else           B[wave * GH + k] = acc;
}

// per CSR slot (32 lanes): coef = sigmoid(relu(A[ci]+B[r]+ea*w)@Wg2+b2)*dis[r]*dis[ci]
__global__ __launch_bounds__(256) void k_coef(
    const int* __restrict__ row_sorted, const int* __restrict__ col_sorted,
    const float* __restrict__ ea_sorted, const float* __restrict__ dis,
    const float* __restrict__ A, const float* __restrict__ Bm,
    const float* __restrict__ Wg1, const float* __restrict__ Wg2, const float* __restrict__ bg2,
    float* __restrict__ coef_sorted) {
    long long gid = (long long)blockIdx.x * blockDim.x + threadIdx.x;
    int s = (int)(gid >> 5);
    int k = threadIdx.x & 31;
    if (s >= ETOT) return;
    int r = row_sorted[s], ci = col_sorted[s];
    float ea = ea_sorted[s];
    float t = A[ci * GH + k] + Bm[r * GH + k] + ea * Wg1[2 * C * GH + k];
    t = fmaxf(t, 0.0f);
    float p = t * Wg2[k];
#pragma unroll
    for (int m = 16; m > 0; m >>= 1) p += __shfl_xor(p, m, 32);
    if (k == 0) {
        float gate = sigmoidf_(p + bg2[0]);
        coef_sorted[s] = gate * dis[r] * dis[ci];
    }
}

// wave per node: aggr[n] = sum over CSR slots of coef*h[row]; no atomics
__global__ __launch_bounds__(256) void k_aggr(
    const int* __restrict__ start, const int* __restrict__ row_sorted,
    const float* __restrict__ coef_sorted, const float* __restrict__ h,
    float* __restrict__ aggr) {
    int wid = (blockIdx.x * blockDim.x + threadIdx.x) >> 6;
    int lane = threadIdx.x & 63;
    if (wid >= NODES) return;
    int s0 = start[wid], s1 = start[wid + 1];
    const float2* h2 = (const float2*)h;
    float2 acc = make_float2(0.0f, 0.0f);
    for (int s = s0; s < s1; s++) {
        int r = row_sorted[s];
        float cf = coef_sorted[s];
        float2 v = h2[(size_t)r * 64 + lane];
        acc.x = fmaf(cf, v.x, acc.x);
        acc.y = fmaf(cf, v.y, acc.y);
    }
    ((float2*)aggr)[(size_t)wid * 64 + lane] = acc;
}

// GRU update, 16 nodes per 256-thread block
__global__ __launch_bounds__(256) void k_update(
    float* __restrict__ h, const float* __restrict__ aggr,
    const float* __restrict__ Wz, const float* __restrict__ bz,
    const float* __restrict__ Wr, const float* __restrict__ br,
    const float* __restrict__ Wh, const float* __restrict__ bh) {
    __shared__ float hs[NPB][C + 1], as[NPB][C + 1], rs[NPB][C + 1];
    int n0 = blockIdx.x * NPB;
    for (int idx = threadIdx.x; idx < NPB * C; idx += 256) {
        int n = idx >> 7, c = idx & 127;
        int gn = n0 + n;
        float hv = 0.0f, av = 0.0f;
        if (gn < NODES) { hv = h[(size_t)gn * C + c]; av = aggr[(size_t)gn * C + c]; }
        hs[n][c] = hv; as[n][c] = av;
    }
    __syncthreads();
    int k = threadIdx.x & 127;
    int half = threadIdx.x >> 7;
    float az[8], ar[8];
#pragma unroll
    for (int i = 0; i < 8; i++) { az[i] = bz[k]; ar[i] = br[k]; }
    for (int c = 0; c < C; c++) {
        float wz = Wz[c * C + k], wr = Wr[c * C + k];
#pragma unroll
        for (int i = 0; i < 8; i++) {
            float hv = hs[half * 8 + i][c];
            az[i] = fmaf(hv, wz, az[i]);
            ar[i] = fmaf(hv, wr, ar[i]);
        }
    }
    for (int c = 0; c < C; c++) {
        float wz = Wz[(C + c) * C + k], wr = Wr[(C + c) * C + k];
#pragma unroll
        for (int i = 0; i < 8; i++) {
            float av = as[half * 8 + i][c];
            az[i] = fmaf(av, wz, az[i]);
            ar[i] = fmaf(av, wr, ar[i]);
        }
    }
#pragma unroll
    for (int i = 0; i < 8; i++) {
        az[i] = sigmoidf_(az[i]);
        ar[i] = sigmoidf_(ar[i]);
        rs[half * 8 + i][k] = ar[i];
    }
    __syncthreads();
    float ah[8];
#pragma unroll
    for (int i = 0; i < 8; i++) ah[i] = bh[k];
    for (int c = 0; c < C; c++) {
        float w1 = Wh[c * C + k], w2 = Wh[(C + c) * C + k];
#pragma unroll
        for (int i = 0; i < 8; i++) {
            int n = half * 8 + i;
            ah[i] = fmaf(rs[n][c] * hs[n][c], w1, ah[i]);
            ah[i] = fmaf(as[n][c], w2, ah[i]);
        }
    }
#pragma unroll
    for (int i = 0; i < 8; i++) {
        int n = half * 8 + i; int gn = n0 + n;
        if (gn < NODES) {
            float hc = fmaxf(ah[i], 0.0f);
            float z = az[i];
            h[(size_t)gn * C + k] = (1.0f - z) * hs[n][k] + z * hc;
        }
    }
}

// out = relu([h0,h]@Wf1+bf1)@Wf2+bf2
__global__ __launch_bounds__(256) void k_final(
    const float* __restrict__ h0, const float* __restrict__ h,
    const float* __restrict__ Wf1, const float* __restrict__ bf1,
    const float* __restrict__ Wf2, const float* __restrict__ bf2,
    float* __restrict__ out) {
    __shared__ float h0s[NPB][C + 1], hs[NPB][C + 1], fs[NPB][C + 1];
    int n0 = blockIdx.x * NPB;
    for (int idx = threadIdx.x; idx < NPB * C; idx += 256) {
        int n = idx >> 7, c = idx & 127;
        int gn = n0 + n;
        float a = 0.0f, b = 0.0f;
        if (gn < NODES) { a = h0[(size_t)gn * C + c]; b = h[(size_t)gn * C + c]; }
        h0s[n][c] = a; hs[n][c] = b;
    }
    __syncthreads();
    int k = threadIdx.x & 127;
    int half = threadIdx.x >> 7;
    float acc[8];
#pragma unroll
    for (int i = 0; i < 8; i++) acc[i] = bf1[k];
    for (int c = 0; c < C; c++) {
        float w1 = Wf1[c * C + k], w2 = Wf1[(C + c) * C + k];
#pragma unroll
        for (int i = 0; i < 8; i++) {
            int n = half * 8 + i;
            acc[i] = fmaf(h0s[n][c], w1, acc[i]);
            acc[i] = fmaf(hs[n][c], w2, acc[i]);
        }
    }
#pragma unroll
    for (int i = 0; i < 8; i++) fs[half * 8 + i][k] = fmaxf(acc[i], 0.0f);
    __syncthreads();
    if (threadIdx.x < NPB * 2) {
        int n = threadIdx.x >> 1, o = threadIdx.x & 1;
        int gn = n0 + n;
        if (gn < NODES) {
            float a = bf2[o];
#pragma unroll 16
            for (int c = 0; c < C; c++) a = fmaf(fs[n][c], Wf2[c * 2 + o], a);
            out[(size_t)gn * 2 + o] = a;
        }
    }
}

extern "C" void kernel_launch(void* const* d_in, const int* in_sizes, int n_in,
                              void* d_out, int out_size, void* d_ws, size_t ws_size,
                              hipStream_t stream) {
    const float* x    = (const float*)d_in[0];
    const int*   eidx = (const int*)d_in[1];
    const float* eattr= (const float*)d_in[2];
    const float* Wpre = (const float*)d_in[3];  const float* bpre = (const float*)d_in[4];
    const float* Winit= (const float*)d_in[5];  const float* binit= (const float*)d_in[6];
    const float* Wg1  = (const float*)d_in[7];  const float* bg1  = (const float*)d_in[8];
    const float* Wg2  = (const float*)d_in[9];  const float* bg2  = (const float*)d_in[10];
    const float* Wz   = (const float*)d_in[11]; const float* bz   = (const float*)d_in[12];
    const float* Wr   = (const float*)d_in[13]; const float* br   = (const float*)d_in[14];
    const float* Wh   = (const float*)d_in[15]; const float* bh   = (const float*)d_in[16];
    const float* Wf1  = (const float*)d_in[17]; const float* bf1  = (const float*)d_in[18];
    const float* Wf2  = (const float*)d_in[19]; const float* bf2  = (const float*)d_in[20];
    float* out = (float*)d_out;

    // workspace layout (all 4-byte elements)
    float* ws  = (float*)d_ws;
    float* dis = ws;                               // N
    float* h   = dis + NODES;                      // N*C
    float* h0  = h + (size_t)NODES * C;            // N*C
    float* A   = h0 + (size_t)NODES * C;           // N*GH
    float* B   = A + (size_t)NODES * GH;           // N*GH
    float* aggr= B + (size_t)NODES * GH;           // N*C
    int*   start = (int*)(aggr + (size_t)NODES * C);   // N+1
    int*   cursor = start + NODES + 1;                 // N (+1 pad)
    int*   row_sorted = cursor + NODES + 1;            // ETOT
    int*   col_sorted = row_sorted + ETOT;             // ETOT
    float* ea_sorted  = (float*)(col_sorted + ETOT);   // ETOT
    float* coef_sorted= ea_sorted + ETOT;              // ETOT
    const size_t REQ = (size_t)((coef_sorted + ETOT) - ws) * sizeof(float);
    if (ws_size < REQ) return;  // fail visibly rather than corrupt memory

    hipMemsetAsync(dis, 0, NODES * sizeof(float), stream);
    k_degree<<<(NEDGES + 255) / 256, 256, 0, stream>>>(eidx + NEDGES, dis);
    k_scan<<<1, 1024, 0, stream>>>(dis, start, cursor);   // reads integer counts before k_dis overwrites
    k_dis<<<(NODES + 255) / 256, 256, 0, stream>>>(dis);
    k_csr<<<(ETOT + 255) / 256, 256, 0, stream>>>(eidx, eattr, cursor, row_sorted, col_sorted, ea_sorted);
    k_preproc<<<(NODES + 255) / 256, 256, 0, stream>>>(x, Wpre, bpre, Winit, binit, h0, h);

    for (int l = 0; l < LAYERS; l++) {
        k_gateAB<<<(NODES * 64 + 255) / 256, 256, 0, stream>>>(h, Wg1, bg1, A, B);
        k_coef<<<(int)(((long long)ETOT * 32 + 255) / 256), 256, 0, stream>>>(
            row_sorted, col_sorted, ea_sorted, dis, A, B, Wg1, Wg2, bg2, coef_sorted);
        k_aggr<<<(NODES * 64 + 255) / 256, 256, 0, stream>>>(start, row_sorted, coef_sorted, h, aggr);
        k_update<<<(NODES + NPB - 1) / NPB, 256, 0, stream>>>(h, aggr, Wz, bz, Wr, br, Wh, bh);
    }
    k_final<<<(NODES + NPB - 1) / NPB, 256, 0, stream>>>(h0, h, Wf1, bf1, Wf2, bf2, out);
}

// Round 4
// 1832.196 us; speedup vs baseline: 4.9896x; 1.5746x over previous
//
#include <hip/hip_runtime.h>
#include <math.h>

#define NODES 50000
#define NEDGES 800000
#define ETOT (NEDGES + NODES)
#define FIN 16
#define PRE 32
#define C 128
#define GH 32
#define LAYERS 5
#define NPB 16

typedef _Float16 f16;
typedef f16 f16x8 __attribute__((ext_vector_type(8)));
typedef f16 f16x2 __attribute__((ext_vector_type(2)));
typedef float f32x4 __attribute__((ext_vector_type(4)));

__device__ __forceinline__ float sigmoidf_(float x) { return 1.0f / (1.0f + __expf(-x)); }

// XOR-swizzled LDS byte offset: 16B-block index ^= (row&7)
__device__ __forceinline__ int swz_off(int row, int bytecol, int stride) {
    return row * stride + ((((bytecol) >> 4) ^ (row & 7)) << 4) + (bytecol & 15);
}

__global__ void k_degree(const int* __restrict__ col, float* __restrict__ deg) {
    int e = blockIdx.x * blockDim.x + threadIdx.x;
    if (e < NEDGES) atomicAdd(&deg[col[e]], 1.0f);
}

__global__ void k_dis(float* __restrict__ deg_dis) {
    int i = blockIdx.x * blockDim.x + threadIdx.x;
    if (i < NODES) deg_dis[i] = rsqrtf(deg_dis[i] + 1.0f);
}

// single-block exclusive prefix scan of (deg+1) -> start[], cursor[]
__global__ __launch_bounds__(1024) void k_scan(
    const float* __restrict__ deg, int* __restrict__ start, int* __restrict__ cursor) {
    __shared__ int chunk[1024];
    __shared__ int carry;
    if (threadIdx.x == 0) carry = 0;
    __syncthreads();
    for (int base = 0; base < NODES; base += 1024) {
        int i = base + threadIdx.x;
        int v = (i < NODES) ? (int)deg[i] + 1 : 0;
        chunk[threadIdx.x] = v;
        __syncthreads();
        for (int off = 1; off < 1024; off <<= 1) {
            int t = (threadIdx.x >= off) ? chunk[threadIdx.x - off] : 0;
            __syncthreads();
            chunk[threadIdx.x] += t;
            __syncthreads();
        }
        int incl = chunk[threadIdx.x];
        int block_total = chunk[1023];
        int s = carry + incl - v;
        if (i < NODES) { start[i] = s; cursor[i] = s; }
        __syncthreads();
        if (threadIdx.x == 0) carry += block_total;
        __syncthreads();
    }
    if (threadIdx.x == 0) start[NODES] = carry;
}

__global__ __launch_bounds__(256) void k_csr(
    const int* __restrict__ eidx, const float* __restrict__ eattr,
    int* __restrict__ cursor,
    int* __restrict__ row_sorted, int* __restrict__ col_sorted, float* __restrict__ ea_sorted) {
    int e = blockIdx.x * blockDim.x + threadIdx.x;
    if (e >= ETOT) return;
    int r, ci; float ea;
    if (e < NEDGES) { r = eidx[e]; ci = eidx[NEDGES + e]; ea = eattr[e]; }
    else            { r = ci = e - NEDGES; ea = 0.0f; }
    int slot = atomicAdd(&cursor[ci], 1);
    row_sorted[slot] = r;
    col_sorted[slot] = ci;
    ea_sorted[slot] = ea;
}

// pre-convert weights to fragment-ordered f16 buffers
// WcatF: K=256 -> 384 cols (z|r|p);  WhtopF: K=128 -> 128 cols;  Wg1F: K=128 -> 64 cols (A|B)
__global__ __launch_bounds__(256) void k_prep_w(
    const float* __restrict__ Wz, const float* __restrict__ Wr, const float* __restrict__ Wh,
    const float* __restrict__ Wg1,
    f16* __restrict__ WcatF, f16* __restrict__ WhtopF, f16* __restrict__ Wg1F) {
    int t = blockIdx.x * 256 + threadIdx.x;
    int l = t & 63;
    int lr = l & 15, lh = l >> 4;
    if (t < 24 * 8 * 64) {
        int idx = t >> 6; int nt = idx >> 3, ks = idx & 7;
        int n = nt * 16 + lr;
        f16x8 v;
#pragma unroll
        for (int j = 0; j < 8; j++) {
            int k = ks * 32 + lh * 8 + j;
            float x;
            if (n < 128)      x = Wz[k * 128 + n];
            else if (n < 256) x = Wr[k * 128 + (n - 128)];
            else              x = (k >= 128) ? Wh[k * 128 + (n - 256)] : 0.0f;
            v[j] = (f16)x;
        }
        *(f16x8*)(WcatF + (size_t)t * 8) = v;
    } else if (t < 24 * 8 * 64 + 8 * 4 * 64) {
        int t2 = t - 24 * 8 * 64;
        int idx = t2 >> 6; int nt = idx >> 2, ks = idx & 3;
        int n = nt * 16 + lr;
        f16x8 v;
#pragma unroll
        for (int j = 0; j < 8; j++) {
            int k = ks * 32 + lh * 8 + j;
            v[j] = (f16)Wh[k * 128 + n];
        }
        *(f16x8*)(WhtopF + (size_t)t2 * 8) = v;
    } else if (t < 24 * 8 * 64 + 8 * 4 * 64 + 4 * 4 * 64) {
        int t3 = t - (24 * 8 * 64 + 8 * 4 * 64);
        int idx = t3 >> 6; int nt = idx >> 2, ks = idx & 3;
        int cg = nt * 16 + lr;
        f16x8 v;
#pragma unroll
        for (int j = 0; j < 8; j++) {
            int k = ks * 32 + lh * 8 + j;
            v[j] = (f16)((cg < 32) ? Wg1[k * GH + cg] : Wg1[(128 + k) * GH + (cg - 32)]);
        }
        *(f16x8*)(Wg1F + (size_t)t3 * 8) = v;
    }
}

__global__ __launch_bounds__(256) void k_preproc(
    const float* __restrict__ x, const float* __restrict__ Wpre, const float* __restrict__ bpre,
    const float* __restrict__ Winit, const float* __restrict__ binit,
    float* __restrict__ h0, float* __restrict__ h) {
    __shared__ float sWpre[FIN * PRE], sbpre[PRE], sWinit[PRE * C], sbinit[C];
    for (int i = threadIdx.x; i < FIN * PRE; i += blockDim.x) sWpre[i] = Wpre[i];
    for (int i = threadIdx.x; i < PRE; i += blockDim.x) sbpre[i] = bpre[i];
    for (int i = threadIdx.x; i < PRE * C; i += blockDim.x) sWinit[i] = Winit[i];
    for (int i = threadIdx.x; i < C; i += blockDim.x) sbinit[i] = binit[i];
    __syncthreads();
    int n = blockIdx.x * blockDim.x + threadIdx.x;
    if (n >= NODES) return;
    float xv[FIN];
#pragma unroll
    for (int i = 0; i < FIN; i++) xv[i] = x[n * FIN + i];
    float pre[PRE];
#pragma unroll
    for (int k = 0; k < PRE; k++) {
        float a = sbpre[k];
#pragma unroll
        for (int i = 0; i < FIN; i++) a = fmaf(xv[i], sWpre[i * PRE + k], a);
        pre[k] = fmaxf(a, 0.0f);
    }
    for (int k = 0; k < C; k++) {
        float a = sbinit[k];
#pragma unroll
        for (int j = 0; j < PRE; j++) a = fmaf(pre[j], sWinit[j * C + k], a);
        a = fmaxf(a, 0.0f);
        h0[n * C + k] = a;
        h[n * C + k] = a;
    }
}

// standalone gate A/B for layer 0 (bias folded into A)
__global__ __launch_bounds__(256) void k_gateAB(
    const float* __restrict__ h, const float* __restrict__ Wg1, const float* __restrict__ bg1,
    float* __restrict__ A, float* __restrict__ B) {
    int wave = (blockIdx.x * blockDim.x + threadIdx.x) >> 6;
    int lane = threadIdx.x & 63;
    if (wave >= NODES) return;
    int k = lane & 31;
    const float* W = Wg1 + ((lane < 32) ? 0 : C * GH);
    const float* hrow = h + wave * C;
    float acc = (lane < 32) ? bg1[k] : 0.0f;
#pragma unroll 8
    for (int c = 0; c < C; c++) acc = fmaf(hrow[c], W[c * GH + k], acc);
    if (lane < 32) A[wave * GH + k] = acc;
    else           B[wave * GH + k] = acc;
}

__global__ __launch_bounds__(256) void k_coef(
    const int* __restrict__ row_sorted, const int* __restrict__ col_sorted,
    const float* __restrict__ ea_sorted, const float* __restrict__ dis,
    const float* __restrict__ A, const float* __restrict__ Bm,
    const float* __restrict__ Wg1, const float* __restrict__ Wg2, const float* __restrict__ bg2,
    float* __restrict__ coef_sorted) {
    long long gid = (long long)blockIdx.x * blockDim.x + threadIdx.x;
    int s = (int)(gid >> 5);
    int k = threadIdx.x & 31;
    if (s >= ETOT) return;
    int r = row_sorted[s], ci = col_sorted[s];
    float ea = ea_sorted[s];
    float t = A[ci * GH + k] + Bm[r * GH + k] + ea * Wg1[2 * C * GH + k];
    t = fmaxf(t, 0.0f);
    float p = t * Wg2[k];
#pragma unroll
    for (int m = 16; m > 0; m >>= 1) p += __shfl_xor(p, m, 32);
    if (k == 0) {
        float gate = sigmoidf_(p + bg2[0]);
        coef_sorted[s] = gate * dis[r] * dis[ci];
    }
}

__global__ __launch_bounds__(256) void k_aggr(
    const int* __restrict__ start, const int* __restrict__ row_sorted,
    const float* __restrict__ coef_sorted, const float* __restrict__ h,
    float* __restrict__ aggr) {
    int wid = (blockIdx.x * blockDim.x + threadIdx.x) >> 6;
    int lane = threadIdx.x & 63;
    if (wid >= NODES) return;
    int s0 = start[wid], s1 = start[wid + 1];
    const float2* h2 = (const float2*)h;
    float2 acc = make_float2(0.0f, 0.0f);
    for (int s = s0; s < s1; s++) {
        int r = row_sorted[s];
        float cf = coef_sorted[s];
        float2 v = h2[(size_t)r * 64 + lane];
        acc.x = fmaf(cf, v.x, acc.x);
        acc.y = fmaf(cf, v.y, acc.y);
    }
    ((float2*)aggr)[(size_t)wid * 64 + lane] = acc;
}

// GRU update via MFMA (f16 in / f32 accum) + fused gate A/B for next layer.
// 32 nodes/block, 4 waves. GEMM1: [h|aggr](K=256) -> z|r|p (384 cols).
// GEMM2: (r*h)(K=128) @ Wh_top + p + bh -> hc. GEMM3: h_new(K=128) @ Wg1F -> A|B.
__global__ __launch_bounds__(256) void k_update_mfma(
    float* __restrict__ h, const float* __restrict__ aggr,
    const f16* __restrict__ WcatF, const f16* __restrict__ WhtopF, const f16* __restrict__ Wg1F,
    const float* __restrict__ bz, const float* __restrict__ br, const float* __restrict__ bh,
    const float* __restrict__ bg1,
    float* __restrict__ Aout, float* __restrict__ Bout) {
    __shared__ float zs[32][132];   // during GEMM1 aliased as za: f16 [32][256] swizzled (16384B <= 16896B)
    __shared__ float ps[32][132];
    __shared__ f16 rhbuf[32 * 128]; // swizzled; reused as h_new staging for GEMM3
    char* zaB = (char*)&zs[0][0];
    char* rhB = (char*)&rhbuf[0];

    int tid = threadIdx.x;
    int l = tid & 63, w = tid >> 6;
    int lr = l & 15, lh = l >> 4;
    int n0 = blockIdx.x * 32;

    // stage za = [h | aggr] as swizzled f16
    for (int p = tid; p < 32 * 128; p += 256) {
        int row = p >> 7;
        int k2 = (p & 127) * 2;
        int gn = n0 + row;
        float2 v = make_float2(0.0f, 0.0f);
        if (gn < NODES) {
            v = (k2 < 128) ? *(const float2*)&h[(size_t)gn * C + k2]
                           : *(const float2*)&aggr[(size_t)gn * C + (k2 - 128)];
        }
        f16x2 hv; hv[0] = (f16)v.x; hv[1] = (f16)v.y;
        *(f16x2*)(zaB + swz_off(row, k2 * 2, 512)) = hv;
    }
    __syncthreads();

    // GEMM1
    f32x4 acc[2][6];
#pragma unroll
    for (int rt = 0; rt < 2; rt++)
#pragma unroll
        for (int n = 0; n < 6; n++)
#pragma unroll
            for (int j = 0; j < 4; j++) acc[rt][n][j] = 0.0f;
#pragma unroll
    for (int ks = 0; ks < 8; ks++) {
        int kk = ks * 32 + lh * 8;
        f16x8 a0 = *(const f16x8*)(zaB + swz_off(lr,      kk * 2, 512));
        f16x8 a1 = *(const f16x8*)(zaB + swz_off(lr + 16, kk * 2, 512));
#pragma unroll
        for (int ntl = 0; ntl < 6; ntl++) {
            int nt = w * 6 + ntl;
            f16x8 b = *(const f16x8*)(WcatF + ((size_t)(nt * 8 + ks) * 64 + l) * 8);
            acc[0][ntl] = __builtin_amdgcn_mfma_f32_16x16x32_f16(a0, b, acc[0][ntl], 0, 0, 0);
            acc[1][ntl] = __builtin_amdgcn_mfma_f32_16x16x32_f16(a1, b, acc[1][ntl], 0, 0, 0);
        }
    }
    __syncthreads();  // za reads done before zs overwrite

    // epilogue 1: z -> zs, r*h -> rhbuf(f16), p -> ps
#pragma unroll
    for (int rt = 0; rt < 2; rt++) {
#pragma unroll
        for (int ntl = 0; ntl < 6; ntl++) {
            int cg = (w * 6 + ntl) * 16 + lr;
#pragma unroll
            for (int j = 0; j < 4; j++) {
                int row = rt * 16 + lh * 4 + j;
                int gn = n0 + row;
                float v = acc[rt][ntl][j];
                if (cg < 128) {
                    zs[row][cg] = sigmoidf_(v + bz[cg]);
                } else if (cg < 256) {
                    int c = cg - 128;
                    float rv = sigmoidf_(v + br[c]);
                    float hov = (gn < NODES) ? h[(size_t)gn * C + c] : 0.0f;
                    *(f16*)(rhB + swz_off(row, c * 2, 256)) = (f16)(rv * hov);
                } else {
                    ps[row][cg - 256] = v;
                }
            }
        }
    }
    __syncthreads();

    // GEMM2: hc_pre = ps + bh + (r*h) @ Wh_top
    f32x4 acc2[2][2];
#pragma unroll
    for (int rt = 0; rt < 2; rt++)
#pragma unroll
        for (int ntl = 0; ntl < 2; ntl++) {
            int cg = (w * 2 + ntl) * 16 + lr;
#pragma unroll
            for (int j = 0; j < 4; j++)
                acc2[rt][ntl][j] = ps[rt * 16 + lh * 4 + j][cg] + bh[cg];
        }
#pragma unroll
    for (int ks = 0; ks < 4; ks++) {
        int kk = ks * 32 + lh * 8;
        f16x8 a0 = *(const f16x8*)(rhB + swz_off(lr,      kk * 2, 256));
        f16x8 a1 = *(const f16x8*)(rhB + swz_off(lr + 16, kk * 2, 256));
#pragma unroll
        for (int ntl = 0; ntl < 2; ntl++) {
            f16x8 b = *(const f16x8*)(WhtopF + ((size_t)((w * 2 + ntl) * 4 + ks) * 64 + l) * 8);
            acc2[0][ntl] = __builtin_amdgcn_mfma_f32_16x16x32_f16(a0, b, acc2[0][ntl], 0, 0, 0);
            acc2[1][ntl] = __builtin_amdgcn_mfma_f32_16x16x32_f16(a1, b, acc2[1][ntl], 0, 0, 0);
        }
    }
    __syncthreads();  // rh reads done before h_new staging overwrite

    // epilogue 2: h_new = (1-z)*h + z*relu(hc); write global + stage f16 for GEMM3
#pragma unroll
    for (int rt = 0; rt < 2; rt++)
#pragma unroll
        for (int ntl = 0; ntl < 2; ntl++) {
            int cg = (w * 2 + ntl) * 16 + lr;
#pragma unroll
            for (int j = 0; j < 4; j++) {
                int row = rt * 16 + lh * 4 + j;
                int gn = n0 + row;
                float hc = fmaxf(acc2[rt][ntl][j], 0.0f);
                float z = zs[row][cg];
                float hov = (gn < NODES) ? h[(size_t)gn * C + cg] : 0.0f;
                float hn = (1.0f - z) * hov + z * hc;
                if (gn < NODES) h[(size_t)gn * C + cg] = hn;
                *(f16*)(rhB + swz_off(row, cg * 2, 256)) = (f16)hn;
            }
        }
    __syncthreads();

    // GEMM3: A|B = h_new @ Wg1F (A gets +bg1)
    f32x4 acc3[2];
#pragma unroll
    for (int rt = 0; rt < 2; rt++)
#pragma unroll
        for (int j = 0; j < 4; j++) acc3[rt][j] = 0.0f;
#pragma unroll
    for (int ks = 0; ks < 4; ks++) {
        int kk = ks * 32 + lh * 8;
        f16x8 a0 = *(const f16x8*)(rhB + swz_off(lr,      kk * 2, 256));
        f16x8 a1 = *(const f16x8*)(rhB + swz_off(lr + 16, kk * 2, 256));
        f16x8 b = *(const f16x8*)(Wg1F + ((size_t)(w * 4 + ks) * 64 + l) * 8);
        acc3[0] = __builtin_amdgcn_mfma_f32_16x16x32_f16(a0, b, acc3[0], 0, 0, 0);
        acc3[1] = __builtin_amdgcn_mfma_f32_16x16x32_f16(a1, b, acc3[1], 0, 0, 0);
    }
    int col3 = w * 16 + lr;  // 0..63
#pragma unroll
    for (int rt = 0; rt < 2; rt++)
#pragma unroll
        for (int j = 0; j < 4; j++) {
            int row = rt * 16 + lh * 4 + j;
            int gn = n0 + row;
            if (gn < NODES) {
                float v = acc3[rt][j];
                if (col3 < 32) Aout[(size_t)gn * GH + col3] = v + bg1[col3];
                else           Bout[(size_t)gn * GH + (col3 - 32)] = v;
            }
        }
}

__global__ __launch_bounds__(256) void k_final(
    const float* __restrict__ h0, const float* __restrict__ h,
    const float* __restrict__ Wf1, const float* __restrict__ bf1,
    const float* __restrict__ Wf2, const float* __restrict__ bf2,
    float* __restrict__ out) {
    __shared__ float h0s[NPB][C + 1], hs[NPB][C + 1], fs[NPB][C + 1];
    int n0 = blockIdx.x * NPB;
    for (int idx = threadIdx.x; idx < NPB * C; idx += 256) {
        int n = idx >> 7, c = idx & 127;
        int gn = n0 + n;
        float a = 0.0f, b = 0.0f;
        if (gn < NODES) { a = h0[(size_t)gn * C + c]; b = h[(size_t)gn * C + c]; }
        h0s[n][c] = a; hs[n][c] = b;
    }
    __syncthreads();
    int k = threadIdx.x & 127;
    int half = threadIdx.x >> 7;
    float acc[8];
#pragma unroll
    for (int i = 0; i < 8; i++) acc[i] = bf1[k];
    for (int c = 0; c < C; c++) {
        float w1 = Wf1[c * C + k], w2 = Wf1[(C + c) * C + k];
#pragma unroll
        for (int i = 0; i < 8; i++) {
            int n = half * 8 + i;
            acc[i] = fmaf(h0s[n][c], w1, acc[i]);
            acc[i] = fmaf(hs[n][c], w2, acc[i]);
        }
    }
#pragma unroll
    for (int i = 0; i < 8; i++) fs[half * 8 + i][k] = fmaxf(acc[i], 0.0f);
    __syncthreads();
    if (threadIdx.x < NPB * 2) {
        int n = threadIdx.x >> 1, o = threadIdx.x & 1;
        int gn = n0 + n;
        if (gn < NODES) {
            float a = bf2[o];
#pragma unroll 16
            for (int c = 0; c < C; c++) a = fmaf(fs[n][c], Wf2[c * 2 + o], a);
            out[(size_t)gn * 2 + o] = a;
        }
    }
}

extern "C" void kernel_launch(void* const* d_in, const int* in_sizes, int n_in,
                              void* d_out, int out_size, void* d_ws, size_t ws_size,
                              hipStream_t stream) {
    const float* x    = (const float*)d_in[0];
    const int*   eidx = (const int*)d_in[1];
    const float* eattr= (const float*)d_in[2];
    const float* Wpre = (const float*)d_in[3];  const float* bpre = (const float*)d_in[4];
    const float* Winit= (const float*)d_in[5];  const float* binit= (const float*)d_in[6];
    const float* Wg1  = (const float*)d_in[7];  const float* bg1  = (const float*)d_in[8];
    const float* Wg2  = (const float*)d_in[9];  const float* bg2  = (const float*)d_in[10];
    const float* Wz   = (const float*)d_in[11]; const float* bz   = (const float*)d_in[12];
    const float* Wr   = (const float*)d_in[13]; const float* br   = (const float*)d_in[14];
    const float* Wh   = (const float*)d_in[15]; const float* bh   = (const float*)d_in[16];
    const float* Wf1  = (const float*)d_in[17]; const float* bf1  = (const float*)d_in[18];
    const float* Wf2  = (const float*)d_in[19]; const float* bf2  = (const float*)d_in[20];
    float* out = (float*)d_out;

    float* ws  = (float*)d_ws;
    float* dis = ws;                               // N
    float* h   = dis + NODES;                      // N*C
    float* h0  = h + (size_t)NODES * C;            // N*C
    float* A   = h0 + (size_t)NODES * C;           // N*GH
    float* B   = A + (size_t)NODES * GH;           // N*GH
    float* aggr= B + (size_t)NODES * GH;           // N*C
    int*   start = (int*)(aggr + (size_t)NODES * C);   // N+1
    int*   cursor = start + NODES + 1;                 // N (+1 pad)
    int*   row_sorted = cursor + NODES + 1;            // ETOT
    int*   col_sorted = row_sorted + ETOT;             // ETOT
    float* ea_sorted  = (float*)(col_sorted + ETOT);   // ETOT
    float* coef_sorted= ea_sorted + ETOT;              // ETOT
    size_t f16_base = (size_t)((coef_sorted + ETOT) - ws);
    f16_base = (f16_base + 3) & ~(size_t)3;            // 16B align
    f16* WcatF  = (f16*)(ws + f16_base);               // 24*8*64*8 f16
    f16* WhtopF = WcatF + 24 * 8 * 64 * 8;             // 8*4*64*8 f16
    f16* Wg1F   = WhtopF + 8 * 4 * 64 * 8;             // 4*4*64*8 f16
    const size_t REQ = (f16_base + (24 * 8 + 8 * 4 + 4 * 4) * 64 * 4) * sizeof(float);
    if (ws_size < REQ) return;

    hipMemsetAsync(dis, 0, NODES * sizeof(float), stream);
    k_degree<<<(NEDGES + 255) / 256, 256, 0, stream>>>(eidx + NEDGES, dis);
    k_scan<<<1, 1024, 0, stream>>>(dis, start, cursor);
    k_dis<<<(NODES + 255) / 256, 256, 0, stream>>>(dis);
    k_csr<<<(ETOT + 255) / 256, 256, 0, stream>>>(eidx, eattr, cursor, row_sorted, col_sorted, ea_sorted);
    k_prep_w<<<(24 * 8 * 64 + 8 * 4 * 64 + 4 * 4 * 64 + 255) / 256, 256, 0, stream>>>(
        Wz, Wr, Wh, Wg1, WcatF, WhtopF, Wg1F);
    k_preproc<<<(NODES + 255) / 256, 256, 0, stream>>>(x, Wpre, bpre, Winit, binit, h0, h);
    k_gateAB<<<(NODES * 64 + 255) / 256, 256, 0, stream>>>(h, Wg1, bg1, A, B);

    for (int l = 0; l < LAYERS; l++) {
        k_coef<<<(int)(((long long)ETOT * 32 + 255) / 256), 256, 0, stream>>>(
            row_sorted, col_sorted, ea_sorted, dis, A, B, Wg1, Wg2, bg2, coef_sorted);
        k_aggr<<<(NODES * 64 + 255) / 256, 256, 0, stream>>>(start, row_sorted, coef_sorted, h, aggr);
        k_update_mfma<<<(NODES + 31) / 32, 256, 0, stream>>>(
            h, aggr, WcatF, WhtopF, Wg1F, bz, br, bh, bg1, A, B);
    }
    k_final<<<(NODES + NPB - 1) / NPB, 256, 0, stream>>>(h0, h, Wf1, bf1, Wf2, bf2, out);
}

// Round 5
// 1501.521 us; speedup vs baseline: 6.0884x; 1.2202x over previous
//
#include <hip/hip_runtime.h>
#include <math.h>

#define NODES 50000
#define NEDGES 800000
#define ETOT (NEDGES + NODES)
#define FIN 16
#define PRE 32
#define C 128
#define GH 32
#define LAYERS 5

typedef _Float16 f16;
typedef f16 f16x8 __attribute__((ext_vector_type(8)));
typedef f16 f16x2 __attribute__((ext_vector_type(2)));
typedef float f32x4 __attribute__((ext_vector_type(4)));

__device__ __forceinline__ float sigmoidf_(float x) { return 1.0f / (1.0f + __expf(-x)); }

// XOR-swizzled LDS byte offset: 16B-block index ^= (row&7)
__device__ __forceinline__ int swz_off(int row, int bytecol, int stride) {
    return row * stride + ((((bytecol) >> 4) ^ (row & 7)) << 4) + (bytecol & 15);
}

__global__ void k_degree(const int* __restrict__ col, float* __restrict__ deg) {
    int e = blockIdx.x * blockDim.x + threadIdx.x;
    if (e < NEDGES) atomicAdd(&deg[col[e]], 1.0f);
}

__global__ void k_dis(float* __restrict__ deg_dis) {
    int i = blockIdx.x * blockDim.x + threadIdx.x;
    if (i < NODES) deg_dis[i] = rsqrtf(deg_dis[i] + 1.0f);
}

// single-block exclusive prefix scan of (deg+1) -> start[], cursor[]
__global__ __launch_bounds__(1024) void k_scan(
    const float* __restrict__ deg, int* __restrict__ start, int* __restrict__ cursor) {
    __shared__ int chunk[1024];
    __shared__ int carry;
    if (threadIdx.x == 0) carry = 0;
    __syncthreads();
    for (int base = 0; base < NODES; base += 1024) {
        int i = base + threadIdx.x;
        int v = (i < NODES) ? (int)deg[i] + 1 : 0;
        chunk[threadIdx.x] = v;
        __syncthreads();
        for (int off = 1; off < 1024; off <<= 1) {
            int t = (threadIdx.x >= off) ? chunk[threadIdx.x - off] : 0;
            __syncthreads();
            chunk[threadIdx.x] += t;
            __syncthreads();
        }
        int incl = chunk[threadIdx.x];
        int block_total = chunk[1023];
        int s = carry + incl - v;
        if (i < NODES) { start[i] = s; cursor[i] = s; }
        __syncthreads();
        if (threadIdx.x == 0) carry += block_total;
        __syncthreads();
    }
    if (threadIdx.x == 0) start[NODES] = carry;
}

__global__ __launch_bounds__(256) void k_csr(
    const int* __restrict__ eidx, const float* __restrict__ eattr,
    int* __restrict__ cursor,
    int* __restrict__ row_sorted, float* __restrict__ ea_sorted) {
    int e = blockIdx.x * blockDim.x + threadIdx.x;
    if (e >= ETOT) return;
    int r, ci; float ea;
    if (e < NEDGES) { r = eidx[e]; ci = eidx[NEDGES + e]; ea = eattr[e]; }
    else            { r = ci = e - NEDGES; ea = 0.0f; }
    int slot = atomicAdd(&cursor[ci], 1);
    row_sorted[slot] = r;
    ea_sorted[slot] = ea;
}

// pre-convert weights to fragment-ordered f16 buffers
// WcatF: K=256 -> 384 cols (z|r|p); WhtopF: K=128 -> 128; Wg1F: K=128 -> 64 (A|B); Wf1F: K=256 -> 128
__global__ __launch_bounds__(256) void k_prep_w(
    const float* __restrict__ Wz, const float* __restrict__ Wr, const float* __restrict__ Wh,
    const float* __restrict__ Wg1, const float* __restrict__ Wf1,
    f16* __restrict__ WcatF, f16* __restrict__ WhtopF, f16* __restrict__ Wg1F,
    f16* __restrict__ Wf1F) {
    int t = blockIdx.x * 256 + threadIdx.x;
    int l = t & 63;
    int lr = l & 15, lh = l >> 4;
    if (t < 24 * 8 * 64) {
        int idx = t >> 6; int nt = idx >> 3, ks = idx & 7;
        int n = nt * 16 + lr;
        f16x8 v;
#pragma unroll
        for (int j = 0; j < 8; j++) {
            int k = ks * 32 + lh * 8 + j;
            float x;
            if (n < 128)      x = Wz[k * 128 + n];
            else if (n < 256) x = Wr[k * 128 + (n - 128)];
            else              x = (k >= 128) ? Wh[k * 128 + (n - 256)] : 0.0f;
            v[j] = (f16)x;
        }
        *(f16x8*)(WcatF + (size_t)t * 8) = v;
    } else if (t < 24 * 8 * 64 + 8 * 4 * 64) {
        int t2 = t - 24 * 8 * 64;
        int idx = t2 >> 6; int nt = idx >> 2, ks = idx & 3;
        int n = nt * 16 + lr;
        f16x8 v;
#pragma unroll
        for (int j = 0; j < 8; j++) {
            int k = ks * 32 + lh * 8 + j;
            v[j] = (f16)Wh[k * 128 + n];
        }
        *(f16x8*)(WhtopF + (size_t)t2 * 8) = v;
    } else if (t < 24 * 8 * 64 + 8 * 4 * 64 + 4 * 4 * 64) {
        int t3 = t - (24 * 8 * 64 + 8 * 4 * 64);
        int idx = t3 >> 6; int nt = idx >> 2, ks = idx & 3;
        int cg = nt * 16 + lr;
        f16x8 v;
#pragma unroll
        for (int j = 0; j < 8; j++) {
            int k = ks * 32 + lh * 8 + j;
            v[j] = (f16)((cg < 32) ? Wg1[k * GH + cg] : Wg1[(128 + k) * GH + (cg - 32)]);
        }
        *(f16x8*)(Wg1F + (size_t)t3 * 8) = v;
    } else if (t < 24 * 8 * 64 + 8 * 4 * 64 + 4 * 4 * 64 + 8 * 8 * 64) {
        int t4 = t - (24 * 8 * 64 + 8 * 4 * 64 + 4 * 4 * 64);
        int idx = t4 >> 6; int nt = idx >> 3, ks = idx & 7;
        int n = nt * 16 + lr;
        f16x8 v;
#pragma unroll
        for (int j = 0; j < 8; j++) {
            int k = ks * 32 + lh * 8 + j;
            v[j] = (f16)Wf1[k * 128 + n];
        }
        *(f16x8*)(Wf1F + (size_t)t4 * 8) = v;
    }
}

__global__ __launch_bounds__(256) void k_preproc(
    const float* __restrict__ x, const float* __restrict__ Wpre, const float* __restrict__ bpre,
    const float* __restrict__ Winit, const float* __restrict__ binit,
    float* __restrict__ h0, float* __restrict__ h) {
    __shared__ float sWpre[FIN * PRE], sbpre[PRE], sWinit[PRE * C], sbinit[C];
    for (int i = threadIdx.x; i < FIN * PRE; i += blockDim.x) sWpre[i] = Wpre[i];
    for (int i = threadIdx.x; i < PRE; i += blockDim.x) sbpre[i] = bpre[i];
    for (int i = threadIdx.x; i < PRE * C; i += blockDim.x) sWinit[i] = Winit[i];
    for (int i = threadIdx.x; i < C; i += blockDim.x) sbinit[i] = binit[i];
    __syncthreads();
    int n = blockIdx.x * blockDim.x + threadIdx.x;
    if (n >= NODES) return;
    float xv[FIN];
#pragma unroll
    for (int i = 0; i < FIN; i++) xv[i] = x[n * FIN + i];
    float pre[PRE];
#pragma unroll
    for (int k = 0; k < PRE; k++) {
        float a = sbpre[k];
#pragma unroll
        for (int i = 0; i < FIN; i++) a = fmaf(xv[i], sWpre[i * PRE + k], a);
        pre[k] = fmaxf(a, 0.0f);
    }
    for (int k = 0; k < C; k++) {
        float a = sbinit[k];
#pragma unroll
        for (int j = 0; j < PRE; j++) a = fmaf(pre[j], sWinit[j * C + k], a);
        a = fmaxf(a, 0.0f);
        h0[n * C + k] = a;
        h[n * C + k] = a;
    }
}

// standalone gate A/B for layer 0 (bias folded into A)
__global__ __launch_bounds__(256) void k_gateAB(
    const float* __restrict__ h, const float* __restrict__ Wg1, const float* __restrict__ bg1,
    float* __restrict__ A, float* __restrict__ B) {
    int wave = (blockIdx.x * blockDim.x + threadIdx.x) >> 6;
    int lane = threadIdx.x & 63;
    if (wave >= NODES) return;
    int k = lane & 31;
    const float* W = Wg1 + ((lane < 32) ? 0 : C * GH);
    const float* hrow = h + wave * C;
    float acc = (lane < 32) ? bg1[k] : 0.0f;
#pragma unroll 8
    for (int c = 0; c < C; c++) acc = fmaf(hrow[c], W[c * GH + k], acc);
    if (lane < 32) A[wave * GH + k] = acc;
    else           B[wave * GH + k] = acc;
}

// fused gate+aggregate: wave per node; A[ci],dis[ci] hoisted (CSR: col==wid)
__global__ __launch_bounds__(256) void k_msg(
    const int* __restrict__ start, const int* __restrict__ row_sorted,
    const float* __restrict__ ea_sorted, const float* __restrict__ dis,
    const float* __restrict__ A, const float* __restrict__ Bm,
    const float* __restrict__ Wg1, const float* __restrict__ Wg2, const float* __restrict__ bg2,
    const float* __restrict__ h, float* __restrict__ aggr) {
    int wid = (blockIdx.x * blockDim.x + threadIdx.x) >> 6;
    int lane = threadIdx.x & 63;
    if (wid >= NODES) return;
    int k = lane & 31;
    int s0 = start[wid], s1 = start[wid + 1];
    float a_reg = A[wid * GH + k];           // bg1 already folded in
    float w_ea = Wg1[2 * C * GH + k];
    float wg2 = Wg2[k];
    float b2 = bg2[0];
    float dci = dis[wid];
    const float2* h2 = (const float2*)h;
    float2 acc = make_float2(0.0f, 0.0f);
#pragma unroll 2
    for (int s = s0; s < s1; s++) {
        int r = row_sorted[s];
        float ea = ea_sorted[s];
        float2 v = h2[(size_t)r * 64 + lane];           // issue early, used after reduce
        float t = fmaxf(a_reg + Bm[r * GH + k] + ea * w_ea, 0.0f);
        float p = t * wg2;
#pragma unroll
        for (int m = 16; m > 0; m >>= 1) p += __shfl_xor(p, m, 32);
        float coef = sigmoidf_(p + b2) * dis[r] * dci;
        acc.x = fmaf(coef, v.x, acc.x);
        acc.y = fmaf(coef, v.y, acc.y);
    }
    ((float2*)aggr)[(size_t)wid * 64 + lane] = acc;
}

// GRU update via MFMA (f16 in / f32 accum) + fused gate A/B for next layer.
__global__ __launch_bounds__(256) void k_update_mfma(
    float* __restrict__ h, const float* __restrict__ aggr,
    const f16* __restrict__ WcatF, const f16* __restrict__ WhtopF, const f16* __restrict__ Wg1F,
    const float* __restrict__ bz, const float* __restrict__ br, const float* __restrict__ bh,
    const float* __restrict__ bg1,
    float* __restrict__ Aout, float* __restrict__ Bout) {
    __shared__ float zs[32][132];   // during GEMM1 aliased as za: f16 [32][256] swizzled
    __shared__ float ps[32][132];
    __shared__ f16 rhbuf[32 * 128]; // swizzled; reused as h_new staging for GEMM3
    char* zaB = (char*)&zs[0][0];
    char* rhB = (char*)&rhbuf[0];

    int tid = threadIdx.x;
    int l = tid & 63, w = tid >> 6;
    int lr = l & 15, lh = l >> 4;
    int n0 = blockIdx.x * 32;

    for (int p = tid; p < 32 * 128; p += 256) {
        int row = p >> 7;
        int k2 = (p & 127) * 2;
        int gn = n0 + row;
        float2 v = make_float2(0.0f, 0.0f);
        if (gn < NODES) {
            v = (k2 < 128) ? *(const float2*)&h[(size_t)gn * C + k2]
                           : *(const float2*)&aggr[(size_t)gn * C + (k2 - 128)];
        }
        f16x2 hv; hv[0] = (f16)v.x; hv[1] = (f16)v.y;
        *(f16x2*)(zaB + swz_off(row, k2 * 2, 512)) = hv;
    }
    __syncthreads();

    f32x4 acc[2][6];
#pragma unroll
    for (int rt = 0; rt < 2; rt++)
#pragma unroll
        for (int n = 0; n < 6; n++)
#pragma unroll
            for (int j = 0; j < 4; j++) acc[rt][n][j] = 0.0f;
#pragma unroll
    for (int ks = 0; ks < 8; ks++) {
        int kk = ks * 32 + lh * 8;
        f16x8 a0 = *(const f16x8*)(zaB + swz_off(lr,      kk * 2, 512));
        f16x8 a1 = *(const f16x8*)(zaB + swz_off(lr + 16, kk * 2, 512));
#pragma unroll
        for (int ntl = 0; ntl < 6; ntl++) {
            int nt = w * 6 + ntl;
            f16x8 b = *(const f16x8*)(WcatF + ((size_t)(nt * 8 + ks) * 64 + l) * 8);
            acc[0][ntl] = __builtin_amdgcn_mfma_f32_16x16x32_f16(a0, b, acc[0][ntl], 0, 0, 0);
            acc[1][ntl] = __builtin_amdgcn_mfma_f32_16x16x32_f16(a1, b, acc[1][ntl], 0, 0, 0);
        }
    }
    __syncthreads();

#pragma unroll
    for (int rt = 0; rt < 2; rt++) {
#pragma unroll
        for (int ntl = 0; ntl < 6; ntl++) {
            int cg = (w * 6 + ntl) * 16 + lr;
#pragma unroll
            for (int j = 0; j < 4; j++) {
                int row = rt * 16 + lh * 4 + j;
                int gn = n0 + row;
                float v = acc[rt][ntl][j];
                if (cg < 128) {
                    zs[row][cg] = sigmoidf_(v + bz[cg]);
                } else if (cg < 256) {
                    int c = cg - 128;
                    float rv = sigmoidf_(v + br[c]);
                    float hov = (gn < NODES) ? h[(size_t)gn * C + c] : 0.0f;
                    *(f16*)(rhB + swz_off(row, c * 2, 256)) = (f16)(rv * hov);
                } else {
                    ps[row][cg - 256] = v;
                }
            }
        }
    }
    __syncthreads();

    f32x4 acc2[2][2];
#pragma unroll
    for (int rt = 0; rt < 2; rt++)
#pragma unroll
        for (int ntl = 0; ntl < 2; ntl++) {
            int cg = (w * 2 + ntl) * 16 + lr;
#pragma unroll
            for (int j = 0; j < 4; j++)
                acc2[rt][ntl][j] = ps[rt * 16 + lh * 4 + j][cg] + bh[cg];
        }
#pragma unroll
    for (int ks = 0; ks < 4; ks++) {
        int kk = ks * 32 + lh * 8;
        f16x8 a0 = *(const f16x8*)(rhB + swz_off(lr,      kk * 2, 256));
        f16x8 a1 = *(const f16x8*)(rhB + swz_off(lr + 16, kk * 2, 256));
#pragma unroll
        for (int ntl = 0; ntl < 2; ntl++) {
            f16x8 b = *(const f16x8*)(WhtopF + ((size_t)((w * 2 + ntl) * 4 + ks) * 64 + l) * 8);
            acc2[0][ntl] = __builtin_amdgcn_mfma_f32_16x16x32_f16(a0, b, acc2[0][ntl], 0, 0, 0);
            acc2[1][ntl] = __builtin_amdgcn_mfma_f32_16x16x32_f16(a1, b, acc2[1][ntl], 0, 0, 0);
        }
    }
    __syncthreads();

#pragma unroll
    for (int rt = 0; rt < 2; rt++)
#pragma unroll
        for (int ntl = 0; ntl < 2; ntl++) {
            int cg = (w * 2 + ntl) * 16 + lr;
#pragma unroll
            for (int j = 0; j < 4; j++) {
                int row = rt * 16 + lh * 4 + j;
                int gn = n0 + row;
                float hc = fmaxf(acc2[rt][ntl][j], 0.0f);
                float z = zs[row][cg];
                float hov = (gn < NODES) ? h[(size_t)gn * C + cg] : 0.0f;
                float hn = (1.0f - z) * hov + z * hc;
                if (gn < NODES) h[(size_t)gn * C + cg] = hn;
                *(f16*)(rhB + swz_off(row, cg * 2, 256)) = (f16)hn;
            }
        }
    __syncthreads();

    f32x4 acc3[2];
#pragma unroll
    for (int rt = 0; rt < 2; rt++)
#pragma unroll
        for (int j = 0; j < 4; j++) acc3[rt][j] = 0.0f;
#pragma unroll
    for (int ks = 0; ks < 4; ks++) {
        int kk = ks * 32 + lh * 8;
        f16x8 a0 = *(const f16x8*)(rhB + swz_off(lr,      kk * 2, 256));
        f16x8 a1 = *(const f16x8*)(rhB + swz_off(lr + 16, kk * 2, 256));
        f16x8 b = *(const f16x8*)(Wg1F + ((size_t)(w * 4 + ks) * 64 + l) * 8);
        acc3[0] = __builtin_amdgcn_mfma_f32_16x16x32_f16(a0, b, acc3[0], 0, 0, 0);
        acc3[1] = __builtin_amdgcn_mfma_f32_16x16x32_f16(a1, b, acc3[1], 0, 0, 0);
    }
    int col3 = w * 16 + lr;
#pragma unroll
    for (int rt = 0; rt < 2; rt++)
#pragma unroll
        for (int j = 0; j < 4; j++) {
            int row = rt * 16 + lh * 4 + j;
            int gn = n0 + row;
            if (gn < NODES) {
                float v = acc3[rt][j];
                if (col3 < 32) Aout[(size_t)gn * GH + col3] = v + bg1[col3];
                else           Bout[(size_t)gn * GH + (col3 - 32)] = v;
            }
        }
}

// final head via MFMA: f = relu([h0|h]@Wf1+bf1); out = f@Wf2+bf2
__global__ __launch_bounds__(256) void k_final_mfma(
    const float* __restrict__ h0, const float* __restrict__ h,
    const f16* __restrict__ Wf1F, const float* __restrict__ bf1,
    const float* __restrict__ Wf2, const float* __restrict__ bf2,
    float* __restrict__ out) {
    __shared__ float fs[32][132];   // aliased during stage as f16 za [32][256] swizzled
    char* zaB = (char*)&fs[0][0];
    int tid = threadIdx.x;
    int l = tid & 63, w = tid >> 6;
    int lr = l & 15, lh = l >> 4;
    int n0 = blockIdx.x * 32;

    for (int p = tid; p < 32 * 128; p += 256) {
        int row = p >> 7;
        int k2 = (p & 127) * 2;
        int gn = n0 + row;
        float2 v = make_float2(0.0f, 0.0f);
        if (gn < NODES) {
            v = (k2 < 128) ? *(const float2*)&h0[(size_t)gn * C + k2]
                           : *(const float2*)&h[(size_t)gn * C + (k2 - 128)];
        }
        f16x2 hv; hv[0] = (f16)v.x; hv[1] = (f16)v.y;
        *(f16x2*)(zaB + swz_off(row, k2 * 2, 512)) = hv;
    }
    __syncthreads();

    f32x4 acc[2][2];
#pragma unroll
    for (int rt = 0; rt < 2; rt++)
#pragma unroll
        for (int n = 0; n < 2; n++)
#pragma unroll
            for (int j = 0; j < 4; j++) acc[rt][n][j] = 0.0f;
#pragma unroll
    for (int ks = 0; ks < 8; ks++) {
        int kk = ks * 32 + lh * 8;
        f16x8 a0 = *(const f16x8*)(zaB + swz_off(lr,      kk * 2, 512));
        f16x8 a1 = *(const f16x8*)(zaB + swz_off(lr + 16, kk * 2, 512));
#pragma unroll
        for (int ntl = 0; ntl < 2; ntl++) {
            f16x8 b = *(const f16x8*)(Wf1F + ((size_t)((w * 2 + ntl) * 8 + ks) * 64 + l) * 8);
            acc[0][ntl] = __builtin_amdgcn_mfma_f32_16x16x32_f16(a0, b, acc[0][ntl], 0, 0, 0);
            acc[1][ntl] = __builtin_amdgcn_mfma_f32_16x16x32_f16(a1, b, acc[1][ntl], 0, 0, 0);
        }
    }
    __syncthreads();  // za reads done before fs overwrite

#pragma unroll
    for (int rt = 0; rt < 2; rt++)
#pragma unroll
        for (int ntl = 0; ntl < 2; ntl++) {
            int cg = (w * 2 + ntl) * 16 + lr;
#pragma unroll
            for (int j = 0; j < 4; j++) {
                int row = rt * 16 + lh * 4 + j;
                fs[row][cg] = fmaxf(acc[rt][ntl][j] + bf1[cg], 0.0f);
            }
        }
    __syncthreads();

    if (tid < 64) {
        int n = tid >> 1, o = tid & 1;
        int gn = n0 + n;
        if (gn < NODES) {
            float a = bf2[o];
#pragma unroll 16
            for (int c = 0; c < C; c++) a = fmaf(fs[n][c], Wf2[c * 2 + o], a);
            out[(size_t)gn * 2 + o] = a;
        }
    }
}

extern "C" void kernel_launch(void* const* d_in, const int* in_sizes, int n_in,
                              void* d_out, int out_size, void* d_ws, size_t ws_size,
                              hipStream_t stream) {
    const float* x    = (const float*)d_in[0];
    const int*   eidx = (const int*)d_in[1];
    const float* eattr= (const float*)d_in[2];
    const float* Wpre = (const float*)d_in[3];  const float* bpre = (const float*)d_in[4];
    const float* Winit= (const float*)d_in[5];  const float* binit= (const float*)d_in[6];
    const float* Wg1  = (const float*)d_in[7];  const float* bg1  = (const float*)d_in[8];
    const float* Wg2  = (const float*)d_in[9];  const float* bg2  = (const float*)d_in[10];
    const float* Wz   = (const float*)d_in[11]; const float* bz   = (const float*)d_in[12];
    const float* Wr   = (const float*)d_in[13]; const float* br   = (const float*)d_in[14];
    const float* Wh   = (const float*)d_in[15]; const float* bh   = (const float*)d_in[16];
    const float* Wf1  = (const float*)d_in[17]; const float* bf1  = (const float*)d_in[18];
    const float* Wf2  = (const float*)d_in[19]; const float* bf2  = (const float*)d_in[20];
    float* out = (float*)d_out;

    float* ws  = (float*)d_ws;
    float* dis = ws;                               // N
    float* h   = dis + NODES;                      // N*C
    float* h0  = h + (size_t)NODES * C;            // N*C
    float* A   = h0 + (size_t)NODES * C;           // N*GH
    float* B   = A + (size_t)NODES * GH;           // N*GH
    float* aggr= B + (size_t)NODES * GH;           // N*C
    int*   start = (int*)(aggr + (size_t)NODES * C);   // N+1
    int*   cursor = start + NODES + 1;                 // N (+1 pad)
    int*   row_sorted = cursor + NODES + 1;            // ETOT
    float* ea_sorted  = (float*)(row_sorted + ETOT);   // ETOT
    size_t f16_base = (size_t)((ea_sorted + ETOT) - ws);
    f16_base = (f16_base + 3) & ~(size_t)3;            // 16B align
    f16* WcatF  = (f16*)(ws + f16_base);               // 24*8*64*8 f16
    f16* WhtopF = WcatF + 24 * 8 * 64 * 8;             // 8*4*64*8
    f16* Wg1F   = WhtopF + 8 * 4 * 64 * 8;             // 4*4*64*8
    f16* Wf1F   = Wg1F + 4 * 4 * 64 * 8;               // 8*8*64*8
    const size_t REQ = (f16_base + (24 * 8 + 8 * 4 + 4 * 4 + 8 * 8) * 64 * 4) * sizeof(float);
    if (ws_size < REQ) return;

    hipMemsetAsync(dis, 0, NODES * sizeof(float), stream);
    k_degree<<<(NEDGES + 255) / 256, 256, 0, stream>>>(eidx + NEDGES, dis);
    k_scan<<<1, 1024, 0, stream>>>(dis, start, cursor);
    k_dis<<<(NODES + 255) / 256, 256, 0, stream>>>(dis);
    k_csr<<<(ETOT + 255) / 256, 256, 0, stream>>>(eidx, eattr, cursor, row_sorted, ea_sorted);
    k_prep_w<<<(24 * 8 * 64 + 8 * 4 * 64 + 4 * 4 * 64 + 8 * 8 * 64 + 255) / 256, 256, 0, stream>>>(
        Wz, Wr, Wh, Wg1, Wf1, WcatF, WhtopF, Wg1F, Wf1F);
    k_preproc<<<(NODES + 255) / 256, 256, 0, stream>>>(x, Wpre, bpre, Winit, binit, h0, h);
    k_gateAB<<<(NODES * 64 + 255) / 256, 256, 0, stream>>>(h, Wg1, bg1, A, B);

    for (int l = 0; l < LAYERS; l++) {
        k_msg<<<(NODES * 64 + 255) / 256, 256, 0, stream>>>(
            start, row_sorted, ea_sorted, dis, A, B, Wg1, Wg2, bg2, h, aggr);
        k_update_mfma<<<(NODES + 31) / 32, 256, 0, stream>>>(
            h, aggr, WcatF, WhtopF, Wg1F, bz, br, bh, bg1, A, B);
    }
    k_final_mfma<<<(NODES + 31) / 32, 256, 0, stream>>>(h0, h, Wf1F, bf1, Wf2, bf2, out);
}

// Round 6
// 1240.681 us; speedup vs baseline: 7.3684x; 1.2102x over previous
//
#include <hip/hip_runtime.h>
#include <math.h>

#define NODES 50000
#define NEDGES 800000
#define ETOT (NEDGES + NODES)
#define FIN 16
#define PRE 32
#define C 128
#define GH 32
#define LAYERS 5
#define RECS 160   // f16 per node record: [B16:32 | h16:128]

typedef _Float16 f16;
typedef f16 f16x8 __attribute__((ext_vector_type(8)));
typedef f16 f16x2 __attribute__((ext_vector_type(2)));
typedef float f32x4 __attribute__((ext_vector_type(4)));

__device__ __forceinline__ float sigmoidf_(float x) { return 1.0f / (1.0f + __expf(-x)); }

// XOR-swizzled LDS byte offset: 16B-block index ^= (row&7)
__device__ __forceinline__ int swz_off(int row, int bytecol, int stride) {
    return row * stride + ((((bytecol) >> 4) ^ (row & 7)) << 4) + (bytecol & 15);
}

__global__ void k_degree(const int* __restrict__ col, float* __restrict__ deg) {
    int e = blockIdx.x * blockDim.x + threadIdx.x;
    if (e < NEDGES) atomicAdd(&deg[col[e]], 1.0f);
}

__global__ void k_dis(float* __restrict__ deg_dis) {
    int i = blockIdx.x * blockDim.x + threadIdx.x;
    if (i < NODES) deg_dis[i] = rsqrtf(deg_dis[i] + 1.0f);
}

// single-block scan: serial per-thread chunks + shfl block scan (2 barriers)
__global__ __launch_bounds__(1024) void k_scan(
    const float* __restrict__ deg, int* __restrict__ start, int* __restrict__ cursor) {
    __shared__ int wsum[16];
    int tid = threadIdx.x;
    int lane = tid & 63, wv = tid >> 6;
    const int CH = (NODES + 1023) / 1024;
    int t0 = tid * CH;
    int t1 = t0 + CH; if (t1 > NODES) t1 = NODES;
    int sum = 0;
    for (int i = t0; i < t1; i++) sum += (int)deg[i] + 1;
    int x = sum;
#pragma unroll
    for (int off = 1; off < 64; off <<= 1) {
        int t = __shfl_up(x, off, 64);
        if (lane >= off) x += t;
    }
    if (lane == 63) wsum[wv] = x;
    __syncthreads();
    if (tid < 16) {
        int y = wsum[tid];
#pragma unroll
        for (int off = 1; off < 16; off <<= 1) {
            int t = __shfl_up(y, off, 16);
            if (tid >= off) y += t;
        }
        wsum[tid] = y;
    }
    __syncthreads();
    int run = x - sum + (wv ? wsum[wv - 1] : 0);
    for (int i = t0; i < t1; i++) {
        start[i] = run; cursor[i] = run;
        run += (int)deg[i] + 1;
    }
    if (tid == 1023) start[NODES] = wsum[15];
}

__global__ __launch_bounds__(256) void k_csr(
    const int* __restrict__ eidx, const float* __restrict__ eattr,
    int* __restrict__ cursor,
    int* __restrict__ row_sorted, float* __restrict__ ea_sorted) {
    int e = blockIdx.x * blockDim.x + threadIdx.x;
    if (e >= ETOT) return;
    int r, ci; float ea;
    if (e < NEDGES) { r = eidx[e]; ci = eidx[NEDGES + e]; ea = eattr[e]; }
    else            { r = ci = e - NEDGES; ea = 0.0f; }
    int slot = atomicAdd(&cursor[ci], 1);
    row_sorted[slot] = r;
    ea_sorted[slot] = ea;
}

// fragment-ordered f16 weight buffers.
// WcatF: K=256, 24 col-tiles ordered per-wave [z0,z1,r0,r1,p0,p1] (wave wv owns tiles wv*6..+5)
// WhtopF: K=128 -> 128 cols; Wg1F: K=128 -> 64 (A|B); Wf1F: K=256 -> 128
__global__ __launch_bounds__(256) void k_prep_w(
    const float* __restrict__ Wz, const float* __restrict__ Wr, const float* __restrict__ Wh,
    const float* __restrict__ Wg1, const float* __restrict__ Wf1,
    f16* __restrict__ WcatF, f16* __restrict__ WhtopF, f16* __restrict__ Wg1F,
    f16* __restrict__ Wf1F) {
    int t = blockIdx.x * 256 + threadIdx.x;
    int l = t & 63;
    int lr = l & 15, lh = l >> 4;
    if (t < 24 * 8 * 64) {
        int idx = t >> 6; int nt = idx >> 3, ks = idx & 7;
        int wv = nt / 6, ntl = nt % 6;
        int grp = ntl >> 1, pr = ntl & 1;
        int ncol = (2 * wv + pr) * 16 + lr;
        f16x8 v;
#pragma unroll
        for (int j = 0; j < 8; j++) {
            int k = ks * 32 + lh * 8 + j;
            float x;
            if (grp == 0)      x = Wz[k * 128 + ncol];
            else if (grp == 1) x = Wr[k * 128 + ncol];
            else               x = (k >= 128) ? Wh[k * 128 + ncol] : 0.0f;
            v[j] = (f16)x;
        }
        *(f16x8*)(WcatF + (size_t)t * 8) = v;
    } else if (t < 24 * 8 * 64 + 8 * 4 * 64) {
        int t2 = t - 24 * 8 * 64;
        int idx = t2 >> 6; int nt = idx >> 2, ks = idx & 3;
        int n = nt * 16 + lr;
        f16x8 v;
#pragma unroll
        for (int j = 0; j < 8; j++) {
            int k = ks * 32 + lh * 8 + j;
            v[j] = (f16)Wh[k * 128 + n];
        }
        *(f16x8*)(WhtopF + (size_t)t2 * 8) = v;
    } else if (t < 24 * 8 * 64 + 8 * 4 * 64 + 4 * 4 * 64) {
        int t3 = t - (24 * 8 * 64 + 8 * 4 * 64);
        int idx = t3 >> 6; int nt = idx >> 2, ks = idx & 3;
        int cg = nt * 16 + lr;
        f16x8 v;
#pragma unroll
        for (int j = 0; j < 8; j++) {
            int k = ks * 32 + lh * 8 + j;
            v[j] = (f16)((cg < 32) ? Wg1[k * GH + cg] : Wg1[(128 + k) * GH + (cg - 32)]);
        }
        *(f16x8*)(Wg1F + (size_t)t3 * 8) = v;
    } else if (t < 24 * 8 * 64 + 8 * 4 * 64 + 4 * 4 * 64 + 8 * 8 * 64) {
        int t4 = t - (24 * 8 * 64 + 8 * 4 * 64 + 4 * 4 * 64);
        int idx = t4 >> 6; int nt = idx >> 3, ks = idx & 7;
        int n = nt * 16 + lr;
        f16x8 v;
#pragma unroll
        for (int j = 0; j < 8; j++) {
            int k = ks * 32 + lh * 8 + j;
            v[j] = (f16)Wf1[k * 128 + n];
        }
        *(f16x8*)(Wf1F + (size_t)t4 * 8) = v;
    }
}

// h = relu(x@W_pre+b_pre); h0_16 = (f16)relu(h@W_init+b_init); h = same (f32)
__global__ __launch_bounds__(256) void k_preproc(
    const float* __restrict__ x, const float* __restrict__ Wpre, const float* __restrict__ bpre,
    const float* __restrict__ Winit, const float* __restrict__ binit,
    f16* __restrict__ h0_16, float* __restrict__ h) {
    __shared__ float sWpre[FIN * PRE], sbpre[PRE], sWinit[PRE * C], sbinit[C];
    for (int i = threadIdx.x; i < FIN * PRE; i += blockDim.x) sWpre[i] = Wpre[i];
    for (int i = threadIdx.x; i < PRE; i += blockDim.x) sbpre[i] = bpre[i];
    for (int i = threadIdx.x; i < PRE * C; i += blockDim.x) sWinit[i] = Winit[i];
    for (int i = threadIdx.x; i < C; i += blockDim.x) sbinit[i] = binit[i];
    __syncthreads();
    int n = blockIdx.x * blockDim.x + threadIdx.x;
    if (n >= NODES) return;
    float xv[FIN];
#pragma unroll
    for (int i = 0; i < FIN; i++) xv[i] = x[n * FIN + i];
    float pre[PRE];
#pragma unroll
    for (int k = 0; k < PRE; k++) {
        float a = sbpre[k];
#pragma unroll
        for (int i = 0; i < FIN; i++) a = fmaf(xv[i], sWpre[i * PRE + k], a);
        pre[k] = fmaxf(a, 0.0f);
    }
    for (int k = 0; k < C; k++) {
        float a = sbinit[k];
#pragma unroll
        for (int j = 0; j < PRE; j++) a = fmaf(pre[j], sWinit[j * C + k], a);
        a = fmaxf(a, 0.0f);
        h0_16[(size_t)n * C + k] = (f16)a;
        h[(size_t)n * C + k] = a;
    }
}

// layer-0: A f32 (bg1 folded), rec0 = {B16 | h16}. One wave per node.
__global__ __launch_bounds__(256) void k_gateAB(
    const float* __restrict__ h, const float* __restrict__ Wg1, const float* __restrict__ bg1,
    float* __restrict__ A, f16* __restrict__ rec) {
    int wave = (blockIdx.x * blockDim.x + threadIdx.x) >> 6;
    int lane = threadIdx.x & 63;
    if (wave >= NODES) return;
    int k = lane & 31;
    const float* W = Wg1 + ((lane < 32) ? 0 : C * GH);
    const float* hrow = h + (size_t)wave * C;
    float acc = (lane < 32) ? bg1[k] : 0.0f;
#pragma unroll 8
    for (int c = 0; c < C; c++) acc = fmaf(hrow[c], W[c * GH + k], acc);
    f16* rw = rec + (size_t)wave * RECS;
    if (lane < 32) A[(size_t)wave * GH + k] = acc;
    else           rw[k] = (f16)acc;
    float2 hv = *(const float2*)(hrow + lane * 2);
    rw[32 + lane * 2] = (f16)hv.x;
    rw[33 + lane * 2] = (f16)hv.y;
}

// fused gate+aggregate: wave per node; gathers one 320B record per edge
__global__ __launch_bounds__(256) void k_msg(
    const int* __restrict__ start, const int* __restrict__ row_sorted,
    const float* __restrict__ ea_sorted, const float* __restrict__ dis,
    const float* __restrict__ A, const f16* __restrict__ rec,
    const float* __restrict__ Wg1, const float* __restrict__ Wg2, const float* __restrict__ bg2,
    f16* __restrict__ aggr16) {
    int wid = (blockIdx.x * blockDim.x + threadIdx.x) >> 6;
    int lane = threadIdx.x & 63;
    if (wid >= NODES) return;
    int k = lane & 31;
    int s0 = start[wid], s1 = start[wid + 1];
    float a_reg = A[(size_t)wid * GH + k];
    float w_ea = Wg1[2 * C * GH + k];
    float wg2v = Wg2[k];
    float b2 = bg2[0];
    float dci = dis[wid];
    float2 acc = make_float2(0.0f, 0.0f);
#pragma unroll 2
    for (int s = s0; s < s1; s++) {
        int r = row_sorted[s];
        float ea = ea_sorted[s];
        const f16* rr = rec + (size_t)r * RECS;
        float dr = dis[r];
        f16x2 hv = *(const f16x2*)(rr + 32 + lane * 2);
        float t = fmaxf(a_reg + (float)rr[k] + ea * w_ea, 0.0f);
        float p = t * wg2v;
#pragma unroll
        for (int m = 16; m > 0; m >>= 1) p += __shfl_xor(p, m, 32);
        float coef = sigmoidf_(p + b2) * dr * dci;
        acc.x = fmaf(coef, (float)hv[0], acc.x);
        acc.y = fmaf(coef, (float)hv[1], acc.y);
    }
    f16x2 o; o[0] = (f16)acc.x; o[1] = (f16)acc.y;
    *(f16x2*)(aggr16 + (size_t)wid * C + lane * 2) = o;
}

// GRU update via MFMA; per-wave column-tile ownership keeps z,p in registers.
// Writes h(f32), rec[next] = {B16|h16}, A(f32).
__global__ __launch_bounds__(256) void k_update_mfma(
    float* __restrict__ h, const f16* __restrict__ aggr16,
    const f16* __restrict__ recC, f16* __restrict__ recN,
    const f16* __restrict__ WcatF, const f16* __restrict__ WhtopF, const f16* __restrict__ Wg1F,
    const float* __restrict__ bz, const float* __restrict__ br, const float* __restrict__ bh,
    const float* __restrict__ bg1,
    float* __restrict__ A) {
    __shared__ f16 za[32 * 256];    // swizzled, row stride 512B; reused for h_new staging
    __shared__ f16 rhbuf[32 * 128]; // swizzled, row stride 256B
    char* zaB = (char*)za;
    char* rhB = (char*)rhbuf;
    int tid = threadIdx.x;
    int l = tid & 63, w = tid >> 6;
    int lr = l & 15, lh = l >> 4;
    int n0 = blockIdx.x * 32;

    // stage za = [h16 | aggr16]
    for (int p = tid; p < 32 * 32; p += 256) {
        int row = p >> 5, seg = p & 31;
        int gn = n0 + row;
        f16x8 v;
#pragma unroll
        for (int j = 0; j < 8; j++) v[j] = (f16)0.0f;
        if (gn < NODES)
            v = (seg < 16) ? *(const f16x8*)(recC + (size_t)gn * RECS + 32 + seg * 8)
                           : *(const f16x8*)(aggr16 + (size_t)gn * C + (seg - 16) * 8);
        *(f16x8*)(zaB + swz_off(row, seg * 16, 512)) = v;
    }
    __syncthreads();

    // GEMM1: tiles [z0,z1,r0,r1,p0,p1] per wave
    f32x4 acc[2][6];
#pragma unroll
    for (int rt = 0; rt < 2; rt++)
#pragma unroll
        for (int n = 0; n < 6; n++)
#pragma unroll
            for (int j = 0; j < 4; j++) acc[rt][n][j] = 0.0f;
#pragma unroll
    for (int ks = 0; ks < 8; ks++) {
        int kk = ks * 32 + lh * 8;
        f16x8 a0 = *(const f16x8*)(zaB + swz_off(lr,      kk * 2, 512));
        f16x8 a1 = *(const f16x8*)(zaB + swz_off(lr + 16, kk * 2, 512));
#pragma unroll
        for (int ntl = 0; ntl < 6; ntl++) {
            f16x8 b = *(const f16x8*)(WcatF + ((size_t)((w * 6 + ntl) * 8 + ks) * 64 + l) * 8);
            acc[0][ntl] = __builtin_amdgcn_mfma_f32_16x16x32_f16(a0, b, acc[0][ntl], 0, 0, 0);
            acc[1][ntl] = __builtin_amdgcn_mfma_f32_16x16x32_f16(a1, b, acc[1][ntl], 0, 0, 0);
        }
    }

    // epilogue1: z->reg (sigmoid), r*h16 -> rhbuf, p stays in acc[rt][4/5]
    float zreg[2][2][4];
#pragma unroll
    for (int rt = 0; rt < 2; rt++)
#pragma unroll
        for (int pr = 0; pr < 2; pr++) {
            int cg = (2 * w + pr) * 16 + lr;
#pragma unroll
            for (int j = 0; j < 4; j++) {
                int row = rt * 16 + lh * 4 + j;
                int gn = n0 + row;
                zreg[rt][pr][j] = sigmoidf_(acc[rt][pr][j] + bz[cg]);
                float rv = sigmoidf_(acc[rt][2 + pr][j] + br[cg]);
                float hv = (gn < NODES) ? (float)recC[(size_t)gn * RECS + 32 + cg] : 0.0f;
                *(f16*)(rhB + swz_off(row, cg * 2, 256)) = (f16)(rv * hv);
            }
        }
    __syncthreads();

    // GEMM2: hc_pre = p + bh + (r*h) @ Wh_top
    f32x4 acc2[2][2];
#pragma unroll
    for (int rt = 0; rt < 2; rt++)
#pragma unroll
        for (int pr = 0; pr < 2; pr++) {
            int cg = (2 * w + pr) * 16 + lr;
#pragma unroll
            for (int j = 0; j < 4; j++)
                acc2[rt][pr][j] = acc[rt][4 + pr][j] + bh[cg];
        }
#pragma unroll
    for (int ks = 0; ks < 4; ks++) {
        int kk = ks * 32 + lh * 8;
        f16x8 a0 = *(const f16x8*)(rhB + swz_off(lr,      kk * 2, 256));
        f16x8 a1 = *(const f16x8*)(rhB + swz_off(lr + 16, kk * 2, 256));
#pragma unroll
        for (int pr = 0; pr < 2; pr++) {
            f16x8 b = *(const f16x8*)(WhtopF + ((size_t)((w * 2 + pr) * 4 + ks) * 64 + l) * 8);
            acc2[0][pr] = __builtin_amdgcn_mfma_f32_16x16x32_f16(a0, b, acc2[0][pr], 0, 0, 0);
            acc2[1][pr] = __builtin_amdgcn_mfma_f32_16x16x32_f16(a1, b, acc2[1][pr], 0, 0, 0);
        }
    }

    // epilogue2: h_new; write h f32 + rec[next] h16; stage h_new into za for GEMM3
#pragma unroll
    for (int rt = 0; rt < 2; rt++)
#pragma unroll
        for (int pr = 0; pr < 2; pr++) {
            int cg = (2 * w + pr) * 16 + lr;
#pragma unroll
            for (int j = 0; j < 4; j++) {
                int row = rt * 16 + lh * 4 + j;
                int gn = n0 + row;
                float hc = fmaxf(acc2[rt][pr][j], 0.0f);
                float z = zreg[rt][pr][j];
                float hold = (gn < NODES) ? h[(size_t)gn * C + cg] : 0.0f;
                float hn = (1.0f - z) * hold + z * hc;
                if (gn < NODES) {
                    h[(size_t)gn * C + cg] = hn;
                    recN[(size_t)gn * RECS + 32 + cg] = (f16)hn;
                }
                *(f16*)(zaB + swz_off(row, cg * 2, 512)) = (f16)hn;
            }
        }
    __syncthreads();

    // GEMM3: A|B16 = h_new @ Wg1F
    f32x4 acc3[2];
#pragma unroll
    for (int rt = 0; rt < 2; rt++)
#pragma unroll
        for (int j = 0; j < 4; j++) acc3[rt][j] = 0.0f;
#pragma unroll
    for (int ks = 0; ks < 4; ks++) {
        int kk = ks * 32 + lh * 8;
        f16x8 a0 = *(const f16x8*)(zaB + swz_off(lr,      kk * 2, 512));
        f16x8 a1 = *(const f16x8*)(zaB + swz_off(lr + 16, kk * 2, 512));
        f16x8 b = *(const f16x8*)(Wg1F + ((size_t)(w * 4 + ks) * 64 + l) * 8);
        acc3[0] = __builtin_amdgcn_mfma_f32_16x16x32_f16(a0, b, acc3[0], 0, 0, 0);
        acc3[1] = __builtin_amdgcn_mfma_f32_16x16x32_f16(a1, b, acc3[1], 0, 0, 0);
    }
    int col3 = w * 16 + lr;
#pragma unroll
    for (int rt = 0; rt < 2; rt++)
#pragma unroll
        for (int j = 0; j < 4; j++) {
            int row = rt * 16 + lh * 4 + j;
            int gn = n0 + row;
            if (gn < NODES) {
                float v = acc3[rt][j];
                if (col3 < 32) A[(size_t)gn * GH + col3] = v + bg1[col3];
                else           recN[(size_t)gn * RECS + (col3 - 32)] = (f16)v;
            }
        }
}

// final head via MFMA: f = relu([h0_16|h]@Wf1+bf1); out = f@Wf2+bf2
__global__ __launch_bounds__(256) void k_final_mfma(
    const f16* __restrict__ h0_16, const float* __restrict__ h,
    const f16* __restrict__ Wf1F, const float* __restrict__ bf1,
    const float* __restrict__ Wf2, const float* __restrict__ bf2,
    float* __restrict__ out) {
    __shared__ float fs[32][132];   // aliased during stage/GEMM as f16 za [32][256] swizzled
    char* zaB = (char*)&fs[0][0];
    int tid = threadIdx.x;
    int l = tid & 63, w = tid >> 6;
    int lr = l & 15, lh = l >> 4;
    int n0 = blockIdx.x * 32;

    for (int p = tid; p < 32 * 16; p += 256) {
        int row = p >> 4, seg = p & 15;
        int gn = n0 + row;
        f16x8 v;
#pragma unroll
        for (int j = 0; j < 8; j++) v[j] = (f16)0.0f;
        if (gn < NODES) v = *(const f16x8*)(h0_16 + (size_t)gn * C + seg * 8);
        *(f16x8*)(zaB + swz_off(row, seg * 16, 512)) = v;
    }
    for (int p = tid; p < 32 * 64; p += 256) {
        int row = p >> 6;
        int c2 = (p & 63) * 2;
        int gn = n0 + row;
        float2 hv = make_float2(0.0f, 0.0f);
        if (gn < NODES) hv = *(const float2*)&h[(size_t)gn * C + c2];
        f16x2 o; o[0] = (f16)hv.x; o[1] = (f16)hv.y;
        *(f16x2*)(zaB + swz_off(row, (128 + c2) * 2, 512)) = o;
    }
    __syncthreads();

    f32x4 acc[2][2];
#pragma unroll
    for (int rt = 0; rt < 2; rt++)
#pragma unroll
        for (int n = 0; n < 2; n++)
#pragma unroll
            for (int j = 0; j < 4; j++) acc[rt][n][j] = 0.0f;
#pragma unroll
    for (int ks = 0; ks < 8; ks++) {
        int kk = ks * 32 + lh * 8;
        f16x8 a0 = *(const f16x8*)(zaB + swz_off(lr,      kk * 2, 512));
        f16x8 a1 = *(const f16x8*)(zaB + swz_off(lr + 16, kk * 2, 512));
#pragma unroll
        for (int ntl = 0; ntl < 2; ntl++) {
            f16x8 b = *(const f16x8*)(Wf1F + ((size_t)((w * 2 + ntl) * 8 + ks) * 64 + l) * 8);
            acc[0][ntl] = __builtin_amdgcn_mfma_f32_16x16x32_f16(a0, b, acc[0][ntl], 0, 0, 0);
            acc[1][ntl] = __builtin_amdgcn_mfma_f32_16x16x32_f16(a1, b, acc[1][ntl], 0, 0, 0);
        }
    }
    __syncthreads();  // za reads done before fs overwrite

#pragma unroll
    for (int rt = 0; rt < 2; rt++)
#pragma unroll
        for (int ntl = 0; ntl < 2; ntl++) {
            int cg = (w * 2 + ntl) * 16 + lr;
#pragma unroll
            for (int j = 0; j < 4; j++) {
                int row = rt * 16 + lh * 4 + j;
                fs[row][cg] = fmaxf(acc[rt][ntl][j] + bf1[cg], 0.0f);
            }
        }
    __syncthreads();

    if (tid < 64) {
        int n = tid >> 1, o = tid & 1;
        int gn = n0 + n;
        if (gn < NODES) {
            float a = bf2[o];
#pragma unroll 16
            for (int c = 0; c < C; c++) a = fmaf(fs[n][c], Wf2[c * 2 + o], a);
            out[(size_t)gn * 2 + o] = a;
        }
    }
}

extern "C" void kernel_launch(void* const* d_in, const int* in_sizes, int n_in,
                              void* d_out, int out_size, void* d_ws, size_t ws_size,
                              hipStream_t stream) {
    const float* x    = (const float*)d_in[0];
    const int*   eidx = (const int*)d_in[1];
    const float* eattr= (const float*)d_in[2];
    const float* Wpre = (const float*)d_in[3];  const float* bpre = (const float*)d_in[4];
    const float* Winit= (const float*)d_in[5];  const float* binit= (const float*)d_in[6];
    const float* Wg1  = (const float*)d_in[7];  const float* bg1  = (const float*)d_in[8];
    const float* Wg2  = (const float*)d_in[9];  const float* bg2  = (const float*)d_in[10];
    const float* Wz   = (const float*)d_in[11]; const float* bz   = (const float*)d_in[12];
    const float* Wr   = (const float*)d_in[13]; const float* br   = (const float*)d_in[14];
    const float* Wh   = (const float*)d_in[15]; const float* bh   = (const float*)d_in[16];
    const float* Wf1  = (const float*)d_in[17]; const float* bf1  = (const float*)d_in[18];
    const float* Wf2  = (const float*)d_in[19]; const float* bf2  = (const float*)d_in[20];
    float* out = (float*)d_out;

    float* ws  = (float*)d_ws;
    float* dis = ws;                               // N
    float* h   = dis + NODES;                      // N*C f32
    float* A   = h + (size_t)NODES * C;            // N*GH f32
    int*   start = (int*)(A + (size_t)NODES * GH);     // N+1
    int*   cursor = start + NODES + 1;                 // N+1
    int*   row_sorted = cursor + NODES + 1;            // ETOT
    float* ea_sorted  = (float*)(row_sorted + ETOT);   // ETOT
    size_t f16_base = (size_t)((ea_sorted + ETOT) - ws);
    f16_base = (f16_base + 3) & ~(size_t)3;            // 16B align
    f16* h0_16  = (f16*)(ws + f16_base);               // N*C f16
    f16* rec0   = h0_16 + (size_t)NODES * C;           // N*RECS f16
    f16* rec1   = rec0 + (size_t)NODES * RECS;         // N*RECS f16
    f16* aggr16 = rec1 + (size_t)NODES * RECS;         // N*C f16
    f16* WcatF  = aggr16 + (size_t)NODES * C;          // 24*8*64*8 f16
    f16* WhtopF = WcatF + 24 * 8 * 64 * 8;
    f16* Wg1F   = WhtopF + 8 * 4 * 64 * 8;
    f16* Wf1F   = Wg1F + 4 * 4 * 64 * 8;
    size_t f16_total = (size_t)NODES * (C + 2 * RECS + C) + (24 * 8 + 8 * 4 + 4 * 4 + 8 * 8) * 64 * 8;
    const size_t REQ = (f16_base + (f16_total + 1) / 2) * sizeof(float);
    if (ws_size < REQ) return;

    hipMemsetAsync(dis, 0, NODES * sizeof(float), stream);
    k_degree<<<(NEDGES + 255) / 256, 256, 0, stream>>>(eidx + NEDGES, dis);
    k_scan<<<1, 1024, 0, stream>>>(dis, start, cursor);
    k_dis<<<(NODES + 255) / 256, 256, 0, stream>>>(dis);
    k_csr<<<(ETOT + 255) / 256, 256, 0, stream>>>(eidx, eattr, cursor, row_sorted, ea_sorted);
    k_prep_w<<<(24 * 8 * 64 + 8 * 4 * 64 + 4 * 4 * 64 + 8 * 8 * 64 + 255) / 256, 256, 0, stream>>>(
        Wz, Wr, Wh, Wg1, Wf1, WcatF, WhtopF, Wg1F, Wf1F);
    k_preproc<<<(NODES + 255) / 256, 256, 0, stream>>>(x, Wpre, bpre, Winit, binit, h0_16, h);
    k_gateAB<<<(NODES * 64 + 255) / 256, 256, 0, stream>>>(h, Wg1, bg1, A, rec0);

    for (int l = 0; l < LAYERS; l++) {
        f16* recC = (l & 1) ? rec1 : rec0;
        f16* recN = (l & 1) ? rec0 : rec1;
        k_msg<<<(NODES * 64 + 255) / 256, 256, 0, stream>>>(
            start, row_sorted, ea_sorted, dis, A, recC, Wg1, Wg2, bg2, aggr16);
        k_update_mfma<<<(NODES + 31) / 32, 256, 0, stream>>>(
            h, aggr16, recC, recN, WcatF, WhtopF, Wg1F, bz, br, bh, bg1, A);
    }
    k_final_mfma<<<(NODES + 31) / 32, 256, 0, stream>>>(h0_16, h, Wf1F, bf1, Wf2, bf2, out);
}

// Round 7
// 1034.153 us; speedup vs baseline: 8.8399x; 1.1997x over previous
//
#include <hip/hip_runtime.h>
#include <math.h>

#define NODES 50000
#define NEDGES 800000
#define ETOT (NEDGES + NODES)
#define FIN 16
#define PRE 32
#define C 128
#define GH 32
#define LAYERS 5
#define RECS 160   // f16 per node record: [B16:32 | hd16:128] where hd = dis[n]*h[n]

typedef _Float16 f16;
typedef f16 f16x8 __attribute__((ext_vector_type(8)));
typedef f16 f16x4 __attribute__((ext_vector_type(4)));
typedef f16 f16x2 __attribute__((ext_vector_type(2)));
typedef float f32x4 __attribute__((ext_vector_type(4)));

__device__ __forceinline__ float sigmoidf_(float x) { return 1.0f / (1.0f + __expf(-x)); }

// XOR-swizzled LDS byte offset: 16B-block index ^= (row&7)
__device__ __forceinline__ int swz_off(int row, int bytecol, int stride) {
    return row * stride + ((((bytecol) >> 4) ^ (row & 7)) << 4) + (bytecol & 15);
}

__global__ void k_degree(const int* __restrict__ col, float* __restrict__ deg) {
    int e = blockIdx.x * blockDim.x + threadIdx.x;
    if (e < NEDGES) atomicAdd(&deg[col[e]], 1.0f);
}

__global__ void k_dis(float* __restrict__ deg_dis) {
    int i = blockIdx.x * blockDim.x + threadIdx.x;
    if (i < NODES) deg_dis[i] = rsqrtf(deg_dis[i] + 1.0f);
}

// single-block scan: serial per-thread chunks + shfl block scan (2 barriers)
__global__ __launch_bounds__(1024) void k_scan(
    const float* __restrict__ deg, int* __restrict__ start, int* __restrict__ cursor) {
    __shared__ int wsum[16];
    int tid = threadIdx.x;
    int lane = tid & 63, wv = tid >> 6;
    const int CH = (NODES + 1023) / 1024;
    int t0 = tid * CH;
    int t1 = t0 + CH; if (t1 > NODES) t1 = NODES;
    int sum = 0;
    for (int i = t0; i < t1; i++) sum += (int)deg[i] + 1;
    int x = sum;
#pragma unroll
    for (int off = 1; off < 64; off <<= 1) {
        int t = __shfl_up(x, off, 64);
        if (lane >= off) x += t;
    }
    if (lane == 63) wsum[wv] = x;
    __syncthreads();
    if (tid < 16) {
        int y = wsum[tid];
#pragma unroll
        for (int off = 1; off < 16; off <<= 1) {
            int t = __shfl_up(y, off, 16);
            if (tid >= off) y += t;
        }
        wsum[tid] = y;
    }
    __syncthreads();
    int run = x - sum + (wv ? wsum[wv - 1] : 0);
    for (int i = t0; i < t1; i++) {
        start[i] = run; cursor[i] = run;
        run += (int)deg[i] + 1;
    }
    if (tid == 1023) start[NODES] = wsum[15];
}

__global__ __launch_bounds__(256) void k_csr(
    const int* __restrict__ eidx, const float* __restrict__ eattr,
    int* __restrict__ cursor,
    int* __restrict__ row_sorted, float* __restrict__ ea_sorted) {
    int e = blockIdx.x * blockDim.x + threadIdx.x;
    if (e >= ETOT) return;
    int r, ci; float ea;
    if (e < NEDGES) { r = eidx[e]; ci = eidx[NEDGES + e]; ea = eattr[e]; }
    else            { r = ci = e - NEDGES; ea = 0.0f; }
    int slot = atomicAdd(&cursor[ci], 1);
    row_sorted[slot] = r;
    ea_sorted[slot] = ea;
}

// fragment-ordered f16 weight buffers.
// WcatF: K=256, 24 col-tiles ordered per-wave [z0,z1,r0,r1,p0,p1] (wave wv owns tiles wv*6..+5)
// WhtopF: K=128 -> 128 cols; Wg1F: K=128 -> 64 (A|B); Wf1F: K=256 -> 128
__global__ __launch_bounds__(256) void k_prep_w(
    const float* __restrict__ Wz, const float* __restrict__ Wr, const float* __restrict__ Wh,
    const float* __restrict__ Wg1, const float* __restrict__ Wf1,
    f16* __restrict__ WcatF, f16* __restrict__ WhtopF, f16* __restrict__ Wg1F,
    f16* __restrict__ Wf1F) {
    int t = blockIdx.x * 256 + threadIdx.x;
    int l = t & 63;
    int lr = l & 15, lh = l >> 4;
    if (t < 24 * 8 * 64) {
        int idx = t >> 6; int nt = idx >> 3, ks = idx & 7;
        int wv = nt / 6, ntl = nt % 6;
        int grp = ntl >> 1, pr = ntl & 1;
        int ncol = (2 * wv + pr) * 16 + lr;
        f16x8 v;
#pragma unroll
        for (int j = 0; j < 8; j++) {
            int k = ks * 32 + lh * 8 + j;
            float x;
            if (grp == 0)      x = Wz[k * 128 + ncol];
            else if (grp == 1) x = Wr[k * 128 + ncol];
            else               x = (k >= 128) ? Wh[k * 128 + ncol] : 0.0f;
            v[j] = (f16)x;
        }
        *(f16x8*)(WcatF + (size_t)t * 8) = v;
    } else if (t < 24 * 8 * 64 + 8 * 4 * 64) {
        int t2 = t - 24 * 8 * 64;
        int idx = t2 >> 6; int nt = idx >> 2, ks = idx & 3;
        int n = nt * 16 + lr;
        f16x8 v;
#pragma unroll
        for (int j = 0; j < 8; j++) {
            int k = ks * 32 + lh * 8 + j;
            v[j] = (f16)Wh[k * 128 + n];
        }
        *(f16x8*)(WhtopF + (size_t)t2 * 8) = v;
    } else if (t < 24 * 8 * 64 + 8 * 4 * 64 + 4 * 4 * 64) {
        int t3 = t - (24 * 8 * 64 + 8 * 4 * 64);
        int idx = t3 >> 6; int nt = idx >> 2, ks = idx & 3;
        int cg = nt * 16 + lr;
        f16x8 v;
#pragma unroll
        for (int j = 0; j < 8; j++) {
            int k = ks * 32 + lh * 8 + j;
            v[j] = (f16)((cg < 32) ? Wg1[k * GH + cg] : Wg1[(128 + k) * GH + (cg - 32)]);
        }
        *(f16x8*)(Wg1F + (size_t)t3 * 8) = v;
    } else if (t < 24 * 8 * 64 + 8 * 4 * 64 + 4 * 4 * 64 + 8 * 8 * 64) {
        int t4 = t - (24 * 8 * 64 + 8 * 4 * 64 + 4 * 4 * 64);
        int idx = t4 >> 6; int nt = idx >> 3, ks = idx & 7;
        int n = nt * 16 + lr;
        f16x8 v;
#pragma unroll
        for (int j = 0; j < 8; j++) {
            int k = ks * 32 + lh * 8 + j;
            v[j] = (f16)Wf1[k * 128 + n];
        }
        *(f16x8*)(Wf1F + (size_t)t4 * 8) = v;
    }
}

// h = relu(x@W_pre+b_pre); h0_16 = (f16)relu(h@W_init+b_init); h = same (f32)
__global__ __launch_bounds__(256) void k_preproc(
    const float* __restrict__ x, const float* __restrict__ Wpre, const float* __restrict__ bpre,
    const float* __restrict__ Winit, const float* __restrict__ binit,
    f16* __restrict__ h0_16, float* __restrict__ h) {
    __shared__ float sWpre[FIN * PRE], sbpre[PRE], sWinit[PRE * C], sbinit[C];
    for (int i = threadIdx.x; i < FIN * PRE; i += blockDim.x) sWpre[i] = Wpre[i];
    for (int i = threadIdx.x; i < PRE; i += blockDim.x) sbpre[i] = bpre[i];
    for (int i = threadIdx.x; i < PRE * C; i += blockDim.x) sWinit[i] = Winit[i];
    for (int i = threadIdx.x; i < C; i += blockDim.x) sbinit[i] = binit[i];
    __syncthreads();
    int n = blockIdx.x * blockDim.x + threadIdx.x;
    if (n >= NODES) return;
    float xv[FIN];
#pragma unroll
    for (int i = 0; i < FIN; i++) xv[i] = x[n * FIN + i];
    float pre[PRE];
#pragma unroll
    for (int k = 0; k < PRE; k++) {
        float a = sbpre[k];
#pragma unroll
        for (int i = 0; i < FIN; i++) a = fmaf(xv[i], sWpre[i * PRE + k], a);
        pre[k] = fmaxf(a, 0.0f);
    }
    for (int k = 0; k < C; k++) {
        float a = sbinit[k];
#pragma unroll
        for (int j = 0; j < PRE; j++) a = fmaf(pre[j], sWinit[j * C + k], a);
        a = fmaxf(a, 0.0f);
        h0_16[(size_t)n * C + k] = (f16)a;
        h[(size_t)n * C + k] = a;
    }
}

// layer-0: A f32 (bg1 folded), rec = {B16 | hd16 = dis*h}. One wave per node.
__global__ __launch_bounds__(256) void k_gateAB(
    const float* __restrict__ h, const float* __restrict__ dis,
    const float* __restrict__ Wg1, const float* __restrict__ bg1,
    float* __restrict__ A, f16* __restrict__ rec) {
    int wave = (blockIdx.x * blockDim.x + threadIdx.x) >> 6;
    int lane = threadIdx.x & 63;
    if (wave >= NODES) return;
    int k = lane & 31;
    const float* W = Wg1 + ((lane < 32) ? 0 : C * GH);
    const float* hrow = h + (size_t)wave * C;
    float acc = (lane < 32) ? bg1[k] : 0.0f;
#pragma unroll 8
    for (int c = 0; c < C; c++) acc = fmaf(hrow[c], W[c * GH + k], acc);
    f16* rw = rec + (size_t)wave * RECS;
    if (lane < 32) A[(size_t)wave * GH + k] = acc;
    else           rw[k] = (f16)acc;
    float dn = dis[wave];
    float2 hv = *(const float2*)(hrow + lane * 2);
    rw[32 + lane * 2] = (f16)(dn * hv.x);
    rw[33 + lane * 2] = (f16)(dn * hv.y);
}

// fused gate+aggregate: wave per node, HALF-WAVE per edge.
// lanes 0-31 process even CSR slots, lanes 32-63 odd slots; each half gathers
// its edge's full 128-ch hd row (f16x4/lane) and computes its own gate.
__global__ __launch_bounds__(256) void k_msg(
    const int* __restrict__ start, const int* __restrict__ row_sorted,
    const float* __restrict__ ea_sorted, const float* __restrict__ dis,
    const float* __restrict__ A, const f16* __restrict__ rec,
    const float* __restrict__ Wg1, const float* __restrict__ Wg2, const float* __restrict__ bg2,
    f16* __restrict__ aggr16) {
    int wid = (blockIdx.x * blockDim.x + threadIdx.x) >> 6;
    int lane = threadIdx.x & 63;
    if (wid >= NODES) return;
    int k = lane & 31;
    int hh = lane >> 5;
    int s0 = start[wid], s1 = start[wid + 1];
    float a_reg = A[(size_t)wid * GH + k];
    float w_ea = Wg1[2 * C * GH + k];
    float wg2v = Wg2[k];
    float b2 = bg2[0];
    float dci = dis[wid];
    f32x4 acc; acc[0] = acc[1] = acc[2] = acc[3] = 0.0f;
#pragma unroll 2
    for (int s = s0 + hh; s < s1; s += 2) {
        int r = row_sorted[s];
        float ea = ea_sorted[s];
        const f16* rr = rec + (size_t)r * RECS;
        f16x4 hv = *(const f16x4*)(rr + 32 + k * 4);       // channels [4k,4k+4), dis[r]-scaled
        float t = fmaxf(a_reg + (float)rr[k] + ea * w_ea, 0.0f);
        float p = t * wg2v;
#pragma unroll
        for (int m = 16; m > 0; m >>= 1) p += __shfl_xor(p, m, 32);
        float coef = sigmoidf_(p + b2) * dci;
        acc[0] = fmaf(coef, (float)hv[0], acc[0]);
        acc[1] = fmaf(coef, (float)hv[1], acc[1]);
        acc[2] = fmaf(coef, (float)hv[2], acc[2]);
        acc[3] = fmaf(coef, (float)hv[3], acc[3]);
    }
#pragma unroll
    for (int j = 0; j < 4; j++) acc[j] += __shfl_xor(acc[j], 32, 64);
    if (hh == 0) {
        f16x4 o;
        o[0] = (f16)acc[0]; o[1] = (f16)acc[1]; o[2] = (f16)acc[2]; o[3] = (f16)acc[3];
        *(f16x4*)(aggr16 + (size_t)wid * C + k * 4) = o;
    }
}

// GRU update via MFMA; per-wave column-tile ownership keeps z,p in registers.
// Reads h f32 + aggr16; writes h f32, rec = {B16|hd16}, A f32.
__global__ __launch_bounds__(256) void k_update_mfma(
    float* __restrict__ h, const f16* __restrict__ aggr16, const float* __restrict__ dis,
    f16* __restrict__ rec,
    const f16* __restrict__ WcatF, const f16* __restrict__ WhtopF, const f16* __restrict__ Wg1F,
    const float* __restrict__ bz, const float* __restrict__ br, const float* __restrict__ bh,
    const float* __restrict__ bg1,
    float* __restrict__ A) {
    __shared__ f16 za[32 * 256];    // swizzled, row stride 512B; reused for h_new staging
    __shared__ f16 rhbuf[32 * 128]; // swizzled, row stride 256B
    char* zaB = (char*)za;
    char* rhB = (char*)rhbuf;
    int tid = threadIdx.x;
    int l = tid & 63, w = tid >> 6;
    int lr = l & 15, lh = l >> 4;
    int n0 = blockIdx.x * 32;

    // stage za = [(f16)h | aggr16]
    for (int p = tid; p < 32 * 64; p += 256) {
        int row = p >> 6;
        int c2 = (p & 63) * 2;
        int gn = n0 + row;
        float2 v = make_float2(0.0f, 0.0f);
        if (gn < NODES) v = *(const float2*)&h[(size_t)gn * C + c2];
        f16x2 o; o[0] = (f16)v.x; o[1] = (f16)v.y;
        *(f16x2*)(zaB + swz_off(row, c2 * 2, 512)) = o;
    }
    for (int p = tid; p < 32 * 16; p += 256) {
        int row = p >> 4, seg = p & 15;
        int gn = n0 + row;
        f16x8 v;
#pragma unroll
        for (int j = 0; j < 8; j++) v[j] = (f16)0.0f;
        if (gn < NODES) v = *(const f16x8*)(aggr16 + (size_t)gn * C + seg * 8);
        *(f16x8*)(zaB + swz_off(row, 256 + seg * 16, 512)) = v;
    }
    __syncthreads();

    // GEMM1: tiles [z0,z1,r0,r1,p0,p1] per wave
    f32x4 acc[2][6];
#pragma unroll
    for (int rt = 0; rt < 2; rt++)
#pragma unroll
        for (int n = 0; n < 6; n++)
#pragma unroll
            for (int j = 0; j < 4; j++) acc[rt][n][j] = 0.0f;
#pragma unroll
    for (int ks = 0; ks < 8; ks++) {
        int kk = ks * 32 + lh * 8;
        f16x8 a0 = *(const f16x8*)(zaB + swz_off(lr,      kk * 2, 512));
        f16x8 a1 = *(const f16x8*)(zaB + swz_off(lr + 16, kk * 2, 512));
#pragma unroll
        for (int ntl = 0; ntl < 6; ntl++) {
            f16x8 b = *(const f16x8*)(WcatF + ((size_t)((w * 6 + ntl) * 8 + ks) * 64 + l) * 8);
            acc[0][ntl] = __builtin_amdgcn_mfma_f32_16x16x32_f16(a0, b, acc[0][ntl], 0, 0, 0);
            acc[1][ntl] = __builtin_amdgcn_mfma_f32_16x16x32_f16(a1, b, acc[1][ntl], 0, 0, 0);
        }
    }

    // epilogue1: z->reg (sigmoid), r*h -> rhbuf, p stays in acc[rt][4/5]
    float zreg[2][2][4];
#pragma unroll
    for (int rt = 0; rt < 2; rt++)
#pragma unroll
        for (int pr = 0; pr < 2; pr++) {
            int cg = (2 * w + pr) * 16 + lr;
#pragma unroll
            for (int j = 0; j < 4; j++) {
                int row = rt * 16 + lh * 4 + j;
                int gn = n0 + row;
                zreg[rt][pr][j] = sigmoidf_(acc[rt][pr][j] + bz[cg]);
                float rv = sigmoidf_(acc[rt][2 + pr][j] + br[cg]);
                float hv = (gn < NODES) ? h[(size_t)gn * C + cg] : 0.0f;
                *(f16*)(rhB + swz_off(row, cg * 2, 256)) = (f16)(rv * hv);
            }
        }
    __syncthreads();

    // GEMM2: hc_pre = p + bh + (r*h) @ Wh_top
    f32x4 acc2[2][2];
#pragma unroll
    for (int rt = 0; rt < 2; rt++)
#pragma unroll
        for (int pr = 0; pr < 2; pr++) {
            int cg = (2 * w + pr) * 16 + lr;
#pragma unroll
            for (int j = 0; j < 4; j++)
                acc2[rt][pr][j] = acc[rt][4 + pr][j] + bh[cg];
        }
#pragma unroll
    for (int ks = 0; ks < 4; ks++) {
        int kk = ks * 32 + lh * 8;
        f16x8 a0 = *(const f16x8*)(rhB + swz_off(lr,      kk * 2, 256));
        f16x8 a1 = *(const f16x8*)(rhB + swz_off(lr + 16, kk * 2, 256));
#pragma unroll
        for (int pr = 0; pr < 2; pr++) {
            f16x8 b = *(const f16x8*)(WhtopF + ((size_t)((w * 2 + pr) * 4 + ks) * 64 + l) * 8);
            acc2[0][pr] = __builtin_amdgcn_mfma_f32_16x16x32_f16(a0, b, acc2[0][pr], 0, 0, 0);
            acc2[1][pr] = __builtin_amdgcn_mfma_f32_16x16x32_f16(a1, b, acc2[1][pr], 0, 0, 0);
        }
    }

    // epilogue2: h_new; write h f32 + rec hd16 (dis-scaled); stage h_new into za for GEMM3
#pragma unroll
    for (int rt = 0; rt < 2; rt++)
#pragma unroll
        for (int pr = 0; pr < 2; pr++) {
            int cg = (2 * w + pr) * 16 + lr;
#pragma unroll
            for (int j = 0; j < 4; j++) {
                int row = rt * 16 + lh * 4 + j;
                int gn = n0 + row;
                float hc = fmaxf(acc2[rt][pr][j], 0.0f);
                float z = zreg[rt][pr][j];
                float hold = (gn < NODES) ? h[(size_t)gn * C + cg] : 0.0f;
                float hn = (1.0f - z) * hold + z * hc;
                if (gn < NODES) {
                    h[(size_t)gn * C + cg] = hn;
                    rec[(size_t)gn * RECS + 32 + cg] = (f16)(hn * dis[gn]);
                }
                *(f16*)(zaB + swz_off(row, cg * 2, 512)) = (f16)hn;
            }
        }
    __syncthreads();

    // GEMM3: A|B16 = h_new @ Wg1F
    f32x4 acc3[2];
#pragma unroll
    for (int rt = 0; rt < 2; rt++)
#pragma unroll
        for (int j = 0; j < 4; j++) acc3[rt][j] = 0.0f;
#pragma unroll
    for (int ks = 0; ks < 4; ks++) {
        int kk = ks * 32 + lh * 8;
        f16x8 a0 = *(const f16x8*)(zaB + swz_off(lr,      kk * 2, 512));
        f16x8 a1 = *(const f16x8*)(zaB + swz_off(lr + 16, kk * 2, 512));
        f16x8 b = *(const f16x8*)(Wg1F + ((size_t)(w * 4 + ks) * 64 + l) * 8);
        acc3[0] = __builtin_amdgcn_mfma_f32_16x16x32_f16(a0, b, acc3[0], 0, 0, 0);
        acc3[1] = __builtin_amdgcn_mfma_f32_16x16x32_f16(a1, b, acc3[1], 0, 0, 0);
    }
    int col3 = w * 16 + lr;
#pragma unroll
    for (int rt = 0; rt < 2; rt++)
#pragma unroll
        for (int j = 0; j < 4; j++) {
            int row = rt * 16 + lh * 4 + j;
            int gn = n0 + row;
            if (gn < NODES) {
                float v = acc3[rt][j];
                if (col3 < 32) A[(size_t)gn * GH + col3] = v + bg1[col3];
                else           rec[(size_t)gn * RECS + (col3 - 32)] = (f16)v;
            }
        }
}

// final head via MFMA: f = relu([h0_16|h]@Wf1+bf1); out = f@Wf2+bf2
__global__ __launch_bounds__(256) void k_final_mfma(
    const f16* __restrict__ h0_16, const float* __restrict__ h,
    const f16* __restrict__ Wf1F, const float* __restrict__ bf1,
    const float* __restrict__ Wf2, const float* __restrict__ bf2,
    float* __restrict__ out) {
    __shared__ float fs[32][132];   // aliased during stage/GEMM as f16 za [32][256] swizzled
    char* zaB = (char*)&fs[0][0];
    int tid = threadIdx.x;
    int l = tid & 63, w = tid >> 6;
    int lr = l & 15, lh = l >> 4;
    int n0 = blockIdx.x * 32;

    for (int p = tid; p < 32 * 16; p += 256) {
        int row = p >> 4, seg = p & 15;
        int gn = n0 + row;
        f16x8 v;
#pragma unroll
        for (int j = 0; j < 8; j++) v[j] = (f16)0.0f;
        if (gn < NODES) v = *(const f16x8*)(h0_16 + (size_t)gn * C + seg * 8);
        *(f16x8*)(zaB + swz_off(row, seg * 16, 512)) = v;
    }
    for (int p = tid; p < 32 * 64; p += 256) {
        int row = p >> 6;
        int c2 = (p & 63) * 2;
        int gn = n0 + row;
        float2 hv = make_float2(0.0f, 0.0f);
        if (gn < NODES) hv = *(const float2*)&h[(size_t)gn * C + c2];
        f16x2 o; o[0] = (f16)hv.x; o[1] = (f16)hv.y;
        *(f16x2*)(zaB + swz_off(row, (128 + c2) * 2, 512)) = o;
    }
    __syncthreads();

    f32x4 acc[2][2];
#pragma unroll
    for (int rt = 0; rt < 2; rt++)
#pragma unroll
        for (int n = 0; n < 2; n++)
#pragma unroll
            for (int j = 0; j < 4; j++) acc[rt][n][j] = 0.0f;
#pragma unroll
    for (int ks = 0; ks < 8; ks++) {
        int kk = ks * 32 + lh * 8;
        f16x8 a0 = *(const f16x8*)(zaB + swz_off(lr,      kk * 2, 512));
        f16x8 a1 = *(const f16x8*)(zaB + swz_off(lr + 16, kk * 2, 512));
#pragma unroll
        for (int ntl = 0; ntl < 2; ntl++) {
            f16x8 b = *(const f16x8*)(Wf1F + ((size_t)((w * 2 + ntl) * 8 + ks) * 64 + l) * 8);
            acc[0][ntl] = __builtin_amdgcn_mfma_f32_16x16x32_f16(a0, b, acc[0][ntl], 0, 0, 0);
            acc[1][ntl] = __builtin_amdgcn_mfma_f32_16x16x32_f16(a1, b, acc[1][ntl], 0, 0, 0);
        }
    }
    __syncthreads();  // za reads done before fs overwrite

#pragma unroll
    for (int rt = 0; rt < 2; rt++)
#pragma unroll
        for (int ntl = 0; ntl < 2; ntl++) {
            int cg = (w * 2 + ntl) * 16 + lr;
#pragma unroll
            for (int j = 0; j < 4; j++) {
                int row = rt * 16 + lh * 4 + j;
                fs[row][cg] = fmaxf(acc[rt][ntl][j] + bf1[cg], 0.0f);
            }
        }
    __syncthreads();

    if (tid < 64) {
        int n = tid >> 1, o = tid & 1;
        int gn = n0 + n;
        if (gn < NODES) {
            float a = bf2[o];
#pragma unroll 16
            for (int c = 0; c < C; c++) a = fmaf(fs[n][c], Wf2[c * 2 + o], a);
            out[(size_t)gn * 2 + o] = a;
        }
    }
}

extern "C" void kernel_launch(void* const* d_in, const int* in_sizes, int n_in,
                              void* d_out, int out_size, void* d_ws, size_t ws_size,
                              hipStream_t stream) {
    const float* x    = (const float*)d_in[0];
    const int*   eidx = (const int*)d_in[1];
    const float* eattr= (const float*)d_in[2];
    const float* Wpre = (const float*)d_in[3];  const float* bpre = (const float*)d_in[4];
    const float* Winit= (const float*)d_in[5];  const float* binit= (const float*)d_in[6];
    const float* Wg1  = (const float*)d_in[7];  const float* bg1  = (const float*)d_in[8];
    const float* Wg2  = (const float*)d_in[9];  const float* bg2  = (const float*)d_in[10];
    const float* Wz   = (const float*)d_in[11]; const float* bz   = (const float*)d_in[12];
    const float* Wr   = (const float*)d_in[13]; const float* br   = (const float*)d_in[14];
    const float* Wh   = (const float*)d_in[15]; const float* bh   = (const float*)d_in[16];
    const float* Wf1  = (const float*)d_in[17]; const float* bf1  = (const float*)d_in[18];
    const float* Wf2  = (const float*)d_in[19]; const float* bf2  = (const float*)d_in[20];
    float* out = (float*)d_out;

    float* ws  = (float*)d_ws;
    float* dis = ws;                               // N
    float* h   = dis + NODES;                      // N*C f32
    float* A   = h + (size_t)NODES * C;            // N*GH f32
    int*   start = (int*)(A + (size_t)NODES * GH);     // N+1
    int*   cursor = start + NODES + 1;                 // N+1
    int*   row_sorted = cursor + NODES + 1;            // ETOT
    float* ea_sorted  = (float*)(row_sorted + ETOT);   // ETOT
    size_t f16_base = (size_t)((ea_sorted + ETOT) - ws);
    f16_base = (f16_base + 3) & ~(size_t)3;            // 16B align
    f16* h0_16  = (f16*)(ws + f16_base);               // N*C f16
    f16* rec    = h0_16 + (size_t)NODES * C;           // N*RECS f16
    f16* aggr16 = rec + (size_t)NODES * RECS;          // N*C f16
    f16* WcatF  = aggr16 + (size_t)NODES * C;          // 24*8*64*8 f16
    f16* WhtopF = WcatF + 24 * 8 * 64 * 8;
    f16* Wg1F   = WhtopF + 8 * 4 * 64 * 8;
    f16* Wf1F   = Wg1F + 4 * 4 * 64 * 8;
    size_t f16_total = (size_t)NODES * (C + RECS + C) + (24 * 8 + 8 * 4 + 4 * 4 + 8 * 8) * 64 * 8;
    const size_t REQ = (f16_base + (f16_total + 1) / 2) * sizeof(float);
    if (ws_size < REQ) return;

    hipMemsetAsync(dis, 0, NODES * sizeof(float), stream);
    k_degree<<<(NEDGES + 255) / 256, 256, 0, stream>>>(eidx + NEDGES, dis);
    k_scan<<<1, 1024, 0, stream>>>(dis, start, cursor);
    k_dis<<<(NODES + 255) / 256, 256, 0, stream>>>(dis);
    k_csr<<<(ETOT + 255) / 256, 256, 0, stream>>>(eidx, eattr, cursor, row_sorted, ea_sorted);
    k_prep_w<<<(24 * 8 * 64 + 8 * 4 * 64 + 4 * 4 * 64 + 8 * 8 * 64 + 255) / 256, 256, 0, stream>>>(
        Wz, Wr, Wh, Wg1, Wf1, WcatF, WhtopF, Wg1F, Wf1F);
    k_preproc<<<(NODES + 255) / 256, 256, 0, stream>>>(x, Wpre, bpre, Winit, binit, h0_16, h);
    k_gateAB<<<(NODES * 64 + 255) / 256, 256, 0, stream>>>(h, dis, Wg1, bg1, A, rec);

    for (int l = 0; l < LAYERS; l++) {
        k_msg<<<(NODES * 64 + 255) / 256, 256, 0, stream>>>(
            start, row_sorted, ea_sorted, dis, A, rec, Wg1, Wg2, bg2, aggr16);
        k_update_mfma<<<(NODES + 31) / 32, 256, 0, stream>>>(
            h, aggr16, dis, rec, WcatF, WhtopF, Wg1F, bz, br, bh, bg1, A);
    }
    k_final_mfma<<<(NODES + 31) / 32, 256, 0, stream>>>(h0_16, h, Wf1F, bf1, Wf2, bf2, out);
}

// Round 8
// 931.436 us; speedup vs baseline: 9.8148x; 1.1103x over previous
//
#include <hip/hip_runtime.h>
#include <math.h>

#define NODES 50000
#define NEDGES 800000
#define ETOT (NEDGES + NODES)
#define FIN 16
#define PRE 32
#define C 128
#define GH 32
#define LAYERS 5
#define RECS 160   // f16 per node record: [B16:32 | hd16:128] where hd = dis[n]*h[n]
#define SCB 64     // scan blocks
#define SCT 256    // scan threads/block
#define SCCH ((NODES + SCB*SCT - 1) / (SCB*SCT))   // elems per thread (=4)

typedef _Float16 f16;
typedef f16 f16x8 __attribute__((ext_vector_type(8)));
typedef f16 f16x4 __attribute__((ext_vector_type(4)));
typedef f16 f16x2 __attribute__((ext_vector_type(2)));
typedef float f32x4 __attribute__((ext_vector_type(4)));

__device__ __forceinline__ float sigmoidf_(float x) { return 1.0f / (1.0f + __expf(-x)); }

// XOR-swizzled LDS byte offset: 16B-block index ^= (row&7)
__device__ __forceinline__ int swz_off(int row, int bytecol, int stride) {
    return row * stride + ((((bytecol) >> 4) ^ (row & 7)) << 4) + (bytecol & 15);
}

__global__ void k_degree(const int* __restrict__ col, float* __restrict__ deg) {
    int e = blockIdx.x * blockDim.x + threadIdx.x;
    if (e < NEDGES) atomicAdd(&deg[col[e]], 1.0f);
}

__global__ void k_dis(float* __restrict__ deg_dis) {
    int i = blockIdx.x * blockDim.x + threadIdx.x;
    if (i < NODES) deg_dis[i] = rsqrtf(deg_dis[i] + 1.0f);
}

// parallel scan, stage 1: per-block sums of (deg+1)
__global__ __launch_bounds__(SCT) void k_scan1(const float* __restrict__ deg, int* __restrict__ bsum) {
    __shared__ int ws4[SCT / 64];
    int b = blockIdx.x, t = threadIdx.x;
    int lane = t & 63, wv = t >> 6;
    int base = (b * SCT + t) * SCCH;
    int sum = 0;
#pragma unroll
    for (int j = 0; j < SCCH; j++) {
        int i = base + j;
        if (i < NODES) sum += (int)deg[i] + 1;
    }
#pragma unroll
    for (int off = 32; off > 0; off >>= 1) sum += __shfl_xor(sum, off, 64);
    if (lane == 0) ws4[wv] = sum;
    __syncthreads();
    if (t == 0) {
        int tot = 0;
#pragma unroll
        for (int j = 0; j < SCT / 64; j++) tot += ws4[j];
        bsum[b] = tot;
    }
}

// stage 2: exclusive scan of SCB block sums (single wave)
__global__ __launch_bounds__(64) void k_scan2(const int* __restrict__ bsum, int* __restrict__ bscan,
                                              int* __restrict__ start) {
    int t = threadIdx.x;
    int v = (t < SCB) ? bsum[t] : 0;
    int x = v;
#pragma unroll
    for (int off = 1; off < 64; off <<= 1) {
        int tt = __shfl_up(x, off, 64);
        if (t >= off) x += tt;
    }
    if (t < SCB) bscan[t] = x - v;
    if (t == SCB - 1) start[NODES] = x;
}

// stage 3: per-element exclusive prefix -> start/cursor
__global__ __launch_bounds__(SCT) void k_scan3(
    const float* __restrict__ deg, const int* __restrict__ bscan,
    int* __restrict__ start, int* __restrict__ cursor) {
    __shared__ int woff[SCT / 64];
    int b = blockIdx.x, t = threadIdx.x;
    int lane = t & 63, wv = t >> 6;
    int base = (b * SCT + t) * SCCH;
    int v[SCCH]; int sum = 0;
#pragma unroll
    for (int j = 0; j < SCCH; j++) {
        int i = base + j;
        v[j] = (i < NODES) ? (int)deg[i] + 1 : 0;
        sum += v[j];
    }
    int x = sum;
#pragma unroll
    for (int off = 1; off < 64; off <<= 1) {
        int tt = __shfl_up(x, off, 64);
        if (lane >= off) x += tt;
    }
    int texcl = x - sum;
    if (lane == 63) woff[wv] = x;
    __syncthreads();
    int wbase = 0;
    for (int j = 0; j < wv; j++) wbase += woff[j];
    int run = bscan[b] + wbase + texcl;
#pragma unroll
    for (int j = 0; j < SCCH; j++) {
        int i = base + j;
        if (i < NODES) { start[i] = run; cursor[i] = run; }
        run += v[j];
    }
}

__global__ __launch_bounds__(256) void k_csr(
    const int* __restrict__ eidx, const float* __restrict__ eattr,
    int* __restrict__ cursor,
    int* __restrict__ row_sorted, float* __restrict__ ea_sorted) {
    int e = blockIdx.x * blockDim.x + threadIdx.x;
    if (e >= ETOT) return;
    int r, ci; float ea;
    if (e < NEDGES) { r = eidx[e]; ci = eidx[NEDGES + e]; ea = eattr[e]; }
    else            { r = ci = e - NEDGES; ea = 0.0f; }
    int slot = atomicAdd(&cursor[ci], 1);
    row_sorted[slot] = r;
    ea_sorted[slot] = ea;
}

// fragment-ordered f16 weight buffers.
// WcatF: K=256, 24 col-tiles ordered per-wave [z0,z1,r0,r1,p0,p1] (wave wv owns tiles wv*6..+5)
// WhtopF: K=128 -> 128 cols; Wg1F: K=128 -> 64 (A|B); Wf1F: K=256 -> 128
__global__ __launch_bounds__(256) void k_prep_w(
    const float* __restrict__ Wz, const float* __restrict__ Wr, const float* __restrict__ Wh,
    const float* __restrict__ Wg1, const float* __restrict__ Wf1,
    f16* __restrict__ WcatF, f16* __restrict__ WhtopF, f16* __restrict__ Wg1F,
    f16* __restrict__ Wf1F) {
    int t = blockIdx.x * 256 + threadIdx.x;
    int l = t & 63;
    int lr = l & 15, lh = l >> 4;
    if (t < 24 * 8 * 64) {
        int idx = t >> 6; int nt = idx >> 3, ks = idx & 7;
        int wv = nt / 6, ntl = nt % 6;
        int grp = ntl >> 1, pr = ntl & 1;
        int ncol = (2 * wv + pr) * 16 + lr;
        f16x8 v;
#pragma unroll
        for (int j = 0; j < 8; j++) {
            int k = ks * 32 + lh * 8 + j;
            float x;
            if (grp == 0)      x = Wz[k * 128 + ncol];
            else if (grp == 1) x = Wr[k * 128 + ncol];
            else               x = (k >= 128) ? Wh[k * 128 + ncol] : 0.0f;
            v[j] = (f16)x;
        }
        *(f16x8*)(WcatF + (size_t)t * 8) = v;
    } else if (t < 24 * 8 * 64 + 8 * 4 * 64) {
        int t2 = t - 24 * 8 * 64;
        int idx = t2 >> 6; int nt = idx >> 2, ks = idx & 3;
        int n = nt * 16 + lr;
        f16x8 v;
#pragma unroll
        for (int j = 0; j < 8; j++) {
            int k = ks * 32 + lh * 8 + j;
            v[j] = (f16)Wh[k * 128 + n];
        }
        *(f16x8*)(WhtopF + (size_t)t2 * 8) = v;
    } else if (t < 24 * 8 * 64 + 8 * 4 * 64 + 4 * 4 * 64) {
        int t3 = t - (24 * 8 * 64 + 8 * 4 * 64);
        int idx = t3 >> 6; int nt = idx >> 2, ks = idx & 3;
        int cg = nt * 16 + lr;
        f16x8 v;
#pragma unroll
        for (int j = 0; j < 8; j++) {
            int k = ks * 32 + lh * 8 + j;
            v[j] = (f16)((cg < 32) ? Wg1[k * GH + cg] : Wg1[(128 + k) * GH + (cg - 32)]);
        }
        *(f16x8*)(Wg1F + (size_t)t3 * 8) = v;
    } else if (t < 24 * 8 * 64 + 8 * 4 * 64 + 4 * 4 * 64 + 8 * 8 * 64) {
        int t4 = t - (24 * 8 * 64 + 8 * 4 * 64 + 4 * 4 * 64);
        int idx = t4 >> 6; int nt = idx >> 3, ks = idx & 7;
        int n = nt * 16 + lr;
        f16x8 v;
#pragma unroll
        for (int j = 0; j < 8; j++) {
            int k = ks * 32 + lh * 8 + j;
            v[j] = (f16)Wf1[k * 128 + n];
        }
        *(f16x8*)(Wf1F + (size_t)t4 * 8) = v;
    }
}

// h = relu(x@W_pre+b_pre); h0_16 = (f16)relu(h@W_init+b_init); h = same (f32)
__global__ __launch_bounds__(256) void k_preproc(
    const float* __restrict__ x, const float* __restrict__ Wpre, const float* __restrict__ bpre,
    const float* __restrict__ Winit, const float* __restrict__ binit,
    f16* __restrict__ h0_16, float* __restrict__ h) {
    __shared__ float sWpre[FIN * PRE], sbpre[PRE], sWinit[PRE * C], sbinit[C];
    for (int i = threadIdx.x; i < FIN * PRE; i += blockDim.x) sWpre[i] = Wpre[i];
    for (int i = threadIdx.x; i < PRE; i += blockDim.x) sbpre[i] = bpre[i];
    for (int i = threadIdx.x; i < PRE * C; i += blockDim.x) sWinit[i] = Winit[i];
    for (int i = threadIdx.x; i < C; i += blockDim.x) sbinit[i] = binit[i];
    __syncthreads();
    int n = blockIdx.x * blockDim.x + threadIdx.x;
    if (n >= NODES) return;
    float xv[FIN];
#pragma unroll
    for (int i = 0; i < FIN; i++) xv[i] = x[n * FIN + i];
    float pre[PRE];
#pragma unroll
    for (int k = 0; k < PRE; k++) {
        float a = sbpre[k];
#pragma unroll
        for (int i = 0; i < FIN; i++) a = fmaf(xv[i], sWpre[i * PRE + k], a);
        pre[k] = fmaxf(a, 0.0f);
    }
    for (int k = 0; k < C; k++) {
        float a = sbinit[k];
#pragma unroll
        for (int j = 0; j < PRE; j++) a = fmaf(pre[j], sWinit[j * C + k], a);
        a = fmaxf(a, 0.0f);
        h0_16[(size_t)n * C + k] = (f16)a;
        h[(size_t)n * C + k] = a;
    }
}

// layer-0: A f32 (bg1 folded), rec = {B16 | hd16 = dis*h}. One wave per node.
__global__ __launch_bounds__(256) void k_gateAB(
    const float* __restrict__ h, const float* __restrict__ dis,
    const float* __restrict__ Wg1, const float* __restrict__ bg1,
    float* __restrict__ A, f16* __restrict__ rec) {
    int wave = (blockIdx.x * blockDim.x + threadIdx.x) >> 6;
    int lane = threadIdx.x & 63;
    if (wave >= NODES) return;
    int k = lane & 31;
    const float* W = Wg1 + ((lane < 32) ? 0 : C * GH);
    const float* hrow = h + (size_t)wave * C;
    float acc = (lane < 32) ? bg1[k] : 0.0f;
#pragma unroll 8
    for (int c = 0; c < C; c++) acc = fmaf(hrow[c], W[c * GH + k], acc);
    f16* rw = rec + (size_t)wave * RECS;
    if (lane < 32) A[(size_t)wave * GH + k] = acc;
    else           rw[k] = (f16)acc;
    float dn = dis[wave];
    float2 hv = *(const float2*)(hrow + lane * 2);
    rw[32 + lane * 2] = (f16)(dn * hv.x);
    rw[33 + lane * 2] = (f16)(dn * hv.y);
}

// fused gate+aggregate: wave per node, HALF-WAVE per edge, 1-deep record prefetch.
__global__ __launch_bounds__(256) void k_msg(
    const int* __restrict__ start, const int* __restrict__ row_sorted,
    const float* __restrict__ ea_sorted, const float* __restrict__ dis,
    const float* __restrict__ A, const f16* __restrict__ rec,
    const float* __restrict__ Wg1, const float* __restrict__ Wg2, const float* __restrict__ bg2,
    f16* __restrict__ aggr16) {
    int wid = (blockIdx.x * blockDim.x + threadIdx.x) >> 6;
    int lane = threadIdx.x & 63;
    if (wid >= NODES) return;
    int k = lane & 31;
    int hh = lane >> 5;
    int s0 = start[wid], s1 = start[wid + 1];
    float a_reg = A[(size_t)wid * GH + k];
    float w_ea = Wg1[2 * C * GH + k];
    float wg2v = Wg2[k];
    float b2 = bg2[0];
    float dci = dis[wid];
    f32x4 acc; acc[0] = acc[1] = acc[2] = acc[3] = 0.0f;

    int s = s0 + hh;
    f16x4 hv0 = {};
    float bb0 = 0.0f, ea0 = 0.0f;
    if (s < s1) {
        int r = row_sorted[s];
        ea0 = ea_sorted[s];
        const f16* rr = rec + (size_t)r * RECS;
        bb0 = (float)rr[k];
        hv0 = *(const f16x4*)(rr + 32 + k * 4);
    }
    while (s < s1) {
        int s2 = s + 2;
        f16x4 hv1 = {};
        float bb1 = 0.0f, ea1 = 0.0f;
        if (s2 < s1) {                       // prefetch next edge's record
            int r = row_sorted[s2];
            ea1 = ea_sorted[s2];
            const f16* rr = rec + (size_t)r * RECS;
            bb1 = (float)rr[k];
            hv1 = *(const f16x4*)(rr + 32 + k * 4);
        }
        float t = fmaxf(a_reg + bb0 + ea0 * w_ea, 0.0f);
        float p = t * wg2v;
#pragma unroll
        for (int m = 16; m > 0; m >>= 1) p += __shfl_xor(p, m, 32);
        float coef = sigmoidf_(p + b2);
        acc[0] = fmaf(coef, (float)hv0[0], acc[0]);
        acc[1] = fmaf(coef, (float)hv0[1], acc[1]);
        acc[2] = fmaf(coef, (float)hv0[2], acc[2]);
        acc[3] = fmaf(coef, (float)hv0[3], acc[3]);
        hv0 = hv1; bb0 = bb1; ea0 = ea1;
        s = s2;
    }
#pragma unroll
    for (int j = 0; j < 4; j++) acc[j] += __shfl_xor(acc[j], 32, 64);
    if (hh == 0) {
        f16x4 o;
        o[0] = (f16)(acc[0] * dci); o[1] = (f16)(acc[1] * dci);
        o[2] = (f16)(acc[2] * dci); o[3] = (f16)(acc[3] * dci);
        *(f16x4*)(aggr16 + (size_t)wid * C + k * 4) = o;
    }
}

// GRU update via MFMA; per-wave column-tile ownership keeps z,p in registers.
// Reads h f32 + aggr16; writes h f32, rec = {B16|hd16}, A f32.
__global__ __launch_bounds__(256) void k_update_mfma(
    float* __restrict__ h, const f16* __restrict__ aggr16, const float* __restrict__ dis,
    f16* __restrict__ rec,
    const f16* __restrict__ WcatF, const f16* __restrict__ WhtopF, const f16* __restrict__ Wg1F,
    const float* __restrict__ bz, const float* __restrict__ br, const float* __restrict__ bh,
    const float* __restrict__ bg1,
    float* __restrict__ A) {
    __shared__ f16 za[32 * 256];    // swizzled, row stride 512B; reused for h_new staging
    __shared__ f16 rhbuf[32 * 128]; // swizzled, row stride 256B
    char* zaB = (char*)za;
    char* rhB = (char*)rhbuf;
    int tid = threadIdx.x;
    int l = tid & 63, w = tid >> 6;
    int lr = l & 15, lh = l >> 4;
    int n0 = blockIdx.x * 32;

    // stage za = [(f16)h | aggr16]
    for (int p = tid; p < 32 * 64; p += 256) {
        int row = p >> 6;
        int c2 = (p & 63) * 2;
        int gn = n0 + row;
        float2 v = make_float2(0.0f, 0.0f);
        if (gn < NODES) v = *(const float2*)&h[(size_t)gn * C + c2];
        f16x2 o; o[0] = (f16)v.x; o[1] = (f16)v.y;
        *(f16x2*)(zaB + swz_off(row, c2 * 2, 512)) = o;
    }
    for (int p = tid; p < 32 * 16; p += 256) {
        int row = p >> 4, seg = p & 15;
        int gn = n0 + row;
        f16x8 v;
#pragma unroll
        for (int j = 0; j < 8; j++) v[j] = (f16)0.0f;
        if (gn < NODES) v = *(const f16x8*)(aggr16 + (size_t)gn * C + seg * 8);
        *(f16x8*)(zaB + swz_off(row, 256 + seg * 16, 512)) = v;
    }
    __syncthreads();

    // GEMM1: tiles [z0,z1,r0,r1,p0,p1] per wave
    f32x4 acc[2][6];
#pragma unroll
    for (int rt = 0; rt < 2; rt++)
#pragma unroll
        for (int n = 0; n < 6; n++)
#pragma unroll
            for (int j = 0; j < 4; j++) acc[rt][n][j] = 0.0f;
#pragma unroll
    for (int ks = 0; ks < 8; ks++) {
        int kk = ks * 32 + lh * 8;
        f16x8 a0 = *(const f16x8*)(zaB + swz_off(lr,      kk * 2, 512));
        f16x8 a1 = *(const f16x8*)(zaB + swz_off(lr + 16, kk * 2, 512));
#pragma unroll
        for (int ntl = 0; ntl < 6; ntl++) {
            f16x8 b = *(const f16x8*)(WcatF + ((size_t)((w * 6 + ntl) * 8 + ks) * 64 + l) * 8);
            acc[0][ntl] = __builtin_amdgcn_mfma_f32_16x16x32_f16(a0, b, acc[0][ntl], 0, 0, 0);
            acc[1][ntl] = __builtin_amdgcn_mfma_f32_16x16x32_f16(a1, b, acc[1][ntl], 0, 0, 0);
        }
    }

    // epilogue1: z->reg (sigmoid), r*h -> rhbuf, p stays in acc[rt][4/5]
    float zreg[2][2][4];
#pragma unroll
    for (int rt = 0; rt < 2; rt++)
#pragma unroll
        for (int pr = 0; pr < 2; pr++) {
            int cg = (2 * w + pr) * 16 + lr;
#pragma unroll
            for (int j = 0; j < 4; j++) {
                int row = rt * 16 + lh * 4 + j;
                int gn = n0 + row;
                zreg[rt][pr][j] = sigmoidf_(acc[rt][pr][j] + bz[cg]);
                float rv = sigmoidf_(acc[rt][2 + pr][j] + br[cg]);
                float hv = (gn < NODES) ? h[(size_t)gn * C + cg] : 0.0f;
                *(f16*)(rhB + swz_off(row, cg * 2, 256)) = (f16)(rv * hv);
            }
        }
    __syncthreads();

    // GEMM2: hc_pre = p + bh + (r*h) @ Wh_top
    f32x4 acc2[2][2];
#pragma unroll
    for (int rt = 0; rt < 2; rt++)
#pragma unroll
        for (int pr = 0; pr < 2; pr++) {
            int cg = (2 * w + pr) * 16 + lr;
#pragma unroll
            for (int j = 0; j < 4; j++)
                acc2[rt][pr][j] = acc[rt][4 + pr][j] + bh[cg];
        }
#pragma unroll
    for (int ks = 0; ks < 4; ks++) {
        int kk = ks * 32 + lh * 8;
        f16x8 a0 = *(const f16x8*)(rhB + swz_off(lr,      kk * 2, 256));
        f16x8 a1 = *(const f16x8*)(rhB + swz_off(lr + 16, kk * 2, 256));
#pragma unroll
        for (int pr = 0; pr < 2; pr++) {
            f16x8 b = *(const f16x8*)(WhtopF + ((size_t)((w * 2 + pr) * 4 + ks) * 64 + l) * 8);
            acc2[0][pr] = __builtin_amdgcn_mfma_f32_16x16x32_f16(a0, b, acc2[0][pr], 0, 0, 0);
            acc2[1][pr] = __builtin_amdgcn_mfma_f32_16x16x32_f16(a1, b, acc2[1][pr], 0, 0, 0);
        }
    }

    // epilogue2: h_new; write h f32 + rec hd16 (dis-scaled); stage h_new into za for GEMM3
#pragma unroll
    for (int rt = 0; rt < 2; rt++)
#pragma unroll
        for (int pr = 0; pr < 2; pr++) {
            int cg = (2 * w + pr) * 16 + lr;
#pragma unroll
            for (int j = 0; j < 4; j++) {
                int row = rt * 16 + lh * 4 + j;
                int gn = n0 + row;
                float hc = fmaxf(acc2[rt][pr][j], 0.0f);
                float z = zreg[rt][pr][j];
                float hold = (gn < NODES) ? h[(size_t)gn * C + cg] : 0.0f;
                float hn = (1.0f - z) * hold + z * hc;
                if (gn < NODES) {
                    h[(size_t)gn * C + cg] = hn;
                    rec[(size_t)gn * RECS + 32 + cg] = (f16)(hn * dis[gn]);
                }
                *(f16*)(zaB + swz_off(row, cg * 2, 512)) = (f16)hn;
            }
        }
    __syncthreads();

    // GEMM3: A|B16 = h_new @ Wg1F
    f32x4 acc3[2];
#pragma unroll
    for (int rt = 0; rt < 2; rt++)
#pragma unroll
        for (int j = 0; j < 4; j++) acc3[rt][j] = 0.0f;
#pragma unroll
    for (int ks = 0; ks < 4; ks++) {
        int kk = ks * 32 + lh * 8;
        f16x8 a0 = *(const f16x8*)(zaB + swz_off(lr,      kk * 2, 512));
        f16x8 a1 = *(const f16x8*)(zaB + swz_off(lr + 16, kk * 2, 512));
        f16x8 b = *(const f16x8*)(Wg1F + ((size_t)(w * 4 + ks) * 64 + l) * 8);
        acc3[0] = __builtin_amdgcn_mfma_f32_16x16x32_f16(a0, b, acc3[0], 0, 0, 0);
        acc3[1] = __builtin_amdgcn_mfma_f32_16x16x32_f16(a1, b, acc3[1], 0, 0, 0);
    }
    int col3 = w * 16 + lr;
#pragma unroll
    for (int rt = 0; rt < 2; rt++)
#pragma unroll
        for (int j = 0; j < 4; j++) {
            int row = rt * 16 + lh * 4 + j;
            int gn = n0 + row;
            if (gn < NODES) {
                float v = acc3[rt][j];
                if (col3 < 32) A[(size_t)gn * GH + col3] = v + bg1[col3];
                else           rec[(size_t)gn * RECS + (col3 - 32)] = (f16)v;
            }
        }
}

// final head via MFMA: f = relu([h0_16|h]@Wf1+bf1); out = f@Wf2+bf2
__global__ __launch_bounds__(256) void k_final_mfma(
    const f16* __restrict__ h0_16, const float* __restrict__ h,
    const f16* __restrict__ Wf1F, const float* __restrict__ bf1,
    const float* __restrict__ Wf2, const float* __restrict__ bf2,
    float* __restrict__ out) {
    __shared__ float fs[32][132];   // aliased during stage/GEMM as f16 za [32][256] swizzled
    char* zaB = (char*)&fs[0][0];
    int tid = threadIdx.x;
    int l = tid & 63, w = tid >> 6;
    int lr = l & 15, lh = l >> 4;
    int n0 = blockIdx.x * 32;

    for (int p = tid; p < 32 * 16; p += 256) {
        int row = p >> 4, seg = p & 15;
        int gn = n0 + row;
        f16x8 v;
#pragma unroll
        for (int j = 0; j < 8; j++) v[j] = (f16)0.0f;
        if (gn < NODES) v = *(const f16x8*)(h0_16 + (size_t)gn * C + seg * 8);
        *(f16x8*)(zaB + swz_off(row, seg * 16, 512)) = v;
    }
    for (int p = tid; p < 32 * 64; p += 256) {
        int row = p >> 6;
        int c2 = (p & 63) * 2;
        int gn = n0 + row;
        float2 hv = make_float2(0.0f, 0.0f);
        if (gn < NODES) hv = *(const float2*)&h[(size_t)gn * C + c2];
        f16x2 o; o[0] = (f16)hv.x; o[1] = (f16)hv.y;
        *(f16x2*)(zaB + swz_off(row, (128 + c2) * 2, 512)) = o;
    }
    __syncthreads();

    f32x4 acc[2][2];
#pragma unroll
    for (int rt = 0; rt < 2; rt++)
#pragma unroll
        for (int n = 0; n < 2; n++)
#pragma unroll
            for (int j = 0; j < 4; j++) acc[rt][n][j] = 0.0f;
#pragma unroll
    for (int ks = 0; ks < 8; ks++) {
        int kk = ks * 32 + lh * 8;
        f16x8 a0 = *(const f16x8*)(zaB + swz_off(lr,      kk * 2, 512));
        f16x8 a1 = *(const f16x8*)(zaB + swz_off(lr + 16, kk * 2, 512));
#pragma unroll
        for (int ntl = 0; ntl < 2; ntl++) {
            f16x8 b = *(const f16x8*)(Wf1F + ((size_t)((w * 2 + ntl) * 8 + ks) * 64 + l) * 8);
            acc[0][ntl] = __builtin_amdgcn_mfma_f32_16x16x32_f16(a0, b, acc[0][ntl], 0, 0, 0);
            acc[1][ntl] = __builtin_amdgcn_mfma_f32_16x16x32_f16(a1, b, acc[1][ntl], 0, 0, 0);
        }
    }
    __syncthreads();  // za reads done before fs overwrite

#pragma unroll
    for (int rt = 0; rt < 2; rt++)
#pragma unroll
        for (int ntl = 0; ntl < 2; ntl++) {
            int cg = (w * 2 + ntl) * 16 + lr;
#pragma unroll
            for (int j = 0; j < 4; j++) {
                int row = rt * 16 + lh * 4 + j;
                fs[row][cg] = fmaxf(acc[rt][ntl][j] + bf1[cg], 0.0f);
            }
        }
    __syncthreads();

    if (tid < 64) {
        int n = tid >> 1, o = tid & 1;
        int gn = n0 + n;
        if (gn < NODES) {
            float a = bf2[o];
#pragma unroll 16
            for (int c = 0; c < C; c++) a = fmaf(fs[n][c], Wf2[c * 2 + o], a);
            out[(size_t)gn * 2 + o] = a;
        }
    }
}

extern "C" void kernel_launch(void* const* d_in, const int* in_sizes, int n_in,
                              void* d_out, int out_size, void* d_ws, size_t ws_size,
                              hipStream_t stream) {
    const float* x    = (const float*)d_in[0];
    const int*   eidx = (const int*)d_in[1];
    const float* eattr= (const float*)d_in[2];
    const float* Wpre = (const float*)d_in[3];  const float* bpre = (const float*)d_in[4];
    const float* Winit= (const float*)d_in[5];  const float* binit= (const float*)d_in[6];
    const float* Wg1  = (const float*)d_in[7];  const float* bg1  = (const float*)d_in[8];
    const float* Wg2  = (const float*)d_in[9];  const float* bg2  = (const float*)d_in[10];
    const float* Wz   = (const float*)d_in[11]; const float* bz   = (const float*)d_in[12];
    const float* Wr   = (const float*)d_in[13]; const float* br   = (const float*)d_in[14];
    const float* Wh   = (const float*)d_in[15]; const float* bh   = (const float*)d_in[16];
    const float* Wf1  = (const float*)d_in[17]; const float* bf1  = (const float*)d_in[18];
    const float* Wf2  = (const float*)d_in[19]; const float* bf2  = (const float*)d_in[20];
    float* out = (float*)d_out;

    float* ws  = (float*)d_ws;
    float* dis = ws;                               // N
    float* h   = dis + NODES;                      // N*C f32
    float* A   = h + (size_t)NODES * C;            // N*GH f32
    int*   start = (int*)(A + (size_t)NODES * GH);     // N+1
    int*   cursor = start + NODES + 1;                 // N+1
    int*   bsum  = cursor + NODES + 1;                 // SCB
    int*   bscan = bsum + SCB;                         // SCB
    int*   row_sorted = bscan + SCB;                   // ETOT
    float* ea_sorted  = (float*)(row_sorted + ETOT);   // ETOT
    size_t f16_base = (size_t)((ea_sorted + ETOT) - ws);
    f16_base = (f16_base + 3) & ~(size_t)3;            // 16B align
    f16* h0_16  = (f16*)(ws + f16_base);               // N*C f16
    f16* rec    = h0_16 + (size_t)NODES * C;           // N*RECS f16
    f16* aggr16 = rec + (size_t)NODES * RECS;          // N*C f16
    f16* WcatF  = aggr16 + (size_t)NODES * C;          // 24*8*64*8 f16
    f16* WhtopF = WcatF + 24 * 8 * 64 * 8;
    f16* Wg1F   = WhtopF + 8 * 4 * 64 * 8;
    f16* Wf1F   = Wg1F + 4 * 4 * 64 * 8;
    size_t f16_total = (size_t)NODES * (C + RECS + C) + (24 * 8 + 8 * 4 + 4 * 4 + 8 * 8) * 64 * 8;
    const size_t REQ = (f16_base + (f16_total + 1) / 2) * sizeof(float);
    if (ws_size < REQ) return;

    hipMemsetAsync(dis, 0, NODES * sizeof(float), stream);
    k_degree<<<(NEDGES + 255) / 256, 256, 0, stream>>>(eidx + NEDGES, dis);
    k_scan1<<<SCB, SCT, 0, stream>>>(dis, bsum);
    k_scan2<<<1, 64, 0, stream>>>(bsum, bscan, start);
    k_scan3<<<SCB, SCT, 0, stream>>>(dis, bscan, start, cursor);
    k_dis<<<(NODES + 255) / 256, 256, 0, stream>>>(dis);
    k_csr<<<(ETOT + 255) / 256, 256, 0, stream>>>(eidx, eattr, cursor, row_sorted, ea_sorted);
    k_prep_w<<<(24 * 8 * 64 + 8 * 4 * 64 + 4 * 4 * 64 + 8 * 8 * 64 + 255) / 256, 256, 0, stream>>>(
        Wz, Wr, Wh, Wg1, Wf1, WcatF, WhtopF, Wg1F, Wf1F);
    k_preproc<<<(NODES + 255) / 256, 256, 0, stream>>>(x, Wpre, bpre, Winit, binit, h0_16, h);
    k_gateAB<<<(NODES * 64 + 255) / 256, 256, 0, stream>>>(h, dis, Wg1, bg1, A, rec);

    for (int l = 0; l < LAYERS; l++) {
        k_msg<<<(NODES * 64 + 255) / 256, 256, 0, stream>>>(
            start, row_sorted, ea_sorted, dis, A, rec, Wg1, Wg2, bg2, aggr16);
        k_update_mfma<<<(NODES + 31) / 32, 256, 0, stream>>>(
            h, aggr16, dis, rec, WcatF, WhtopF, Wg1F, bz, br, bh, bg1, A);
    }
    k_final_mfma<<<(NODES + 31) / 32, 256, 0, stream>>>(h0_16, h, Wf1F, bf1, Wf2, bf2, out);
}

// Round 9
// 756.502 us; speedup vs baseline: 12.0844x; 1.2312x over previous
//
#include <hip/hip_runtime.h>
#include <math.h>

#define NODES 50000
#define NEDGES 800000
#define ETOT (NEDGES + NODES)
#define FIN 16
#define PRE 32
#define C 128
#define GH 32
#define LAYERS 5
#define RECS 160   // f16 per node record: [B16:32 | hd16:128] where hd = dis[n]*h[n]
#define SCB 64     // scan blocks
#define SCT 256    // scan threads/block
#define SCCH ((NODES + SCB*SCT - 1) / (SCB*SCT))   // elems per thread (=4)

typedef _Float16 f16;
typedef f16 f16x8 __attribute__((ext_vector_type(8)));
typedef f16 f16x4 __attribute__((ext_vector_type(4)));
typedef f16 f16x2 __attribute__((ext_vector_type(2)));
typedef float f32x4 __attribute__((ext_vector_type(4)));

__device__ __forceinline__ float sigmoidf_(float x) { return 1.0f / (1.0f + __expf(-x)); }

// XOR-swizzled LDS byte offset: 16B-block index ^= (row&7)
__device__ __forceinline__ int swz_off(int row, int bytecol, int stride) {
    return row * stride + ((((bytecol) >> 4) ^ (row & 7)) << 4) + (bytecol & 15);
}

__global__ void k_degree(const int* __restrict__ col, float* __restrict__ deg) {
    int e = blockIdx.x * blockDim.x + threadIdx.x;
    if (e < NEDGES) atomicAdd(&deg[col[e]], 1.0f);
}

// parallel scan, stage 1: per-block sums of (deg+1)
__global__ __launch_bounds__(SCT) void k_scan1(const float* __restrict__ deg, int* __restrict__ bsum) {
    __shared__ int ws4[SCT / 64];
    int b = blockIdx.x, t = threadIdx.x;
    int lane = t & 63, wv = t >> 6;
    int base = (b * SCT + t) * SCCH;
    int sum = 0;
#pragma unroll
    for (int j = 0; j < SCCH; j++) {
        int i = base + j;
        if (i < NODES) sum += (int)deg[i] + 1;
    }
#pragma unroll
    for (int off = 32; off > 0; off >>= 1) sum += __shfl_xor(sum, off, 64);
    if (lane == 0) ws4[wv] = sum;
    __syncthreads();
    if (t == 0) {
        int tot = 0;
#pragma unroll
        for (int j = 0; j < SCT / 64; j++) tot += ws4[j];
        bsum[b] = tot;
    }
}

// stage 2: exclusive scan of SCB block sums (single wave)
__global__ __launch_bounds__(64) void k_scan2(const int* __restrict__ bsum, int* __restrict__ bscan,
                                              int* __restrict__ start) {
    int t = threadIdx.x;
    int v = (t < SCB) ? bsum[t] : 0;
    int x = v;
#pragma unroll
    for (int off = 1; off < 64; off <<= 1) {
        int tt = __shfl_up(x, off, 64);
        if (t >= off) x += tt;
    }
    if (t < SCB) bscan[t] = x - v;
    if (t == SCB - 1) start[NODES] = x;
}

// stage 3: per-element exclusive prefix -> start/cursor; also dis = rsqrt(deg+1) in-place
__global__ __launch_bounds__(SCT) void k_scan3(
    float* __restrict__ deg_dis, const int* __restrict__ bscan,
    int* __restrict__ start, int* __restrict__ cursor) {
    __shared__ int woff[SCT / 64];
    int b = blockIdx.x, t = threadIdx.x;
    int lane = t & 63, wv = t >> 6;
    int base = (b * SCT + t) * SCCH;
    int v[SCCH]; int sum = 0;
#pragma unroll
    for (int j = 0; j < SCCH; j++) {
        int i = base + j;
        v[j] = (i < NODES) ? (int)deg_dis[i] + 1 : 0;
        sum += v[j];
    }
    int x = sum;
#pragma unroll
    for (int off = 1; off < 64; off <<= 1) {
        int tt = __shfl_up(x, off, 64);
        if (lane >= off) x += tt;
    }
    int texcl = x - sum;
    if (lane == 63) woff[wv] = x;
    __syncthreads();
    int wbase = 0;
    for (int j = 0; j < wv; j++) wbase += woff[j];
    int run = bscan[b] + wbase + texcl;
#pragma unroll
    for (int j = 0; j < SCCH; j++) {
        int i = base + j;
        if (i < NODES) {
            start[i] = run; cursor[i] = run;
            deg_dis[i] = rsqrtf((float)v[j]);
        }
        run += v[j];
    }
}

__global__ __launch_bounds__(256) void k_csr(
    const int* __restrict__ eidx, const float* __restrict__ eattr,
    int* __restrict__ cursor,
    int* __restrict__ row_sorted, float* __restrict__ ea_sorted) {
    int e = blockIdx.x * blockDim.x + threadIdx.x;
    if (e >= ETOT) return;
    int r, ci; float ea;
    if (e < NEDGES) { r = eidx[e]; ci = eidx[NEDGES + e]; ea = eattr[e]; }
    else            { r = ci = e - NEDGES; ea = 0.0f; }
    int slot = atomicAdd(&cursor[ci], 1);
    row_sorted[slot] = r;
    ea_sorted[slot] = ea;
}

// fragment-ordered f16 weight buffers.
// WcatF: K=256, 24 col-tiles ordered per-wave [z0,z1,r0,r1,p0,p1] (wave wv owns tiles wv*6..+5)
// WhtopF: K=128 -> 128 cols; Wg1F: K=128 -> 64 (A|B); Wf1F: K=256 -> 128
__global__ __launch_bounds__(256) void k_prep_w(
    const float* __restrict__ Wz, const float* __restrict__ Wr, const float* __restrict__ Wh,
    const float* __restrict__ Wg1, const float* __restrict__ Wf1,
    f16* __restrict__ WcatF, f16* __restrict__ WhtopF, f16* __restrict__ Wg1F,
    f16* __restrict__ Wf1F) {
    int t = blockIdx.x * 256 + threadIdx.x;
    int l = t & 63;
    int lr = l & 15, lh = l >> 4;
    if (t < 24 * 8 * 64) {
        int idx = t >> 6; int nt = idx >> 3, ks = idx & 7;
        int wv = nt / 6, ntl = nt % 6;
        int grp = ntl >> 1, pr = ntl & 1;
        int ncol = (2 * wv + pr) * 16 + lr;
        f16x8 v;
#pragma unroll
        for (int j = 0; j < 8; j++) {
            int k = ks * 32 + lh * 8 + j;
            float x;
            if (grp == 0)      x = Wz[k * 128 + ncol];
            else if (grp == 1) x = Wr[k * 128 + ncol];
            else               x = (k >= 128) ? Wh[k * 128 + ncol] : 0.0f;
            v[j] = (f16)x;
        }
        *(f16x8*)(WcatF + (size_t)t * 8) = v;
    } else if (t < 24 * 8 * 64 + 8 * 4 * 64) {
        int t2 = t - 24 * 8 * 64;
        int idx = t2 >> 6; int nt = idx >> 2, ks = idx & 3;
        int n = nt * 16 + lr;
        f16x8 v;
#pragma unroll
        for (int j = 0; j < 8; j++) {
            int k = ks * 32 + lh * 8 + j;
            v[j] = (f16)Wh[k * 128 + n];
        }
        *(f16x8*)(WhtopF + (size_t)t2 * 8) = v;
    } else if (t < 24 * 8 * 64 + 8 * 4 * 64 + 4 * 4 * 64) {
        int t3 = t - (24 * 8 * 64 + 8 * 4 * 64);
        int idx = t3 >> 6; int nt = idx >> 2, ks = idx & 3;
        int cg = nt * 16 + lr;
        f16x8 v;
#pragma unroll
        for (int j = 0; j < 8; j++) {
            int k = ks * 32 + lh * 8 + j;
            v[j] = (f16)((cg < 32) ? Wg1[k * GH + cg] : Wg1[(128 + k) * GH + (cg - 32)]);
        }
        *(f16x8*)(Wg1F + (size_t)t3 * 8) = v;
    } else if (t < 24 * 8 * 64 + 8 * 4 * 64 + 4 * 4 * 64 + 8 * 8 * 64) {
        int t4 = t - (24 * 8 * 64 + 8 * 4 * 64 + 4 * 4 * 64);
        int idx = t4 >> 6; int nt = idx >> 3, ks = idx & 7;
        int n = nt * 16 + lr;
        f16x8 v;
#pragma unroll
        for (int j = 0; j < 8; j++) {
            int k = ks * 32 + lh * 8 + j;
            v[j] = (f16)Wf1[k * 128 + n];
        }
        *(f16x8*)(Wf1F + (size_t)t4 * 8) = v;
    }
}

// h = relu(x@W_pre+b_pre); h0_16 = (f16)relu(h@W_init+b_init); h = same (f32)
__global__ __launch_bounds__(256) void k_preproc(
    const float* __restrict__ x, const float* __restrict__ Wpre, const float* __restrict__ bpre,
    const float* __restrict__ Winit, const float* __restrict__ binit,
    f16* __restrict__ h0_16, float* __restrict__ h) {
    __shared__ float sWpre[FIN * PRE], sbpre[PRE], sWinit[PRE * C], sbinit[C];
    for (int i = threadIdx.x; i < FIN * PRE; i += blockDim.x) sWpre[i] = Wpre[i];
    for (int i = threadIdx.x; i < PRE; i += blockDim.x) sbpre[i] = bpre[i];
    for (int i = threadIdx.x; i < PRE * C; i += blockDim.x) sWinit[i] = Winit[i];
    for (int i = threadIdx.x; i < C; i += blockDim.x) sbinit[i] = binit[i];
    __syncthreads();
    int n = blockIdx.x * blockDim.x + threadIdx.x;
    if (n >= NODES) return;
    float xv[FIN];
#pragma unroll
    for (int i = 0; i < FIN; i++) xv[i] = x[n * FIN + i];
    float pre[PRE];
#pragma unroll
    for (int k = 0; k < PRE; k++) {
        float a = sbpre[k];
#pragma unroll
        for (int i = 0; i < FIN; i++) a = fmaf(xv[i], sWpre[i * PRE + k], a);
        pre[k] = fmaxf(a, 0.0f);
    }
    for (int k = 0; k < C; k++) {
        float a = sbinit[k];
#pragma unroll
        for (int j = 0; j < PRE; j++) a = fmaf(pre[j], sWinit[j * C + k], a);
        a = fmaxf(a, 0.0f);
        h0_16[(size_t)n * C + k] = (f16)a;
        h[(size_t)n * C + k] = a;
    }
}

// layer-0 gate via MFMA: A|B16 = h @ Wg1F (+bg1 on A); also rec hd16 = dis*h during staging.
__global__ __launch_bounds__(256) void k_gate0_mfma(
    const float* __restrict__ h, const float* __restrict__ dis,
    const f16* __restrict__ Wg1F, const float* __restrict__ bg1,
    float* __restrict__ A, f16* __restrict__ rec) {
    __shared__ f16 za[32 * 128];    // swizzled, row stride 256B
    char* zaB = (char*)za;
    int tid = threadIdx.x;
    int l = tid & 63, w = tid >> 6;
    int lr = l & 15, lh = l >> 4;
    int n0 = blockIdx.x * 32;

    for (int p = tid; p < 32 * 64; p += 256) {
        int row = p >> 6;
        int c2 = (p & 63) * 2;
        int gn = n0 + row;
        float2 v = make_float2(0.0f, 0.0f);
        if (gn < NODES) v = *(const float2*)&h[(size_t)gn * C + c2];
        f16x2 o; o[0] = (f16)v.x; o[1] = (f16)v.y;
        *(f16x2*)(zaB + swz_off(row, c2 * 2, 256)) = o;
        if (gn < NODES) {
            float dn = dis[gn];
            f16x2 od; od[0] = (f16)(v.x * dn); od[1] = (f16)(v.y * dn);
            *(f16x2*)(rec + (size_t)gn * RECS + 32 + c2) = od;
        }
    }
    __syncthreads();

    f32x4 acc3[2];
#pragma unroll
    for (int rt = 0; rt < 2; rt++)
#pragma unroll
        for (int j = 0; j < 4; j++) acc3[rt][j] = 0.0f;
#pragma unroll
    for (int ks = 0; ks < 4; ks++) {
        int kk = ks * 32 + lh * 8;
        f16x8 a0 = *(const f16x8*)(zaB + swz_off(lr,      kk * 2, 256));
        f16x8 a1 = *(const f16x8*)(zaB + swz_off(lr + 16, kk * 2, 256));
        f16x8 b = *(const f16x8*)(Wg1F + ((size_t)(w * 4 + ks) * 64 + l) * 8);
        acc3[0] = __builtin_amdgcn_mfma_f32_16x16x32_f16(a0, b, acc3[0], 0, 0, 0);
        acc3[1] = __builtin_amdgcn_mfma_f32_16x16x32_f16(a1, b, acc3[1], 0, 0, 0);
    }
    int col3 = w * 16 + lr;
#pragma unroll
    for (int rt = 0; rt < 2; rt++)
#pragma unroll
        for (int j = 0; j < 4; j++) {
            int row = rt * 16 + lh * 4 + j;
            int gn = n0 + row;
            if (gn < NODES) {
                float v = acc3[rt][j];
                if (col3 < 32) A[(size_t)gn * GH + col3] = v + bg1[col3];
                else           rec[(size_t)gn * RECS + (col3 - 32)] = (f16)v;
            }
        }
}

// fused gate+aggregate: wave per node, QUARTER-WAVE (16 lanes) per edge, 1-deep prefetch.
// Each lane handles 2 gate channels (k16, k16+16) and 8 hd channels (k16*8..+8).
__global__ __launch_bounds__(256) void k_msg(
    const int* __restrict__ start, const int* __restrict__ row_sorted,
    const float* __restrict__ ea_sorted, const float* __restrict__ dis,
    const float* __restrict__ A, const f16* __restrict__ rec,
    const float* __restrict__ Wg1, const float* __restrict__ Wg2, const float* __restrict__ bg2,
    f16* __restrict__ aggr16) {
    int wid = (blockIdx.x * blockDim.x + threadIdx.x) >> 6;
    int lane = threadIdx.x & 63;
    if (wid >= NODES) return;
    int k16 = lane & 15;
    int q = lane >> 4;
    int s0 = start[wid], s1 = start[wid + 1];
    float a_a = A[(size_t)wid * GH + k16];
    float a_b = A[(size_t)wid * GH + k16 + 16];
    float w_ea = Wg1[2 * C * GH + k16];
    float w_eb = Wg1[2 * C * GH + k16 + 16];
    float w2a = Wg2[k16], w2b = Wg2[k16 + 16];
    float b2 = bg2[0];
    float dci = dis[wid];
    float acc[8];
#pragma unroll
    for (int j = 0; j < 8; j++) acc[j] = 0.0f;

    int s = s0 + q;
    f16x8 hv0 = {};
    float ba0 = 0.0f, bb0 = 0.0f, ea0 = 0.0f;
    if (s < s1) {
        int r = row_sorted[s];
        ea0 = ea_sorted[s];
        const f16* rr = rec + (size_t)r * RECS;
        ba0 = (float)rr[k16]; bb0 = (float)rr[k16 + 16];
        hv0 = *(const f16x8*)(rr + 32 + k16 * 8);
    }
    while (s < s1) {
        int s2 = s + 4;
        f16x8 hv1 = {};
        float ba1 = 0.0f, bb1 = 0.0f, ea1 = 0.0f;
        if (s2 < s1) {                       // prefetch next edge's record
            int r = row_sorted[s2];
            ea1 = ea_sorted[s2];
            const f16* rr = rec + (size_t)r * RECS;
            ba1 = (float)rr[k16]; bb1 = (float)rr[k16 + 16];
            hv1 = *(const f16x8*)(rr + 32 + k16 * 8);
        }
        float ta = fmaxf(a_a + ba0 + ea0 * w_ea, 0.0f);
        float tb = fmaxf(a_b + bb0 + ea0 * w_eb, 0.0f);
        float p = fmaf(ta, w2a, tb * w2b);
#pragma unroll
        for (int m = 8; m > 0; m >>= 1) p += __shfl_xor(p, m, 16);
        float coef = sigmoidf_(p + b2);
#pragma unroll
        for (int j = 0; j < 8; j++) acc[j] = fmaf(coef, (float)hv0[j], acc[j]);
        hv0 = hv1; ba0 = ba1; bb0 = bb1; ea0 = ea1;
        s = s2;
    }
#pragma unroll
    for (int j = 0; j < 8; j++) {
        acc[j] += __shfl_xor(acc[j], 16, 64);
        acc[j] += __shfl_xor(acc[j], 32, 64);
    }
    if (lane < 16) {
        f16x8 o;
#pragma unroll
        for (int j = 0; j < 8; j++) o[j] = (f16)(acc[j] * dci);
        *(f16x8*)(aggr16 + (size_t)wid * C + k16 * 8) = o;
    }
}

// GRU update via MFMA; per-wave column-tile ownership keeps z,p in registers.
// Reads h f32 + aggr16; writes h f32, rec = {B16|hd16}, A f32.
__global__ __launch_bounds__(256) void k_update_mfma(
    float* __restrict__ h, const f16* __restrict__ aggr16, const float* __restrict__ dis,
    f16* __restrict__ rec,
    const f16* __restrict__ WcatF, const f16* __restrict__ WhtopF, const f16* __restrict__ Wg1F,
    const float* __restrict__ bz, const float* __restrict__ br, const float* __restrict__ bh,
    const float* __restrict__ bg1,
    float* __restrict__ A) {
    __shared__ f16 za[32 * 256];    // swizzled, row stride 512B; reused for h_new staging
    __shared__ f16 rhbuf[32 * 128]; // swizzled, row stride 256B
    char* zaB = (char*)za;
    char* rhB = (char*)rhbuf;
    int tid = threadIdx.x;
    int l = tid & 63, w = tid >> 6;
    int lr = l & 15, lh = l >> 4;
    int n0 = blockIdx.x * 32;

    // stage za = [(f16)h | aggr16]
    for (int p = tid; p < 32 * 64; p += 256) {
        int row = p >> 6;
        int c2 = (p & 63) * 2;
        int gn = n0 + row;
        float2 v = make_float2(0.0f, 0.0f);
        if (gn < NODES) v = *(const float2*)&h[(size_t)gn * C + c2];
        f16x2 o; o[0] = (f16)v.x; o[1] = (f16)v.y;
        *(f16x2*)(zaB + swz_off(row, c2 * 2, 512)) = o;
    }
    for (int p = tid; p < 32 * 16; p += 256) {
        int row = p >> 4, seg = p & 15;
        int gn = n0 + row;
        f16x8 v;
#pragma unroll
        for (int j = 0; j < 8; j++) v[j] = (f16)0.0f;
        if (gn < NODES) v = *(const f16x8*)(aggr16 + (size_t)gn * C + seg * 8);
        *(f16x8*)(zaB + swz_off(row, 256 + seg * 16, 512)) = v;
    }
    __syncthreads();

    // GEMM1: tiles [z0,z1,r0,r1,p0,p1] per wave
    f32x4 acc[2][6];
#pragma unroll
    for (int rt = 0; rt < 2; rt++)
#pragma unroll
        for (int n = 0; n < 6; n++)
#pragma unroll
            for (int j = 0; j < 4; j++) acc[rt][n][j] = 0.0f;
#pragma unroll
    for (int ks = 0; ks < 8; ks++) {
        int kk = ks * 32 + lh * 8;
        f16x8 a0 = *(const f16x8*)(zaB + swz_off(lr,      kk * 2, 512));
        f16x8 a1 = *(const f16x8*)(zaB + swz_off(lr + 16, kk * 2, 512));
#pragma unroll
        for (int ntl = 0; ntl < 6; ntl++) {
            f16x8 b = *(const f16x8*)(WcatF + ((size_t)((w * 6 + ntl) * 8 + ks) * 64 + l) * 8);
            acc[0][ntl] = __builtin_amdgcn_mfma_f32_16x16x32_f16(a0, b, acc[0][ntl], 0, 0, 0);
            acc[1][ntl] = __builtin_amdgcn_mfma_f32_16x16x32_f16(a1, b, acc[1][ntl], 0, 0, 0);
        }
    }

    // epilogue1: z->reg (sigmoid), r*h -> rhbuf, p stays in acc[rt][4/5]
    float zreg[2][2][4];
#pragma unroll
    for (int rt = 0; rt < 2; rt++)
#pragma unroll
        for (int pr = 0; pr < 2; pr++) {
            int cg = (2 * w + pr) * 16 + lr;
#pragma unroll
            for (int j = 0; j < 4; j++) {
                int row = rt * 16 + lh * 4 + j;
                int gn = n0 + row;
                zreg[rt][pr][j] = sigmoidf_(acc[rt][pr][j] + bz[cg]);
                float rv = sigmoidf_(acc[rt][2 + pr][j] + br[cg]);
                float hv = (gn < NODES) ? h[(size_t)gn * C + cg] : 0.0f;
                *(f16*)(rhB + swz_off(row, cg * 2, 256)) = (f16)(rv * hv);
            }
        }
    __syncthreads();

    // GEMM2: hc_pre = p + bh + (r*h) @ Wh_top
    f32x4 acc2[2][2];
#pragma unroll
    for (int rt = 0; rt < 2; rt++)
#pragma unroll
        for (int pr = 0; pr < 2; pr++) {
            int cg = (2 * w + pr) * 16 + lr;
#pragma unroll
            for (int j = 0; j < 4; j++)
                acc2[rt][pr][j] = acc[rt][4 + pr][j] + bh[cg];
        }
#pragma unroll
    for (int ks = 0; ks < 4; ks++) {
        int kk = ks * 32 + lh * 8;
        f16x8 a0 = *(const f16x8*)(rhB + swz_off(lr,      kk * 2, 256));
        f16x8 a1 = *(const f16x8*)(rhB + swz_off(lr + 16, kk * 2, 256));
#pragma unroll
        for (int pr = 0; pr < 2; pr++) {
            f16x8 b = *(const f16x8*)(WhtopF + ((size_t)((w * 2 + pr) * 4 + ks) * 64 + l) * 8);
            acc2[0][pr] = __builtin_amdgcn_mfma_f32_16x16x32_f16(a0, b, acc2[0][pr], 0, 0, 0);
            acc2[1][pr] = __builtin_amdgcn_mfma_f32_16x16x32_f16(a1, b, acc2[1][pr], 0, 0, 0);
        }
    }

    // epilogue2: h_new; write h f32 + rec hd16 (dis-scaled); stage h_new into za for GEMM3
#pragma unroll
    for (int rt = 0; rt < 2; rt++)
#pragma unroll
        for (int pr = 0; pr < 2; pr++) {
            int cg = (2 * w + pr) * 16 + lr;
#pragma unroll
            for (int j = 0; j < 4; j++) {
                int row = rt * 16 + lh * 4 + j;
                int gn = n0 + row;
                float hc = fmaxf(acc2[rt][pr][j], 0.0f);
                float z = zreg[rt][pr][j];
                float hold = (gn < NODES) ? h[(size_t)gn * C + cg] : 0.0f;
                float hn = (1.0f - z) * hold + z * hc;
                if (gn < NODES) {
                    h[(size_t)gn * C + cg] = hn;
                    rec[(size_t)gn * RECS + 32 + cg] = (f16)(hn * dis[gn]);
                }
                *(f16*)(zaB + swz_off(row, cg * 2, 512)) = (f16)hn;
            }
        }
    __syncthreads();

    // GEMM3: A|B16 = h_new @ Wg1F
    f32x4 acc3[2];
#pragma unroll
    for (int rt = 0; rt < 2; rt++)
#pragma unroll
        for (int j = 0; j < 4; j++) acc3[rt][j] = 0.0f;
#pragma unroll
    for (int ks = 0; ks < 4; ks++) {
        int kk = ks * 32 + lh * 8;
        f16x8 a0 = *(const f16x8*)(zaB + swz_off(lr,      kk * 2, 512));
        f16x8 a1 = *(const f16x8*)(zaB + swz_off(lr + 16, kk * 2, 512));
        f16x8 b = *(const f16x8*)(Wg1F + ((size_t)(w * 4 + ks) * 64 + l) * 8);
        acc3[0] = __builtin_amdgcn_mfma_f32_16x16x32_f16(a0, b, acc3[0], 0, 0, 0);
        acc3[1] = __builtin_amdgcn_mfma_f32_16x16x32_f16(a1, b, acc3[1], 0, 0, 0);
    }
    int col3 = w * 16 + lr;
#pragma unroll
    for (int rt = 0; rt < 2; rt++)
#pragma unroll
        for (int j = 0; j < 4; j++) {
            int row = rt * 16 + lh * 4 + j;
            int gn = n0 + row;
            if (gn < NODES) {
                float v = acc3[rt][j];
                if (col3 < 32) A[(size_t)gn * GH + col3] = v + bg1[col3];
                else           rec[(size_t)gn * RECS + (col3 - 32)] = (f16)v;
            }
        }
}

// final head via MFMA: f = relu([h0_16|h]@Wf1+bf1); out = f@Wf2+bf2
__global__ __launch_bounds__(256) void k_final_mfma(
    const f16* __restrict__ h0_16, const float* __restrict__ h,
    const f16* __restrict__ Wf1F, const float* __restrict__ bf1,
    const float* __restrict__ Wf2, const float* __restrict__ bf2,
    float* __restrict__ out) {
    __shared__ float fs[32][132];   // aliased during stage/GEMM as f16 za [32][256] swizzled
    char* zaB = (char*)&fs[0][0];
    int tid = threadIdx.x;
    int l = tid & 63, w = tid >> 6;
    int lr = l & 15, lh = l >> 4;
    int n0 = blockIdx.x * 32;

    for (int p = tid; p < 32 * 16; p += 256) {
        int row = p >> 4, seg = p & 15;
        int gn = n0 + row;
        f16x8 v;
#pragma unroll
        for (int j = 0; j < 8; j++) v[j] = (f16)0.0f;
        if (gn < NODES) v = *(const f16x8*)(h0_16 + (size_t)gn * C + seg * 8);
        *(f16x8*)(zaB + swz_off(row, seg * 16, 512)) = v;
    }
    for (int p = tid; p < 32 * 64; p += 256) {
        int row = p >> 6;
        int c2 = (p & 63) * 2;
        int gn = n0 + row;
        float2 hv = make_float2(0.0f, 0.0f);
        if (gn < NODES) hv = *(const float2*)&h[(size_t)gn * C + c2];
        f16x2 o; o[0] = (f16)hv.x; o[1] = (f16)hv.y;
        *(f16x2*)(zaB + swz_off(row, (128 + c2) * 2, 512)) = o;
    }
    __syncthreads();

    f32x4 acc[2][2];
#pragma unroll
    for (int rt = 0; rt < 2; rt++)
#pragma unroll
        for (int n = 0; n < 2; n++)
#pragma unroll
            for (int j = 0; j < 4; j++) acc[rt][n][j] = 0.0f;
#pragma unroll
    for (int ks = 0; ks < 8; ks++) {
        int kk = ks * 32 + lh * 8;
        f16x8 a0 = *(const f16x8*)(zaB + swz_off(lr,      kk * 2, 512));
        f16x8 a1 = *(const f16x8*)(zaB + swz_off(lr + 16, kk * 2, 512));
#pragma unroll
        for (int ntl = 0; ntl < 2; ntl++) {
            f16x8 b = *(const f16x8*)(Wf1F + ((size_t)((w * 2 + ntl) * 8 + ks) * 64 + l) * 8);
            acc[0][ntl] = __builtin_amdgcn_mfma_f32_16x16x32_f16(a0, b, acc[0][ntl], 0, 0, 0);
            acc[1][ntl] = __builtin_amdgcn_mfma_f32_16x16x32_f16(a1, b, acc[1][ntl], 0, 0, 0);
        }
    }
    __syncthreads();  // za reads done before fs overwrite

#pragma unroll
    for (int rt = 0; rt < 2; rt++)
#pragma unroll
        for (int ntl = 0; ntl < 2; ntl++) {
            int cg = (w * 2 + ntl) * 16 + lr;
#pragma unroll
            for (int j = 0; j < 4; j++) {
                int row = rt * 16 + lh * 4 + j;
                fs[row][cg] = fmaxf(acc[rt][ntl][j] + bf1[cg], 0.0f);
            }
        }
    __syncthreads();

    if (tid < 64) {
        int n = tid >> 1, o = tid & 1;
        int gn = n0 + n;
        if (gn < NODES) {
            float a = bf2[o];
#pragma unroll 16
            for (int c = 0; c < C; c++) a = fmaf(fs[n][c], Wf2[c * 2 + o], a);
            out[(size_t)gn * 2 + o] = a;
        }
    }
}

extern "C" void kernel_launch(void* const* d_in, const int* in_sizes, int n_in,
                              void* d_out, int out_size, void* d_ws, size_t ws_size,
                              hipStream_t stream) {
    const float* x    = (const float*)d_in[0];
    const int*   eidx = (const int*)d_in[1];
    const float* eattr= (const float*)d_in[2];
    const float* Wpre = (const float*)d_in[3];  const float* bpre = (const float*)d_in[4];
    const float* Winit= (const float*)d_in[5];  const float* binit= (const float*)d_in[6];
    const float* Wg1  = (const float*)d_in[7];  const float* bg1  = (const float*)d_in[8];
    const float* Wg2  = (const float*)d_in[9];  const float* bg2  = (const float*)d_in[10];
    const float* Wz   = (const float*)d_in[11]; const float* bz   = (const float*)d_in[12];
    const float* Wr   = (const float*)d_in[13]; const float* br   = (const float*)d_in[14];
    const float* Wh   = (const float*)d_in[15]; const float* bh   = (const float*)d_in[16];
    const float* Wf1  = (const float*)d_in[17]; const float* bf1  = (const float*)d_in[18];
    const float* Wf2  = (const float*)d_in[19]; const float* bf2  = (const float*)d_in[20];
    float* out = (float*)d_out;

    float* ws  = (float*)d_ws;
    float* dis = ws;                               // N (deg during preamble, then rsqrt)
    float* h   = dis + NODES;                      // N*C f32
    float* A   = h + (size_t)NODES * C;            // N*GH f32
    int*   start = (int*)(A + (size_t)NODES * GH);     // N+1
    int*   cursor = start + NODES + 1;                 // N+1
    int*   bsum  = cursor + NODES + 1;                 // SCB
    int*   bscan = bsum + SCB;                         // SCB
    int*   row_sorted = bscan + SCB;                   // ETOT
    float* ea_sorted  = (float*)(row_sorted + ETOT);   // ETOT
    size_t f16_base = (size_t)((ea_sorted + ETOT) - ws);
    f16_base = (f16_base + 3) & ~(size_t)3;            // 16B align
    f16* h0_16  = (f16*)(ws + f16_base);               // N*C f16
    f16* rec    = h0_16 + (size_t)NODES * C;           // N*RECS f16
    f16* aggr16 = rec + (size_t)NODES * RECS;          // N*C f16
    f16* WcatF  = aggr16 + (size_t)NODES * C;          // 24*8*64*8 f16
    f16* WhtopF = WcatF + 24 * 8 * 64 * 8;
    f16* Wg1F   = WhtopF + 8 * 4 * 64 * 8;
    f16* Wf1F   = Wg1F + 4 * 4 * 64 * 8;
    size_t f16_total = (size_t)NODES * (C + RECS + C) + (24 * 8 + 8 * 4 + 4 * 4 + 8 * 8) * 64 * 8;
    const size_t REQ = (f16_base + (f16_total + 1) / 2) * sizeof(float);
    if (ws_size < REQ) return;

    hipMemsetAsync(dis, 0, NODES * sizeof(float), stream);
    k_degree<<<(NEDGES + 255) / 256, 256, 0, stream>>>(eidx + NEDGES, dis);
    k_scan1<<<SCB, SCT, 0, stream>>>(dis, bsum);
    k_scan2<<<1, 64, 0, stream>>>(bsum, bscan, start);
    k_scan3<<<SCB, SCT, 0, stream>>>(dis, bscan, start, cursor);   // also writes dis
    k_csr<<<(ETOT + 255) / 256, 256, 0, stream>>>(eidx, eattr, cursor, row_sorted, ea_sorted);
    k_prep_w<<<(24 * 8 * 64 + 8 * 4 * 64 + 4 * 4 * 64 + 8 * 8 * 64 + 255) / 256, 256, 0, stream>>>(
        Wz, Wr, Wh, Wg1, Wf1, WcatF, WhtopF, Wg1F, Wf1F);
    k_preproc<<<(NODES + 255) / 256, 256, 0, stream>>>(x, Wpre, bpre, Winit, binit, h0_16, h);
    k_gate0_mfma<<<(NODES + 31) / 32, 256, 0, stream>>>(h, dis, Wg1F, bg1, A, rec);

    for (int l = 0; l < LAYERS; l++) {
        k_msg<<<(NODES * 64 + 255) / 256, 256, 0, stream>>>(
            start, row_sorted, ea_sorted, dis, A, rec, Wg1, Wg2, bg2, aggr16);
        k_update_mfma<<<(NODES + 31) / 32, 256, 0, stream>>>(
            h, aggr16, dis, rec, WcatF, WhtopF, Wg1F, bz, br, bh, bg1, A);
    }
    k_final_mfma<<<(NODES + 31) / 32, 256, 0, stream>>>(h0_16, h, Wf1F, bf1, Wf2, bf2, out);
}

// Round 10
// 730.455 us; speedup vs baseline: 12.5153x; 1.0357x over previous
//
#include <hip/hip_runtime.h>
#include <math.h>

#define NODES 50000
#define NEDGES 800000
#define ETOT (NEDGES + NODES)
#define FIN 16
#define PRE 32
#define C 128
#define GH 32
#define LAYERS 5
#define RECS 160   // f16 per node record: [B16perm:32 | hd16:128] where hd = dis[n]*h[n]
#define SCB 64     // scan blocks
#define SCT 256    // scan threads/block
#define SCCH ((NODES + SCB*SCT - 1) / (SCB*SCT))   // elems per thread (=4)

typedef _Float16 f16;
typedef f16 f16x8 __attribute__((ext_vector_type(8)));
typedef f16 f16x4 __attribute__((ext_vector_type(4)));
typedef f16 f16x2 __attribute__((ext_vector_type(2)));
typedef float f32x4 __attribute__((ext_vector_type(4)));

__device__ __forceinline__ float sigmoidf_(float x) { return 1.0f / (1.0f + __expf(-x)); }

// XOR-swizzled LDS byte offset: 16B-block index ^= (row&7)
__device__ __forceinline__ int swz_off(int row, int bytecol, int stride) {
    return row * stride + ((((bytecol) >> 4) ^ (row & 7)) << 4) + (bytecol & 15);
}

// B channel c (0..31) -> permuted record position, so msg lane k8 reads f16x4
__device__ __forceinline__ int bperm(int c) { return 4 * (c & 7) + (c >> 3); }

__global__ void k_degree(const int* __restrict__ col, float* __restrict__ deg) {
    int e = blockIdx.x * blockDim.x + threadIdx.x;
    if (e < NEDGES) atomicAdd(&deg[col[e]], 1.0f);
}

// parallel scan, stage 1: per-block sums of (deg+1)
__global__ __launch_bounds__(SCT) void k_scan1(const float* __restrict__ deg, int* __restrict__ bsum) {
    __shared__ int ws4[SCT / 64];
    int b = blockIdx.x, t = threadIdx.x;
    int lane = t & 63, wv = t >> 6;
    int base = (b * SCT + t) * SCCH;
    int sum = 0;
#pragma unroll
    for (int j = 0; j < SCCH; j++) {
        int i = base + j;
        if (i < NODES) sum += (int)deg[i] + 1;
    }
#pragma unroll
    for (int off = 32; off > 0; off >>= 1) sum += __shfl_xor(sum, off, 64);
    if (lane == 0) ws4[wv] = sum;
    __syncthreads();
    if (t == 0) {
        int tot = 0;
#pragma unroll
        for (int j = 0; j < SCT / 64; j++) tot += ws4[j];
        bsum[b] = tot;
    }
}

// stage 2: exclusive scan of SCB block sums (single wave)
__global__ __launch_bounds__(64) void k_scan2(const int* __restrict__ bsum, int* __restrict__ bscan,
                                              int* __restrict__ start) {
    int t = threadIdx.x;
    int v = (t < SCB) ? bsum[t] : 0;
    int x = v;
#pragma unroll
    for (int off = 1; off < 64; off <<= 1) {
        int tt = __shfl_up(x, off, 64);
        if (t >= off) x += tt;
    }
    if (t < SCB) bscan[t] = x - v;
    if (t == SCB - 1) start[NODES] = x;
}

// stage 3: per-element exclusive prefix -> start/cursor; also dis = rsqrt(deg+1) in-place
__global__ __launch_bounds__(SCT) void k_scan3(
    float* __restrict__ deg_dis, const int* __restrict__ bscan,
    int* __restrict__ start, int* __restrict__ cursor) {
    __shared__ int woff[SCT / 64];
    int b = blockIdx.x, t = threadIdx.x;
    int lane = t & 63, wv = t >> 6;
    int base = (b * SCT + t) * SCCH;
    int v[SCCH]; int sum = 0;
#pragma unroll
    for (int j = 0; j < SCCH; j++) {
        int i = base + j;
        v[j] = (i < NODES) ? (int)deg_dis[i] + 1 : 0;
        sum += v[j];
    }
    int x = sum;
#pragma unroll
    for (int off = 1; off < 64; off <<= 1) {
        int tt = __shfl_up(x, off, 64);
        if (lane >= off) x += tt;
    }
    int texcl = x - sum;
    if (lane == 63) woff[wv] = x;
    __syncthreads();
    int wbase = 0;
    for (int j = 0; j < wv; j++) wbase += woff[j];
    int run = bscan[b] + wbase + texcl;
#pragma unroll
    for (int j = 0; j < SCCH; j++) {
        int i = base + j;
        if (i < NODES) {
            start[i] = run; cursor[i] = run;
            deg_dis[i] = rsqrtf((float)v[j]);
        }
        run += v[j];
    }
}

__global__ __launch_bounds__(256) void k_csr(
    const int* __restrict__ eidx, const float* __restrict__ eattr,
    int* __restrict__ cursor,
    int* __restrict__ row_sorted, float* __restrict__ ea_sorted) {
    int e = blockIdx.x * blockDim.x + threadIdx.x;
    if (e >= ETOT) return;
    int r, ci; float ea;
    if (e < NEDGES) { r = eidx[e]; ci = eidx[NEDGES + e]; ea = eattr[e]; }
    else            { r = ci = e - NEDGES; ea = 0.0f; }
    int slot = atomicAdd(&cursor[ci], 1);
    row_sorted[slot] = r;
    ea_sorted[slot] = ea;
}

// fragment-ordered f16 weight buffers.
// WcatF: K=256, 24 col-tiles ordered per-wave [z0,z1,r0,r1,p0,p1] (wave wv owns tiles wv*6..+5)
// WhtopF: K=128 -> 128 cols; Wg1F: K=128 -> 64 (A|B); Wf1F: K=256 -> 128
__global__ __launch_bounds__(256) void k_prep_w(
    const float* __restrict__ Wz, const float* __restrict__ Wr, const float* __restrict__ Wh,
    const float* __restrict__ Wg1, const float* __restrict__ Wf1,
    f16* __restrict__ WcatF, f16* __restrict__ WhtopF, f16* __restrict__ Wg1F,
    f16* __restrict__ Wf1F) {
    int t = blockIdx.x * 256 + threadIdx.x;
    int l = t & 63;
    int lr = l & 15, lh = l >> 4;
    if (t < 24 * 8 * 64) {
        int idx = t >> 6; int nt = idx >> 3, ks = idx & 7;
        int wv = nt / 6, ntl = nt % 6;
        int grp = ntl >> 1, pr = ntl & 1;
        int ncol = (2 * wv + pr) * 16 + lr;
        f16x8 v;
#pragma unroll
        for (int j = 0; j < 8; j++) {
            int k = ks * 32 + lh * 8 + j;
            float x;
            if (grp == 0)      x = Wz[k * 128 + ncol];
            else if (grp == 1) x = Wr[k * 128 + ncol];
            else               x = (k >= 128) ? Wh[k * 128 + ncol] : 0.0f;
            v[j] = (f16)x;
        }
        *(f16x8*)(WcatF + (size_t)t * 8) = v;
    } else if (t < 24 * 8 * 64 + 8 * 4 * 64) {
        int t2 = t - 24 * 8 * 64;
        int idx = t2 >> 6; int nt = idx >> 2, ks = idx & 3;
        int n = nt * 16 + lr;
        f16x8 v;
#pragma unroll
        for (int j = 0; j < 8; j++) {
            int k = ks * 32 + lh * 8 + j;
            v[j] = (f16)Wh[k * 128 + n];
        }
        *(f16x8*)(WhtopF + (size_t)t2 * 8) = v;
    } else if (t < 24 * 8 * 64 + 8 * 4 * 64 + 4 * 4 * 64) {
        int t3 = t - (24 * 8 * 64 + 8 * 4 * 64);
        int idx = t3 >> 6; int nt = idx >> 2, ks = idx & 3;
        int cg = nt * 16 + lr;
        f16x8 v;
#pragma unroll
        for (int j = 0; j < 8; j++) {
            int k = ks * 32 + lh * 8 + j;
            v[j] = (f16)((cg < 32) ? Wg1[k * GH + cg] : Wg1[(128 + k) * GH + (cg - 32)]);
        }
        *(f16x8*)(Wg1F + (size_t)t3 * 8) = v;
    } else if (t < 24 * 8 * 64 + 8 * 4 * 64 + 4 * 4 * 64 + 8 * 8 * 64) {
        int t4 = t - (24 * 8 * 64 + 8 * 4 * 64 + 4 * 4 * 64);
        int idx = t4 >> 6; int nt = idx >> 3, ks = idx & 7;
        int n = nt * 16 + lr;
        f16x8 v;
#pragma unroll
        for (int j = 0; j < 8; j++) {
            int k = ks * 32 + lh * 8 + j;
            v[j] = (f16)Wf1[k * 128 + n];
        }
        *(f16x8*)(Wf1F + (size_t)t4 * 8) = v;
    }
}

// wave-per-node preproc: coalesced writes. pre[32] in lanes 0-31, shared via shfl.
__global__ __launch_bounds__(256) void k_preproc(
    const float* __restrict__ x, const float* __restrict__ Wpre, const float* __restrict__ bpre,
    const float* __restrict__ Winit, const float* __restrict__ binit,
    f16* __restrict__ h0_16, float* __restrict__ h) {
    __shared__ float sWpre[FIN * PRE], sbpre[PRE], sWinit[PRE * C], sbinit[C];
    for (int i = threadIdx.x; i < FIN * PRE; i += blockDim.x) sWpre[i] = Wpre[i];
    for (int i = threadIdx.x; i < PRE; i += blockDim.x) sbpre[i] = bpre[i];
    for (int i = threadIdx.x; i < PRE * C; i += blockDim.x) sWinit[i] = Winit[i];
    for (int i = threadIdx.x; i < C; i += blockDim.x) sbinit[i] = binit[i];
    __syncthreads();
    int wave = (blockIdx.x * blockDim.x + threadIdx.x) >> 6;
    int lane = threadIdx.x & 63;
    if (wave >= NODES) return;
    float xk = (lane < FIN) ? x[(size_t)wave * FIN + lane] : 0.0f;
    float pre = (lane < PRE) ? sbpre[lane] : 0.0f;
#pragma unroll
    for (int i = 0; i < FIN; i++) {
        float xi = __shfl(xk, i, 64);
        pre = fmaf(xi, (lane < PRE) ? sWpre[i * PRE + lane] : 0.0f, pre);
    }
    pre = fmaxf(pre, 0.0f);
    int c = lane * 2;
    float a0 = sbinit[c], a1 = sbinit[c + 1];
#pragma unroll
    for (int j = 0; j < PRE; j++) {
        float pj = __shfl(pre, j, 64);
        a0 = fmaf(pj, sWinit[j * C + c], a0);
        a1 = fmaf(pj, sWinit[j * C + c + 1], a1);
    }
    a0 = fmaxf(a0, 0.0f); a1 = fmaxf(a1, 0.0f);
    *(float2*)&h[(size_t)wave * C + c] = make_float2(a0, a1);
    f16x2 o; o[0] = (f16)a0; o[1] = (f16)a1;
    *(f16x2*)&h0_16[(size_t)wave * C + c] = o;
}

// layer-0 gate via MFMA: A|B16 = h @ Wg1F (+bg1 on A); also rec hd16 = dis*h during staging.
__global__ __launch_bounds__(256) void k_gate0_mfma(
    const float* __restrict__ h, const float* __restrict__ dis,
    const f16* __restrict__ Wg1F, const float* __restrict__ bg1,
    float* __restrict__ A, f16* __restrict__ rec) {
    __shared__ f16 za[32 * 128];    // swizzled, row stride 256B
    char* zaB = (char*)za;
    int tid = threadIdx.x;
    int l = tid & 63, w = tid >> 6;
    int lr = l & 15, lh = l >> 4;
    int n0 = blockIdx.x * 32;

    for (int p = tid; p < 32 * 64; p += 256) {
        int row = p >> 6;
        int c2 = (p & 63) * 2;
        int gn = n0 + row;
        float2 v = make_float2(0.0f, 0.0f);
        if (gn < NODES) v = *(const float2*)&h[(size_t)gn * C + c2];
        f16x2 o; o[0] = (f16)v.x; o[1] = (f16)v.y;
        *(f16x2*)(zaB + swz_off(row, c2 * 2, 256)) = o;
        if (gn < NODES) {
            float dn = dis[gn];
            f16x2 od; od[0] = (f16)(v.x * dn); od[1] = (f16)(v.y * dn);
            *(f16x2*)(rec + (size_t)gn * RECS + 32 + c2) = od;
        }
    }
    __syncthreads();

    f32x4 acc3[2];
#pragma unroll
    for (int rt = 0; rt < 2; rt++)
#pragma unroll
        for (int j = 0; j < 4; j++) acc3[rt][j] = 0.0f;
#pragma unroll
    for (int ks = 0; ks < 4; ks++) {
        int kk = ks * 32 + lh * 8;
        f16x8 a0 = *(const f16x8*)(zaB + swz_off(lr,      kk * 2, 256));
        f16x8 a1 = *(const f16x8*)(zaB + swz_off(lr + 16, kk * 2, 256));
        f16x8 b = *(const f16x8*)(Wg1F + ((size_t)(w * 4 + ks) * 64 + l) * 8);
        acc3[0] = __builtin_amdgcn_mfma_f32_16x16x32_f16(a0, b, acc3[0], 0, 0, 0);
        acc3[1] = __builtin_amdgcn_mfma_f32_16x16x32_f16(a1, b, acc3[1], 0, 0, 0);
    }
    int col3 = w * 16 + lr;
#pragma unroll
    for (int rt = 0; rt < 2; rt++)
#pragma unroll
        for (int j = 0; j < 4; j++) {
            int row = rt * 16 + lh * 4 + j;
            int gn = n0 + row;
            if (gn < NODES) {
                float v = acc3[rt][j];
                if (col3 < 32) A[(size_t)gn * GH + col3] = v + bg1[col3];
                else           rec[(size_t)gn * RECS + bperm(col3 - 32)] = (f16)v;
            }
        }
}

// fused gate+aggregate: wave per node, EIGHTH-WAVE (8 lanes) per edge, 1-deep prefetch.
// Lane k8 handles gate channels {k8,k8+8,k8+16,k8+24} (one f16x4 via bperm) and hd
// channels [k8*16, k8*16+16).
__global__ __launch_bounds__(256) void k_msg(
    const int* __restrict__ start, const int* __restrict__ row_sorted,
    const float* __restrict__ ea_sorted, const float* __restrict__ dis,
    const float* __restrict__ A, const f16* __restrict__ rec,
    const float* __restrict__ Wg1, const float* __restrict__ Wg2, const float* __restrict__ bg2,
    f16* __restrict__ aggr16) {
    int wid = (blockIdx.x * blockDim.x + threadIdx.x) >> 6;
    int lane = threadIdx.x & 63;
    if (wid >= NODES) return;
    int k8 = lane & 7;
    int q = lane >> 3;
    int s0 = start[wid], s1 = start[wid + 1];
    float a_0 = A[(size_t)wid * GH + k8];
    float a_1 = A[(size_t)wid * GH + k8 + 8];
    float a_2 = A[(size_t)wid * GH + k8 + 16];
    float a_3 = A[(size_t)wid * GH + k8 + 24];
    const float* wg1e = Wg1 + 2 * C * GH;
    float wea0 = wg1e[k8], wea1 = wg1e[k8 + 8], wea2 = wg1e[k8 + 16], wea3 = wg1e[k8 + 24];
    float w20 = Wg2[k8], w21 = Wg2[k8 + 8], w22 = Wg2[k8 + 16], w23 = Wg2[k8 + 24];
    float b2 = bg2[0];
    float dci = dis[wid];
    float acc[16];
#pragma unroll
    for (int j = 0; j < 16; j++) acc[j] = 0.0f;

    int s = s0 + q;
    f16x8 ha0 = {}, hb0 = {};
    f16x4 bb0 = {};
    float ea0 = 0.0f;
    if (s < s1) {
        int r = row_sorted[s];
        ea0 = ea_sorted[s];
        const f16* rr = rec + (size_t)r * RECS;
        bb0 = *(const f16x4*)(rr + k8 * 4);
        ha0 = *(const f16x8*)(rr + 32 + k8 * 16);
        hb0 = *(const f16x8*)(rr + 32 + k8 * 16 + 8);
    }
    while (s < s1) {
        int s2 = s + 8;
        f16x8 ha1 = {}, hb1 = {};
        f16x4 bb1 = {};
        float ea1 = 0.0f;
        if (s2 < s1) {                       // prefetch next edge's record
            int r = row_sorted[s2];
            ea1 = ea_sorted[s2];
            const f16* rr = rec + (size_t)r * RECS;
            bb1 = *(const f16x4*)(rr + k8 * 4);
            ha1 = *(const f16x8*)(rr + 32 + k8 * 16);
            hb1 = *(const f16x8*)(rr + 32 + k8 * 16 + 8);
        }
        float t0 = fmaxf(a_0 + (float)bb0[0] + ea0 * wea0, 0.0f);
        float t1 = fmaxf(a_1 + (float)bb0[1] + ea0 * wea1, 0.0f);
        float t2 = fmaxf(a_2 + (float)bb0[2] + ea0 * wea2, 0.0f);
        float t3 = fmaxf(a_3 + (float)bb0[3] + ea0 * wea3, 0.0f);
        float p = t0 * w20;
        p = fmaf(t1, w21, p);
        p = fmaf(t2, w22, p);
        p = fmaf(t3, w23, p);
        p += __shfl_xor(p, 4, 8);
        p += __shfl_xor(p, 2, 8);
        p += __shfl_xor(p, 1, 8);
        float coef = sigmoidf_(p + b2);
#pragma unroll
        for (int j = 0; j < 8; j++) {
            acc[j]     = fmaf(coef, (float)ha0[j], acc[j]);
            acc[8 + j] = fmaf(coef, (float)hb0[j], acc[8 + j]);
        }
        ha0 = ha1; hb0 = hb1; bb0 = bb1; ea0 = ea1;
        s = s2;
    }
#pragma unroll
    for (int j = 0; j < 16; j++) {
        acc[j] += __shfl_xor(acc[j], 8, 64);
        acc[j] += __shfl_xor(acc[j], 16, 64);
        acc[j] += __shfl_xor(acc[j], 32, 64);
    }
    if (lane < 8) {
        f16x8 o1, o2;
#pragma unroll
        for (int j = 0; j < 8; j++) { o1[j] = (f16)(acc[j] * dci); o2[j] = (f16)(acc[8 + j] * dci); }
        *(f16x8*)(aggr16 + (size_t)wid * C + k8 * 16) = o1;
        *(f16x8*)(aggr16 + (size_t)wid * C + k8 * 16 + 8) = o2;
    }
}

// GRU update via MFMA; per-wave column-tile ownership keeps z,p in registers.
// Reads h f32 + aggr16; writes h f32, rec = {B16perm|hd16}, A f32.
__global__ __launch_bounds__(256) void k_update_mfma(
    float* __restrict__ h, const f16* __restrict__ aggr16, const float* __restrict__ dis,
    f16* __restrict__ rec,
    const f16* __restrict__ WcatF, const f16* __restrict__ WhtopF, const f16* __restrict__ Wg1F,
    const float* __restrict__ bz, const float* __restrict__ br, const float* __restrict__ bh,
    const float* __restrict__ bg1,
    float* __restrict__ A) {
    __shared__ f16 za[32 * 256];    // swizzled, row stride 512B; reused for h_new staging
    __shared__ f16 rhbuf[32 * 128]; // swizzled, row stride 256B
    char* zaB = (char*)za;
    char* rhB = (char*)rhbuf;
    int tid = threadIdx.x;
    int l = tid & 63, w = tid >> 6;
    int lr = l & 15, lh = l >> 4;
    int n0 = blockIdx.x * 32;

    // stage za = [(f16)h | aggr16]
    for (int p = tid; p < 32 * 64; p += 256) {
        int row = p >> 6;
        int c2 = (p & 63) * 2;
        int gn = n0 + row;
        float2 v = make_float2(0.0f, 0.0f);
        if (gn < NODES) v = *(const float2*)&h[(size_t)gn * C + c2];
        f16x2 o; o[0] = (f16)v.x; o[1] = (f16)v.y;
        *(f16x2*)(zaB + swz_off(row, c2 * 2, 512)) = o;
    }
    for (int p = tid; p < 32 * 16; p += 256) {
        int row = p >> 4, seg = p & 15;
        int gn = n0 + row;
        f16x8 v;
#pragma unroll
        for (int j = 0; j < 8; j++) v[j] = (f16)0.0f;
        if (gn < NODES) v = *(const f16x8*)(aggr16 + (size_t)gn * C + seg * 8);
        *(f16x8*)(zaB + swz_off(row, 256 + seg * 16, 512)) = v;
    }
    __syncthreads();

    // GEMM1: tiles [z0,z1,r0,r1,p0,p1] per wave
    f32x4 acc[2][6];
#pragma unroll
    for (int rt = 0; rt < 2; rt++)
#pragma unroll
        for (int n = 0; n < 6; n++)
#pragma unroll
            for (int j = 0; j < 4; j++) acc[rt][n][j] = 0.0f;
#pragma unroll
    for (int ks = 0; ks < 8; ks++) {
        int kk = ks * 32 + lh * 8;
        f16x8 a0 = *(const f16x8*)(zaB + swz_off(lr,      kk * 2, 512));
        f16x8 a1 = *(const f16x8*)(zaB + swz_off(lr + 16, kk * 2, 512));
#pragma unroll
        for (int ntl = 0; ntl < 6; ntl++) {
            f16x8 b = *(const f16x8*)(WcatF + ((size_t)((w * 6 + ntl) * 8 + ks) * 64 + l) * 8);
            acc[0][ntl] = __builtin_amdgcn_mfma_f32_16x16x32_f16(a0, b, acc[0][ntl], 0, 0, 0);
            acc[1][ntl] = __builtin_amdgcn_mfma_f32_16x16x32_f16(a1, b, acc[1][ntl], 0, 0, 0);
        }
    }

    // epilogue1: z->reg (sigmoid), r*h -> rhbuf (h from za), p stays in acc[rt][4/5]
    float zreg[2][2][4];
#pragma unroll
    for (int rt = 0; rt < 2; rt++)
#pragma unroll
        for (int pr = 0; pr < 2; pr++) {
            int cg = (2 * w + pr) * 16 + lr;
#pragma unroll
            for (int j = 0; j < 4; j++) {
                int row = rt * 16 + lh * 4 + j;
                zreg[rt][pr][j] = sigmoidf_(acc[rt][pr][j] + bz[cg]);
                float rv = sigmoidf_(acc[rt][2 + pr][j] + br[cg]);
                float hv = (float)*(const f16*)(zaB + swz_off(row, cg * 2, 512));
                *(f16*)(rhB + swz_off(row, cg * 2, 256)) = (f16)(rv * hv);
            }
        }
    __syncthreads();

    // GEMM2: hc_pre = p + bh + (r*h) @ Wh_top
    f32x4 acc2[2][2];
#pragma unroll
    for (int rt = 0; rt < 2; rt++)
#pragma unroll
        for (int pr = 0; pr < 2; pr++) {
            int cg = (2 * w + pr) * 16 + lr;
#pragma unroll
            for (int j = 0; j < 4; j++)
                acc2[rt][pr][j] = acc[rt][4 + pr][j] + bh[cg];
        }
#pragma unroll
    for (int ks = 0; ks < 4; ks++) {
        int kk = ks * 32 + lh * 8;
        f16x8 a0 = *(const f16x8*)(rhB + swz_off(lr,      kk * 2, 256));
        f16x8 a1 = *(const f16x8*)(rhB + swz_off(lr + 16, kk * 2, 256));
#pragma unroll
        for (int pr = 0; pr < 2; pr++) {
            f16x8 b = *(const f16x8*)(WhtopF + ((size_t)((w * 2 + pr) * 4 + ks) * 64 + l) * 8);
            acc2[0][pr] = __builtin_amdgcn_mfma_f32_16x16x32_f16(a0, b, acc2[0][pr], 0, 0, 0);
            acc2[1][pr] = __builtin_amdgcn_mfma_f32_16x16x32_f16(a1, b, acc2[1][pr], 0, 0, 0);
        }
    }

    // epilogue2: h_new; write h f32 + rec hd16 (dis-scaled); stage h_new into za for GEMM3
#pragma unroll
    for (int rt = 0; rt < 2; rt++)
#pragma unroll
        for (int pr = 0; pr < 2; pr++) {
            int cg = (2 * w + pr) * 16 + lr;
#pragma unroll
            for (int j = 0; j < 4; j++) {
                int row = rt * 16 + lh * 4 + j;
                int gn = n0 + row;
                float hc = fmaxf(acc2[rt][pr][j], 0.0f);
                float z = zreg[rt][pr][j];
                float hold = (gn < NODES) ? h[(size_t)gn * C + cg] : 0.0f;
                float hn = (1.0f - z) * hold + z * hc;
                if (gn < NODES) {
                    h[(size_t)gn * C + cg] = hn;
                    rec[(size_t)gn * RECS + 32 + cg] = (f16)(hn * dis[gn]);
                }
                *(f16*)(zaB + swz_off(row, cg * 2, 512)) = (f16)hn;
            }
        }
    __syncthreads();

    // GEMM3: A|B16 = h_new @ Wg1F
    f32x4 acc3[2];
#pragma unroll
    for (int rt = 0; rt < 2; rt++)
#pragma unroll
        for (int j = 0; j < 4; j++) acc3[rt][j] = 0.0f;
#pragma unroll
    for (int ks = 0; ks < 4; ks++) {
        int kk = ks * 32 + lh * 8;
        f16x8 a0 = *(const f16x8*)(zaB + swz_off(lr,      kk * 2, 512));
        f16x8 a1 = *(const f16x8*)(zaB + swz_off(lr + 16, kk * 2, 512));
        f16x8 b = *(const f16x8*)(Wg1F + ((size_t)(w * 4 + ks) * 64 + l) * 8);
        acc3[0] = __builtin_amdgcn_mfma_f32_16x16x32_f16(a0, b, acc3[0], 0, 0, 0);
        acc3[1] = __builtin_amdgcn_mfma_f32_16x16x32_f16(a1, b, acc3[1], 0, 0, 0);
    }
    int col3 = w * 16 + lr;
#pragma unroll
    for (int rt = 0; rt < 2; rt++)
#pragma unroll
        for (int j = 0; j < 4; j++) {
            int row = rt * 16 + lh * 4 + j;
            int gn = n0 + row;
            if (gn < NODES) {
                float v = acc3[rt][j];
                if (col3 < 32) A[(size_t)gn * GH + col3] = v + bg1[col3];
                else           rec[(size_t)gn * RECS + bperm(col3 - 32)] = (f16)v;
            }
        }
}

// final head via MFMA: f = relu([h0_16|h]@Wf1+bf1); out = f@Wf2+bf2
__global__ __launch_bounds__(256) void k_final_mfma(
    const f16* __restrict__ h0_16, const float* __restrict__ h,
    const f16* __restrict__ Wf1F, const float* __restrict__ bf1,
    const float* __restrict__ Wf2, const float* __restrict__ bf2,
    float* __restrict__ out) {
    __shared__ float fs[32][132];   // aliased during stage/GEMM as f16 za [32][256] swizzled
    char* zaB = (char*)&fs[0][0];
    int tid = threadIdx.x;
    int l = tid & 63, w = tid >> 6;
    int lr = l & 15, lh = l >> 4;
    int n0 = blockIdx.x * 32;

    for (int p = tid; p < 32 * 16; p += 256) {
        int row = p >> 4, seg = p & 15;
        int gn = n0 + row;
        f16x8 v;
#pragma unroll
        for (int j = 0; j < 8; j++) v[j] = (f16)0.0f;
        if (gn < NODES) v = *(const f16x8*)(h0_16 + (size_t)gn * C + seg * 8);
        *(f16x8*)(zaB + swz_off(row, seg * 16, 512)) = v;
    }
    for (int p = tid; p < 32 * 64; p += 256) {
        int row = p >> 6;
        int c2 = (p & 63) * 2;
        int gn = n0 + row;
        float2 hv = make_float2(0.0f, 0.0f);
        if (gn < NODES) hv = *(const float2*)&h[(size_t)gn * C + c2];
        f16x2 o; o[0] = (f16)hv.x; o[1] = (f16)hv.y;
        *(f16x2*)(zaB + swz_off(row, (128 + c2) * 2, 512)) = o;
    }
    __syncthreads();

    f32x4 acc[2][2];
#pragma unroll
    for (int rt = 0; rt < 2; rt++)
#pragma unroll
        for (int n = 0; n < 2; n++)
#pragma unroll
            for (int j = 0; j < 4; j++) acc[rt][n][j] = 0.0f;
#pragma unroll
    for (int ks = 0; ks < 8; ks++) {
        int kk = ks * 32 + lh * 8;
        f16x8 a0 = *(const f16x8*)(zaB + swz_off(lr,      kk * 2, 512));
        f16x8 a1 = *(const f16x8*)(zaB + swz_off(lr + 16, kk * 2, 512));
#pragma unroll
        for (int ntl = 0; ntl < 2; ntl++) {
            f16x8 b = *(const f16x8*)(Wf1F + ((size_t)((w * 2 + ntl) * 8 + ks) * 64 + l) * 8);
            acc[0][ntl] = __builtin_amdgcn_mfma_f32_16x16x32_f16(a0, b, acc[0][ntl], 0, 0, 0);
            acc[1][ntl] = __builtin_amdgcn_mfma_f32_16x16x32_f16(a1, b, acc[1][ntl], 0, 0, 0);
        }
    }
    __syncthreads();  // za reads done before fs overwrite

#pragma unroll
    for (int rt = 0; rt < 2; rt++)
#pragma unroll
        for (int ntl = 0; ntl < 2; ntl++) {
            int cg = (w * 2 + ntl) * 16 + lr;
#pragma unroll
            for (int j = 0; j < 4; j++) {
                int row = rt * 16 + lh * 4 + j;
                fs[row][cg] = fmaxf(acc[rt][ntl][j] + bf1[cg], 0.0f);
            }
        }
    __syncthreads();

    if (tid < 64) {
        int n = tid >> 1, o = tid & 1;
        int gn = n0 + n;
        if (gn < NODES) {
            float a = bf2[o];
#pragma unroll 16
            for (int c = 0; c < C; c++) a = fmaf(fs[n][c], Wf2[c * 2 + o], a);
            out[(size_t)gn * 2 + o] = a;
        }
    }
}

extern "C" void kernel_launch(void* const* d_in, const int* in_sizes, int n_in,
                              void* d_out, int out_size, void* d_ws, size_t ws_size,
                              hipStream_t stream) {
    const float* x    = (const float*)d_in[0];
    const int*   eidx = (const int*)d_in[1];
    const float* eattr= (const float*)d_in[2];
    const float* Wpre = (const float*)d_in[3];  const float* bpre = (const float*)d_in[4];
    const float* Winit= (const float*)d_in[5];  const float* binit= (const float*)d_in[6];
    const float* Wg1  = (const float*)d_in[7];  const float* bg1  = (const float*)d_in[8];
    const float* Wg2  = (const float*)d_in[9];  const float* bg2  = (const float*)d_in[10];
    const float* Wz   = (const float*)d_in[11]; const float* bz   = (const float*)d_in[12];
    const float* Wr   = (const float*)d_in[13]; const float* br   = (const float*)d_in[14];
    const float* Wh   = (const float*)d_in[15]; const float* bh   = (const float*)d_in[16];
    const float* Wf1  = (const float*)d_in[17]; const float* bf1  = (const float*)d_in[18];
    const float* Wf2  = (const float*)d_in[19]; const float* bf2  = (const float*)d_in[20];
    float* out = (float*)d_out;

    float* ws  = (float*)d_ws;
    float* dis = ws;                               // N (deg during preamble, then rsqrt)
    float* h   = dis + NODES;                      // N*C f32
    float* A   = h + (size_t)NODES * C;            // N*GH f32
    int*   start = (int*)(A + (size_t)NODES * GH);     // N+1
    int*   cursor = start + NODES + 1;                 // N+1
    int*   bsum  = cursor + NODES + 1;                 // SCB
    int*   bscan = bsum + SCB;                         // SCB
    int*   row_sorted = bscan + SCB;                   // ETOT
    float* ea_sorted  = (float*)(row_sorted + ETOT);   // ETOT
    size_t f16_base = (size_t)((ea_sorted + ETOT) - ws);
    f16_base = (f16_base + 3) & ~(size_t)3;            // 16B align
    f16* h0_16  = (f16*)(ws + f16_base);               // N*C f16
    f16* rec    = h0_16 + (size_t)NODES * C;           // N*RECS f16
    f16* aggr16 = rec + (size_t)NODES * RECS;          // N*C f16
    f16* WcatF  = aggr16 + (size_t)NODES * C;          // 24*8*64*8 f16
    f16* WhtopF = WcatF + 24 * 8 * 64 * 8;
    f16* Wg1F   = WhtopF + 8 * 4 * 64 * 8;
    f16* Wf1F   = Wg1F + 4 * 4 * 64 * 8;
    size_t f16_total = (size_t)NODES * (C + RECS + C) + (24 * 8 + 8 * 4 + 4 * 4 + 8 * 8) * 64 * 8;
    const size_t REQ = (f16_base + (f16_total + 1) / 2) * sizeof(float);
    if (ws_size < REQ) return;

    hipMemsetAsync(dis, 0, NODES * sizeof(float), stream);
    k_degree<<<(NEDGES + 255) / 256, 256, 0, stream>>>(eidx + NEDGES, dis);
    k_scan1<<<SCB, SCT, 0, stream>>>(dis, bsum);
    k_scan2<<<1, 64, 0, stream>>>(bsum, bscan, start);
    k_scan3<<<SCB, SCT, 0, stream>>>(dis, bscan, start, cursor);   // also writes dis
    k_csr<<<(ETOT + 255) / 256, 256, 0, stream>>>(eidx, eattr, cursor, row_sorted, ea_sorted);
    k_prep_w<<<(24 * 8 * 64 + 8 * 4 * 64 + 4 * 4 * 64 + 8 * 8 * 64 + 255) / 256, 256, 0, stream>>>(
        Wz, Wr, Wh, Wg1, Wf1, WcatF, WhtopF, Wg1F, Wf1F);
    k_preproc<<<(NODES * 64 + 255) / 256, 256, 0, stream>>>(x, Wpre, bpre, Winit, binit, h0_16, h);
    k_gate0_mfma<<<(NODES + 31) / 32, 256, 0, stream>>>(h, dis, Wg1F, bg1, A, rec);

    for (int l = 0; l < LAYERS; l++) {
        k_msg<<<(NODES * 64 + 255) / 256, 256, 0, stream>>>(
            start, row_sorted, ea_sorted, dis, A, rec, Wg1, Wg2, bg2, aggr16);
        k_update_mfma<<<(NODES + 31) / 32, 256, 0, stream>>>(
            h, aggr16, dis, rec, WcatF, WhtopF, Wg1F, bz, br, bh, bg1, A);
    }
    k_final_mfma<<<(NODES + 31) / 32, 256, 0, stream>>>(h0_16, h, Wf1F, bf1, Wf2, bf2, out);
}

// Round 12
// 631.834 us; speedup vs baseline: 14.4687x; 1.1561x over previous
//
#include <hip/hip_runtime.h>
#include <math.h>

#define NODES 50000
#define NEDGES 800000
#define ETOT (NEDGES + NODES)
#define FIN 16
#define PRE 32
#define C 128
#define GH 32
#define LAYERS 5
#define RECS 160   // f16 per node record: [B16perm:32 | hd16:128] where hd = dis[n]*h[n]
#define SCB 64     // scan blocks
#define SCT 256    // scan threads/block
#define SCCH ((NODES + SCB*SCT - 1) / (SCB*SCT))   // elems per thread (=4)

typedef _Float16 f16;
typedef f16 f16x8 __attribute__((ext_vector_type(8)));
typedef f16 f16x4 __attribute__((ext_vector_type(4)));
typedef f16 f16x2 __attribute__((ext_vector_type(2)));
typedef float f32x4 __attribute__((ext_vector_type(4)));

__device__ __forceinline__ float sigmoidf_(float x) { return 1.0f / (1.0f + __expf(-x)); }

// XOR-swizzled LDS byte offset: 16B-block index ^= (row&7)
__device__ __forceinline__ int swz_off(int row, int bytecol, int stride) {
    return row * stride + ((((bytecol) >> 4) ^ (row & 7)) << 4) + (bytecol & 15);
}

// gate channel c (0..31) -> permuted position, so msg lane k8 reads one vector
__device__ __forceinline__ int bperm(int c) { return 4 * (c & 7) + (c >> 3); }

__global__ void k_degree(const int* __restrict__ col, float* __restrict__ deg) {
    int e = blockIdx.x * blockDim.x + threadIdx.x;
    if (e < NEDGES) atomicAdd(&deg[col[e]], 1.0f);
}

// parallel scan, stage 1: per-block sums of (deg+1)
__global__ __launch_bounds__(SCT) void k_scan1(const float* __restrict__ deg, int* __restrict__ bsum) {
    __shared__ int ws4[SCT / 64];
    int b = blockIdx.x, t = threadIdx.x;
    int lane = t & 63, wv = t >> 6;
    int base = (b * SCT + t) * SCCH;
    int sum = 0;
#pragma unroll
    for (int j = 0; j < SCCH; j++) {
        int i = base + j;
        if (i < NODES) sum += (int)deg[i] + 1;
    }
#pragma unroll
    for (int off = 32; off > 0; off >>= 1) sum += __shfl_xor(sum, off, 64);
    if (lane == 0) ws4[wv] = sum;
    __syncthreads();
    if (t == 0) {
        int tot = 0;
#pragma unroll
        for (int j = 0; j < SCT / 64; j++) tot += ws4[j];
        bsum[b] = tot;
    }
}

// stage 2: exclusive scan of SCB block sums (single wave)
__global__ __launch_bounds__(64) void k_scan2(const int* __restrict__ bsum, int* __restrict__ bscan,
                                              int* __restrict__ start) {
    int t = threadIdx.x;
    int v = (t < SCB) ? bsum[t] : 0;
    int x = v;
#pragma unroll
    for (int off = 1; off < 64; off <<= 1) {
        int tt = __shfl_up(x, off, 64);
        if (t >= off) x += tt;
    }
    if (t < SCB) bscan[t] = x - v;
    if (t == SCB - 1) start[NODES] = x;
}

// stage 3: per-element exclusive prefix -> start/cursor; also dis = rsqrt(deg+1) in-place
__global__ __launch_bounds__(SCT) void k_scan3(
    float* __restrict__ deg_dis, const int* __restrict__ bscan,
    int* __restrict__ start, int* __restrict__ cursor) {
    __shared__ int woff[SCT / 64];
    int b = blockIdx.x, t = threadIdx.x;
    int lane = t & 63, wv = t >> 6;
    int base = (b * SCT + t) * SCCH;
    int v[SCCH]; int sum = 0;
#pragma unroll
    for (int j = 0; j < SCCH; j++) {
        int i = base + j;
        v[j] = (i < NODES) ? (int)deg_dis[i] + 1 : 0;
        sum += v[j];
    }
    int x = sum;
#pragma unroll
    for (int off = 1; off < 64; off <<= 1) {
        int tt = __shfl_up(x, off, 64);
        if (lane >= off) x += tt;
    }
    int texcl = x - sum;
    if (lane == 63) woff[wv] = x;
    __syncthreads();
    int wbase = 0;
    for (int j = 0; j < wv; j++) wbase += woff[j];
    int run = bscan[b] + wbase + texcl;
#pragma unroll
    for (int j = 0; j < SCCH; j++) {
        int i = base + j;
        if (i < NODES) {
            start[i] = run; cursor[i] = run;
            deg_dis[i] = rsqrtf((float)v[j]);
        }
        run += v[j];
    }
}

__global__ __launch_bounds__(256) void k_csr(
    const int* __restrict__ eidx, const float* __restrict__ eattr,
    int* __restrict__ cursor,
    int* __restrict__ row_sorted, float* __restrict__ ea_sorted) {
    int e = blockIdx.x * blockDim.x + threadIdx.x;
    if (e >= ETOT) return;
    int r, ci; float ea;
    if (e < NEDGES) { r = eidx[e]; ci = eidx[NEDGES + e]; ea = eattr[e]; }
    else            { r = ci = e - NEDGES; ea = 0.0f; }
    int slot = atomicAdd(&cursor[ci], 1);
    row_sorted[slot] = r;
    ea_sorted[slot] = ea;
}

// fragment-ordered f16 weight buffers.
// WcatF: K=256, 24 col-tiles ordered per-wave [z0,z1,r0,r1,p0,p1] (wave wv owns tiles wv*6..+5)
// WhtopF: K=128 -> 128 cols; Wg1F: K=128 -> 64 (A|B); Wf1F: K=256 -> 128
__global__ __launch_bounds__(256) void k_prep_w(
    const float* __restrict__ Wz, const float* __restrict__ Wr, const float* __restrict__ Wh,
    const float* __restrict__ Wg1, const float* __restrict__ Wf1,
    f16* __restrict__ WcatF, f16* __restrict__ WhtopF, f16* __restrict__ Wg1F,
    f16* __restrict__ Wf1F) {
    int t = blockIdx.x * 256 + threadIdx.x;
    int l = t & 63;
    int lr = l & 15, lh = l >> 4;
    if (t < 24 * 8 * 64) {
        int idx = t >> 6; int nt = idx >> 3, ks = idx & 7;
        int wv = nt / 6, ntl = nt % 6;
        int grp = ntl >> 1, pr = ntl & 1;
        int ncol = (2 * wv + pr) * 16 + lr;
        f16x8 v;
#pragma unroll
        for (int j = 0; j < 8; j++) {
            int k = ks * 32 + lh * 8 + j;
            float x;
            if (grp == 0)      x = Wz[k * 128 + ncol];
            else if (grp == 1) x = Wr[k * 128 + ncol];
            else               x = (k >= 128) ? Wh[k * 128 + ncol] : 0.0f;
            v[j] = (f16)x;
        }
        *(f16x8*)(WcatF + (size_t)t * 8) = v;
    } else if (t < 24 * 8 * 64 + 8 * 4 * 64) {
        int t2 = t - 24 * 8 * 64;
        int idx = t2 >> 6; int nt = idx >> 2, ks = idx & 3;
        int n = nt * 16 + lr;
        f16x8 v;
#pragma unroll
        for (int j = 0; j < 8; j++) {
            int k = ks * 32 + lh * 8 + j;
            v[j] = (f16)Wh[k * 128 + n];
        }
        *(f16x8*)(WhtopF + (size_t)t2 * 8) = v;
    } else if (t < 24 * 8 * 64 + 8 * 4 * 64 + 4 * 4 * 64) {
        int t3 = t - (24 * 8 * 64 + 8 * 4 * 64);
        int idx = t3 >> 6; int nt = idx >> 2, ks = idx & 3;
        int cg = nt * 16 + lr;
        f16x8 v;
#pragma unroll
        for (int j = 0; j < 8; j++) {
            int k = ks * 32 + lh * 8 + j;
            v[j] = (f16)((cg < 32) ? Wg1[k * GH + cg] : Wg1[(128 + k) * GH + (cg - 32)]);
        }
        *(f16x8*)(Wg1F + (size_t)t3 * 8) = v;
    } else if (t < 24 * 8 * 64 + 8 * 4 * 64 + 4 * 4 * 64 + 8 * 8 * 64) {
        int t4 = t - (24 * 8 * 64 + 8 * 4 * 64 + 4 * 4 * 64);
        int idx = t4 >> 6; int nt = idx >> 3, ks = idx & 7;
        int n = nt * 16 + lr;
        f16x8 v;
#pragma unroll
        for (int j = 0; j < 8; j++) {
            int k = ks * 32 + lh * 8 + j;
            v[j] = (f16)Wf1[k * 128 + n];
        }
        *(f16x8*)(Wf1F + (size_t)t4 * 8) = v;
    }
}

// wave-per-node preproc: coalesced writes; h kept in f16 only.
__global__ __launch_bounds__(256) void k_preproc(
    const float* __restrict__ x, const float* __restrict__ Wpre, const float* __restrict__ bpre,
    const float* __restrict__ Winit, const float* __restrict__ binit,
    f16* __restrict__ h0_16, f16* __restrict__ h16) {
    __shared__ float sWpre[FIN * PRE], sbpre[PRE], sWinit[PRE * C], sbinit[C];
    for (int i = threadIdx.x; i < FIN * PRE; i += blockDim.x) sWpre[i] = Wpre[i];
    for (int i = threadIdx.x; i < PRE; i += blockDim.x) sbpre[i] = bpre[i];
    for (int i = threadIdx.x; i < PRE * C; i += blockDim.x) sWinit[i] = Winit[i];
    for (int i = threadIdx.x; i < C; i += blockDim.x) sbinit[i] = binit[i];
    __syncthreads();
    int wave = (blockIdx.x * blockDim.x + threadIdx.x) >> 6;
    int lane = threadIdx.x & 63;
    if (wave >= NODES) return;
    float xk = (lane < FIN) ? x[(size_t)wave * FIN + lane] : 0.0f;
    float pre = (lane < PRE) ? sbpre[lane] : 0.0f;
#pragma unroll
    for (int i = 0; i < FIN; i++) {
        float xi = __shfl(xk, i, 64);
        pre = fmaf(xi, (lane < PRE) ? sWpre[i * PRE + lane] : 0.0f, pre);
    }
    pre = fmaxf(pre, 0.0f);
    int c = lane * 2;
    float a0 = sbinit[c], a1 = sbinit[c + 1];
#pragma unroll
    for (int j = 0; j < PRE; j++) {
        float pj = __shfl(pre, j, 64);
        a0 = fmaf(pj, sWinit[j * C + c], a0);
        a1 = fmaf(pj, sWinit[j * C + c + 1], a1);
    }
    a0 = fmaxf(a0, 0.0f); a1 = fmaxf(a1, 0.0f);
    f16x2 o; o[0] = (f16)a0; o[1] = (f16)a1;
    *(f16x2*)&h0_16[(size_t)wave * C + c] = o;
    *(f16x2*)&h16[(size_t)wave * C + c] = o;
}

// layer-0 gate via MFMA: A|B16 = h @ Wg1F (+bg1 on A, both permuted); rec hd16 = dis*h.
__global__ __launch_bounds__(256) void k_gate0_mfma(
    const f16* __restrict__ h16, const float* __restrict__ dis,
    const f16* __restrict__ Wg1F, const float* __restrict__ bg1,
    float* __restrict__ A, f16* __restrict__ rec) {
    __shared__ f16 za[32 * 128];    // swizzled, row stride 256B
    char* zaB = (char*)za;
    int tid = threadIdx.x;
    int l = tid & 63, w = tid >> 6;
    int lr = l & 15, lh = l >> 4;
    int n0 = blockIdx.x * 32;

    for (int p = tid; p < 32 * 16; p += 256) {
        int row = p >> 4, seg = p & 15;
        int gn = n0 + row;
        f16x8 v = {};
        if (gn < NODES) v = *(const f16x8*)(h16 + (size_t)gn * C + seg * 8);
        *(f16x8*)(zaB + swz_off(row, seg * 16, 256)) = v;
        if (gn < NODES) {
            float dn = dis[gn];
            f16x8 od;
#pragma unroll
            for (int j = 0; j < 8; j++) od[j] = (f16)((float)v[j] * dn);
            *(f16x8*)(rec + (size_t)gn * RECS + 32 + seg * 8) = od;
        }
    }
    __syncthreads();

    f32x4 acc3[2];
#pragma unroll
    for (int rt = 0; rt < 2; rt++)
#pragma unroll
        for (int j = 0; j < 4; j++) acc3[rt][j] = 0.0f;
#pragma unroll
    for (int ks = 0; ks < 4; ks++) {
        int kk = ks * 32 + lh * 8;
        f16x8 a0 = *(const f16x8*)(zaB + swz_off(lr,      kk * 2, 256));
        f16x8 a1 = *(const f16x8*)(zaB + swz_off(lr + 16, kk * 2, 256));
        f16x8 b = *(const f16x8*)(Wg1F + ((size_t)(w * 4 + ks) * 64 + l) * 8);
        acc3[0] = __builtin_amdgcn_mfma_f32_16x16x32_f16(a0, b, acc3[0], 0, 0, 0);
        acc3[1] = __builtin_amdgcn_mfma_f32_16x16x32_f16(a1, b, acc3[1], 0, 0, 0);
    }
    int col3 = w * 16 + lr;
#pragma unroll
    for (int rt = 0; rt < 2; rt++)
#pragma unroll
        for (int j = 0; j < 4; j++) {
            int row = rt * 16 + lh * 4 + j;
            int gn = n0 + row;
            if (gn < NODES) {
                float v = acc3[rt][j];
                if (col3 < 32) A[(size_t)gn * GH + bperm(col3)] = v + bg1[col3];
                else           rec[(size_t)gn * RECS + bperm(col3 - 32)] = (f16)v;
            }
        }
}

// fused gate+aggregate: wave per node, EIGHTH-WAVE (8 lanes) per edge, 1-deep prefetch.
__global__ __launch_bounds__(256) void k_msg(
    const int* __restrict__ start, const int* __restrict__ row_sorted,
    const float* __restrict__ ea_sorted, const float* __restrict__ dis,
    const float* __restrict__ A, const f16* __restrict__ rec,
    const float* __restrict__ Wg1, const float* __restrict__ Wg2, const float* __restrict__ bg2,
    f16* __restrict__ aggr16) {
    int wid = (blockIdx.x * blockDim.x + threadIdx.x) >> 6;
    int lane = threadIdx.x & 63;
    if (wid >= NODES) return;
    int k8 = lane & 7;
    int q = lane >> 3;
    int s0 = start[wid], s1 = start[wid + 1];
    float4 a4 = *(const float4*)(A + (size_t)wid * GH + k8 * 4);   // channels {k8,k8+8,k8+16,k8+24}
    const float* wg1e = Wg1 + 2 * C * GH;
    float wea0 = wg1e[k8], wea1 = wg1e[k8 + 8], wea2 = wg1e[k8 + 16], wea3 = wg1e[k8 + 24];
    float w20 = Wg2[k8], w21 = Wg2[k8 + 8], w22 = Wg2[k8 + 16], w23 = Wg2[k8 + 24];
    float b2 = bg2[0];
    float dci = dis[wid];
    float acc[16];
#pragma unroll
    for (int j = 0; j < 16; j++) acc[j] = 0.0f;

    int s = s0 + q;
    f16x8 ha0 = {}, hb0 = {};
    f16x4 bb0 = {};
    float ea0 = 0.0f;
    if (s < s1) {
        int r = row_sorted[s];
        ea0 = ea_sorted[s];
        const f16* rr = rec + (size_t)r * RECS;
        bb0 = *(const f16x4*)(rr + k8 * 4);
        ha0 = *(const f16x8*)(rr + 32 + k8 * 16);
        hb0 = *(const f16x8*)(rr + 32 + k8 * 16 + 8);
    }
    while (s < s1) {
        int s2 = s + 8;
        f16x8 ha1 = {}, hb1 = {};
        f16x4 bb1 = {};
        float ea1 = 0.0f;
        if (s2 < s1) {                       // prefetch next edge's record
            int r = row_sorted[s2];
            ea1 = ea_sorted[s2];
            const f16* rr = rec + (size_t)r * RECS;
            bb1 = *(const f16x4*)(rr + k8 * 4);
            ha1 = *(const f16x8*)(rr + 32 + k8 * 16);
            hb1 = *(const f16x8*)(rr + 32 + k8 * 16 + 8);
        }
        float t0 = fmaxf(a4.x + (float)bb0[0] + ea0 * wea0, 0.0f);
        float t1 = fmaxf(a4.y + (float)bb0[1] + ea0 * wea1, 0.0f);
        float t2 = fmaxf(a4.z + (float)bb0[2] + ea0 * wea2, 0.0f);
        float t3 = fmaxf(a4.w + (float)bb0[3] + ea0 * wea3, 0.0f);
        float p = t0 * w20;
        p = fmaf(t1, w21, p);
        p = fmaf(t2, w22, p);
        p = fmaf(t3, w23, p);
        p += __shfl_xor(p, 4, 8);
        p += __shfl_xor(p, 2, 8);
        p += __shfl_xor(p, 1, 8);
        float coef = sigmoidf_(p + b2);
#pragma unroll
        for (int j = 0; j < 8; j++) {
            acc[j]     = fmaf(coef, (float)ha0[j], acc[j]);
            acc[8 + j] = fmaf(coef, (float)hb0[j], acc[8 + j]);
        }
        ha0 = ha1; hb0 = hb1; bb0 = bb1; ea0 = ea1;
        s = s2;
    }
#pragma unroll
    for (int j = 0; j < 16; j++) {
        acc[j] += __shfl_xor(acc[j], 8, 64);
        acc[j] += __shfl_xor(acc[j], 16, 64);
        acc[j] += __shfl_xor(acc[j], 32, 64);
    }
    if (lane < 8) {
        f16x8 o1, o2;
#pragma unroll
        for (int j = 0; j < 8; j++) { o1[j] = (f16)(acc[j] * dci); o2[j] = (f16)(acc[8 + j] * dci); }
        *(f16x8*)(aggr16 + (size_t)wid * C + k8 * 16) = o1;
        *(f16x8*)(aggr16 + (size_t)wid * C + k8 * 16 + 8) = o2;
    }
}

// GRU update via MFMA; per-wave column-tile ownership keeps z,p in registers.
// Reads h16 + aggr16; writes h16, rec = {B16perm|hd16}, A f32 (permuted).
__global__ __launch_bounds__(256) void k_update_mfma(
    f16* __restrict__ h16, const f16* __restrict__ aggr16, const float* __restrict__ dis,
    f16* __restrict__ rec,
    const f16* __restrict__ WcatF, const f16* __restrict__ WhtopF, const f16* __restrict__ Wg1F,
    const float* __restrict__ bz, const float* __restrict__ br, const float* __restrict__ bh,
    const float* __restrict__ bg1,
    float* __restrict__ A) {
    __shared__ f16 za[32 * 256];    // swizzled, row stride 512B; reused for h_new staging
    __shared__ f16 rhbuf[32 * 128]; // swizzled, row stride 256B
    char* zaB = (char*)za;
    char* rhB = (char*)rhbuf;
    int tid = threadIdx.x;
    int l = tid & 63, w = tid >> 6;
    int lr = l & 15, lh = l >> 4;
    int n0 = blockIdx.x * 32;

    // stage za = [h16 | aggr16], pure f16x8 copies
    for (int p = tid; p < 32 * 16; p += 256) {
        int row = p >> 4, seg = p & 15;
        int gn = n0 + row;
        f16x8 v = {};
        if (gn < NODES) v = *(const f16x8*)(h16 + (size_t)gn * C + seg * 8);
        *(f16x8*)(zaB + swz_off(row, seg * 16, 512)) = v;
    }
    for (int p = tid; p < 32 * 16; p += 256) {
        int row = p >> 4, seg = p & 15;
        int gn = n0 + row;
        f16x8 v = {};
        if (gn < NODES) v = *(const f16x8*)(aggr16 + (size_t)gn * C + seg * 8);
        *(f16x8*)(zaB + swz_off(row, 256 + seg * 16, 512)) = v;
    }
    __syncthreads();

    // GEMM1: tiles [z0,z1,r0,r1,p0,p1] per wave
    f32x4 acc[2][6];
#pragma unroll
    for (int rt = 0; rt < 2; rt++)
#pragma unroll
        for (int n = 0; n < 6; n++)
#pragma unroll
            for (int j = 0; j < 4; j++) acc[rt][n][j] = 0.0f;
#pragma unroll
    for (int ks = 0; ks < 8; ks++) {
        int kk = ks * 32 + lh * 8;
        f16x8 a0 = *(const f16x8*)(zaB + swz_off(lr,      kk * 2, 512));
        f16x8 a1 = *(const f16x8*)(zaB + swz_off(lr + 16, kk * 2, 512));
#pragma unroll
        for (int ntl = 0; ntl < 6; ntl++) {
            f16x8 b = *(const f16x8*)(WcatF + ((size_t)((w * 6 + ntl) * 8 + ks) * 64 + l) * 8);
            acc[0][ntl] = __builtin_amdgcn_mfma_f32_16x16x32_f16(a0, b, acc[0][ntl], 0, 0, 0);
            acc[1][ntl] = __builtin_amdgcn_mfma_f32_16x16x32_f16(a1, b, acc[1][ntl], 0, 0, 0);
        }
    }

    // epilogue1: z->reg (sigmoid), r*h -> rhbuf (h from za), p stays in acc[rt][4/5]
    float zreg[2][2][4];
#pragma unroll
    for (int rt = 0; rt < 2; rt++)
#pragma unroll
        for (int pr = 0; pr < 2; pr++) {
            int cg = (2 * w + pr) * 16 + lr;
#pragma unroll
            for (int j = 0; j < 4; j++) {
                int row = rt * 16 + lh * 4 + j;
                zreg[rt][pr][j] = sigmoidf_(acc[rt][pr][j] + bz[cg]);
                float rv = sigmoidf_(acc[rt][2 + pr][j] + br[cg]);
                float hv = (float)*(const f16*)(zaB + swz_off(row, cg * 2, 512));
                *(f16*)(rhB + swz_off(row, cg * 2, 256)) = (f16)(rv * hv);
            }
        }
    __syncthreads();

    // GEMM2: hc_pre = p + bh + (r*h) @ Wh_top
    f32x4 acc2[2][2];
#pragma unroll
    for (int rt = 0; rt < 2; rt++)
#pragma unroll
        for (int pr = 0; pr < 2; pr++) {
            int cg = (2 * w + pr) * 16 + lr;
#pragma unroll
            for (int j = 0; j < 4; j++)
                acc2[rt][pr][j] = acc[rt][4 + pr][j] + bh[cg];
        }
#pragma unroll
    for (int ks = 0; ks < 4; ks++) {
        int kk = ks * 32 + lh * 8;
        f16x8 a0 = *(const f16x8*)(rhB + swz_off(lr,      kk * 2, 256));
        f16x8 a1 = *(const f16x8*)(rhB + swz_off(lr + 16, kk * 2, 256));
#pragma unroll
        for (int pr = 0; pr < 2; pr++) {
            f16x8 b = *(const f16x8*)(WhtopF + ((size_t)((w * 2 + pr) * 4 + ks) * 64 + l) * 8);
            acc2[0][pr] = __builtin_amdgcn_mfma_f32_16x16x32_f16(a0, b, acc2[0][pr], 0, 0, 0);
            acc2[1][pr] = __builtin_amdgcn_mfma_f32_16x16x32_f16(a1, b, acc2[1][pr], 0, 0, 0);
        }
    }

    // epilogue2: h_new = (1-z)*hold(za) + z*relu(hc); write h16 + rec hd16; stage into za
#pragma unroll
    for (int rt = 0; rt < 2; rt++)
#pragma unroll
        for (int pr = 0; pr < 2; pr++) {
            int cg = (2 * w + pr) * 16 + lr;
#pragma unroll
            for (int j = 0; j < 4; j++) {
                int row = rt * 16 + lh * 4 + j;
                int gn = n0 + row;
                float hc = fmaxf(acc2[rt][pr][j], 0.0f);
                float z = zreg[rt][pr][j];
                float hold = (float)*(const f16*)(zaB + swz_off(row, cg * 2, 512));
                float hn = (1.0f - z) * hold + z * hc;
                if (gn < NODES) {
                    h16[(size_t)gn * C + cg] = (f16)hn;
                    rec[(size_t)gn * RECS + 32 + cg] = (f16)(hn * dis[gn]);
                }
                *(f16*)(zaB + swz_off(row, cg * 2, 512)) = (f16)hn;
            }
        }
    __syncthreads();

    // GEMM3: A|B16 = h_new @ Wg1F (both outputs permuted)
    f32x4 acc3[2];
#pragma unroll
    for (int rt = 0; rt < 2; rt++)
#pragma unroll
        for (int j = 0; j < 4; j++) acc3[rt][j] = 0.0f;
#pragma unroll
    for (int ks = 0; ks < 4; ks++) {
        int kk = ks * 32 + lh * 8;
        f16x8 a0 = *(const f16x8*)(zaB + swz_off(lr,      kk * 2, 512));
        f16x8 a1 = *(const f16x8*)(zaB + swz_off(lr + 16, kk * 2, 512));
        f16x8 b = *(const f16x8*)(Wg1F + ((size_t)(w * 4 + ks) * 64 + l) * 8);
        acc3[0] = __builtin_amdgcn_mfma_f32_16x16x32_f16(a0, b, acc3[0], 0, 0, 0);
        acc3[1] = __builtin_amdgcn_mfma_f32_16x16x32_f16(a1, b, acc3[1], 0, 0, 0);
    }
    int col3 = w * 16 + lr;
#pragma unroll
    for (int rt = 0; rt < 2; rt++)
#pragma unroll
        for (int j = 0; j < 4; j++) {
            int row = rt * 16 + lh * 4 + j;
            int gn = n0 + row;
            if (gn < NODES) {
                float v = acc3[rt][j];
                if (col3 < 32) A[(size_t)gn * GH + bperm(col3)] = v + bg1[col3];
                else           rec[(size_t)gn * RECS + bperm(col3 - 32)] = (f16)v;
            }
        }
}

// final head via MFMA: f = relu([h0_16|h16]@Wf1+bf1); out = f@Wf2+bf2
__global__ __launch_bounds__(256) void k_final_mfma(
    const f16* __restrict__ h0_16, const f16* __restrict__ h16,
    const f16* __restrict__ Wf1F, const float* __restrict__ bf1,
    const float* __restrict__ Wf2, const float* __restrict__ bf2,
    float* __restrict__ out) {
    __shared__ float fs[32][132];   // aliased during stage/GEMM as f16 za [32][256] swizzled
    char* zaB = (char*)&fs[0][0];
    int tid = threadIdx.x;
    int l = tid & 63, w = tid >> 6;
    int lr = l & 15, lh = l >> 4;
    int n0 = blockIdx.x * 32;

    for (int p = tid; p < 32 * 16; p += 256) {
        int row = p >> 4, seg = p & 15;
        int gn = n0 + row;
        f16x8 v = {};
        if (gn < NODES) v = *(const f16x8*)(h0_16 + (size_t)gn * C + seg * 8);
        *(f16x8*)(zaB + swz_off(row, seg * 16, 512)) = v;
    }
    for (int p = tid; p < 32 * 16; p += 256) {
        int row = p >> 4, seg = p & 15;
        int gn = n0 + row;
        f16x8 v = {};
        if (gn < NODES) v = *(const f16x8*)(h16 + (size_t)gn * C + seg * 8);
        *(f16x8*)(zaB + swz_off(row, 256 + seg * 16, 512)) = v;
    }
    __syncthreads();

    f32x4 acc[2][2];
#pragma unroll
    for (int rt = 0; rt < 2; rt++)
#pragma unroll
        for (int n = 0; n < 2; n++)
#pragma unroll
            for (int j = 0; j < 4; j++) acc[rt][n][j] = 0.0f;
#pragma unroll
    for (int ks = 0; ks < 8; ks++) {
        int kk = ks * 32 + lh * 8;
        f16x8 a0 = *(const f16x8*)(zaB + swz_off(lr,      kk * 2, 512));
        f16x8 a1 = *(const f16x8*)(zaB + swz_off(lr + 16, kk * 2, 512));
#pragma unroll
        for (int ntl = 0; ntl < 2; ntl++) {
            f16x8 b = *(const f16x8*)(Wf1F + ((size_t)((w * 2 + ntl) * 8 + ks) * 64 + l) * 8);
            acc[0][ntl] = __builtin_amdgcn_mfma_f32_16x16x32_f16(a0, b, acc[0][ntl], 0, 0, 0);
            acc[1][ntl] = __builtin_amdgcn_mfma_f32_16x16x32_f16(a1, b, acc[1][ntl], 0, 0, 0);
        }
    }
    __syncthreads();  // za reads done before fs overwrite

#pragma unroll
    for (int rt = 0; rt < 2; rt++)
#pragma unroll
        for (int ntl = 0; ntl < 2; ntl++) {
            int cg = (w * 2 + ntl) * 16 + lr;
#pragma unroll
            for (int j = 0; j < 4; j++) {
                int row = rt * 16 + lh * 4 + j;
                fs[row][cg] = fmaxf(acc[rt][ntl][j] + bf1[cg], 0.0f);
            }
        }
    __syncthreads();

    if (tid < 64) {
        int n = tid >> 1, o = tid & 1;
        int gn = n0 + n;
        if (gn < NODES) {
            float a = bf2[o];
#pragma unroll 16
            for (int c = 0; c < C; c++) a = fmaf(fs[n][c], Wf2[c * 2 + o], a);
            out[(size_t)gn * 2 + o] = a;
        }
    }
}

extern "C" void kernel_launch(void* const* d_in, const int* in_sizes, int n_in,
                              void* d_out, int out_size, void* d_ws, size_t ws_size,
                              hipStream_t stream) {
    const float* x    = (const float*)d_in[0];
    const int*   eidx = (const int*)d_in[1];
    const float* eattr= (const float*)d_in[2];
    const float* Wpre = (const float*)d_in[3];  const float* bpre = (const float*)d_in[4];
    const float* Winit= (const float*)d_in[5];  const float* binit= (const float*)d_in[6];
    const float* Wg1  = (const float*)d_in[7];  const float* bg1  = (const float*)d_in[8];
    const float* Wg2  = (const float*)d_in[9];  const float* bg2  = (const float*)d_in[10];
    const float* Wz   = (const float*)d_in[11]; const float* bz   = (const float*)d_in[12];
    const float* Wr   = (const float*)d_in[13]; const float* br   = (const float*)d_in[14];
    const float* Wh   = (const float*)d_in[15]; const float* bh   = (const float*)d_in[16];
    const float* Wf1  = (const float*)d_in[17]; const float* bf1  = (const float*)d_in[18];
    const float* Wf2  = (const float*)d_in[19]; const float* bf2  = (const float*)d_in[20];
    float* out = (float*)d_out;

    float* ws  = (float*)d_ws;
    float* dis = ws;                               // N (deg during preamble, then rsqrt)
    float* A   = dis + NODES;                      // N*GH f32 (permuted)
    int*   start = (int*)(A + (size_t)NODES * GH);     // N+1
    int*   cursor = start + NODES + 1;                 // N+1
    int*   bsum  = cursor + NODES + 1;                 // SCB
    int*   bscan = bsum + SCB;                         // SCB
    int*   row_sorted = bscan + SCB;                   // ETOT
    float* ea_sorted  = (float*)(row_sorted + ETOT);   // ETOT
    size_t f16_base = (size_t)((ea_sorted + ETOT) - ws);
    f16_base = (f16_base + 3) & ~(size_t)3;            // 16B align
    f16* h0_16  = (f16*)(ws + f16_base);               // N*C f16
    f16* h16    = h0_16 + (size_t)NODES * C;           // N*C f16
    f16* rec    = h16 + (size_t)NODES * C;             // N*RECS f16
    f16* aggr16 = rec + (size_t)NODES * RECS;          // N*C f16
    f16* WcatF  = aggr16 + (size_t)NODES * C;          // 24*8*64*8 f16
    f16* WhtopF = WcatF + 24 * 8 * 64 * 8;
    f16* Wg1F   = WhtopF + 8 * 4 * 64 * 8;
    f16* Wf1F   = Wg1F + 4 * 4 * 64 * 8;
    size_t f16_total = (size_t)NODES * (C + C + RECS + C) + (24 * 8 + 8 * 4 + 4 * 4 + 8 * 8) * 64 * 8;
    const size_t REQ = (f16_base + (f16_total + 1) / 2) * sizeof(float);
    if (ws_size < REQ) return;

    hipMemsetAsync(dis, 0, NODES * sizeof(float), stream);
    k_degree<<<(NEDGES + 255) / 256, 256, 0, stream>>>(eidx + NEDGES, dis);
    k_scan1<<<SCB, SCT, 0, stream>>>(dis, bsum);
    k_scan2<<<1, 64, 0, stream>>>(bsum, bscan, start);
    k_scan3<<<SCB, SCT, 0, stream>>>(dis, bscan, start, cursor);   // also writes dis
    k_csr<<<(ETOT + 255) / 256, 256, 0, stream>>>(eidx, eattr, cursor, row_sorted, ea_sorted);
    k_prep_w<<<(24 * 8 * 64 + 8 * 4 * 64 + 4 * 4 * 64 + 8 * 8 * 64 + 255) / 256, 256, 0, stream>>>(
        Wz, Wr, Wh, Wg1, Wf1, WcatF, WhtopF, Wg1F, Wf1F);
    k_preproc<<<(NODES * 64 + 255) / 256, 256, 0, stream>>>(x, Wpre, bpre, Winit, binit, h0_16, h16);
    k_gate0_mfma<<<(NODES + 31) / 32, 256, 0, stream>>>(h16, dis, Wg1F, bg1, A, rec);

    for (int l = 0; l < LAYERS; l++) {
        k_msg<<<(NODES * 64 + 255) / 256, 256, 0, stream>>>(
            start, row_sorted, ea_sorted, dis, A, rec, Wg1, Wg2, bg2, aggr16);
        k_update_mfma<<<(NODES + 31) / 32, 256, 0, stream>>>(
            h16, aggr16, dis, rec, WcatF, WhtopF, Wg1F, bz, br, bh, bg1, A);
    }
    k_final_mfma<<<(NODES + 31) / 32, 256, 0, stream>>>(h0_16, h16, Wf1F, bf1, Wf2, bf2, out);
}

// Round 13
// 580.110 us; speedup vs baseline: 15.7588x; 1.0892x over previous
//
#include <hip/hip_runtime.h>
#include <math.h>

#define NODES 50000
#define NEDGES 800000
#define ETOT (NEDGES + NODES)
#define FIN 16
#define PRE 32
#define C 128
#define GH 32
#define LAYERS 5
#define RECS 160   // f16 per node record: [B16perm:32 | hd16:128] where hd = dis[n]*h[n]
#define SCB 64     // scan blocks
#define SCT 256    // scan threads/block
#define SCCH ((NODES + SCB*SCT - 1) / (SCB*SCT))   // elems per thread (=4)

typedef _Float16 f16;
typedef f16 f16x8 __attribute__((ext_vector_type(8)));
typedef f16 f16x4 __attribute__((ext_vector_type(4)));
typedef f16 f16x2 __attribute__((ext_vector_type(2)));
typedef float f32x4 __attribute__((ext_vector_type(4)));

__device__ __forceinline__ float sigmoidf_(float x) { return 1.0f / (1.0f + __expf(-x)); }

// XOR-swizzled LDS byte offset: 16B-block index ^= (row&7)  (stride >= 128B)
__device__ __forceinline__ int swz_off(int row, int bytecol, int stride) {
    return row * stride + ((((bytecol) >> 4) ^ (row & 7)) << 4) + (bytecol & 15);
}
// 64B-stride variant: block index ^= (row&3)
__device__ __forceinline__ int ps_off(int row, int bytecol) {
    return row * 64 + ((((bytecol) >> 4) ^ (row & 3)) << 4) + (bytecol & 15);
}

// gate channel c (0..31) -> permuted position, so msg lane k8 reads one vector
__device__ __forceinline__ int bperm(int c) { return 4 * (c & 7) + (c >> 3); }

__global__ void k_degree(const int* __restrict__ col, float* __restrict__ deg) {
    int e = blockIdx.x * blockDim.x + threadIdx.x;
    if (e < NEDGES) atomicAdd(&deg[col[e]], 1.0f);
}

// parallel scan, stage 1: per-block sums of (deg+1)
__global__ __launch_bounds__(SCT) void k_scan1(const float* __restrict__ deg, int* __restrict__ bsum) {
    __shared__ int ws4[SCT / 64];
    int b = blockIdx.x, t = threadIdx.x;
    int lane = t & 63, wv = t >> 6;
    int base = (b * SCT + t) * SCCH;
    int sum = 0;
#pragma unroll
    for (int j = 0; j < SCCH; j++) {
        int i = base + j;
        if (i < NODES) sum += (int)deg[i] + 1;
    }
#pragma unroll
    for (int off = 32; off > 0; off >>= 1) sum += __shfl_xor(sum, off, 64);
    if (lane == 0) ws4[wv] = sum;
    __syncthreads();
    if (t == 0) {
        int tot = 0;
#pragma unroll
        for (int j = 0; j < SCT / 64; j++) tot += ws4[j];
        bsum[b] = tot;
    }
}

// stage 2: exclusive scan of SCB block sums (single wave)
__global__ __launch_bounds__(64) void k_scan2(const int* __restrict__ bsum, int* __restrict__ bscan,
                                              int* __restrict__ start) {
    int t = threadIdx.x;
    int v = (t < SCB) ? bsum[t] : 0;
    int x = v;
#pragma unroll
    for (int off = 1; off < 64; off <<= 1) {
        int tt = __shfl_up(x, off, 64);
        if (t >= off) x += tt;
    }
    if (t < SCB) bscan[t] = x - v;
    if (t == SCB - 1) start[NODES] = x;
}

// stage 3: per-element exclusive prefix -> start/cursor; also dis = rsqrt(deg+1) in-place
__global__ __launch_bounds__(SCT) void k_scan3(
    float* __restrict__ deg_dis, const int* __restrict__ bscan,
    int* __restrict__ start, int* __restrict__ cursor) {
    __shared__ int woff[SCT / 64];
    int b = blockIdx.x, t = threadIdx.x;
    int lane = t & 63, wv = t >> 6;
    int base = (b * SCT + t) * SCCH;
    int v[SCCH]; int sum = 0;
#pragma unroll
    for (int j = 0; j < SCCH; j++) {
        int i = base + j;
        v[j] = (i < NODES) ? (int)deg_dis[i] + 1 : 0;
        sum += v[j];
    }
    int x = sum;
#pragma unroll
    for (int off = 1; off < 64; off <<= 1) {
        int tt = __shfl_up(x, off, 64);
        if (lane >= off) x += tt;
    }
    int texcl = x - sum;
    if (lane == 63) woff[wv] = x;
    __syncthreads();
    int wbase = 0;
    for (int j = 0; j < wv; j++) wbase += woff[j];
    int run = bscan[b] + wbase + texcl;
#pragma unroll
    for (int j = 0; j < SCCH; j++) {
        int i = base + j;
        if (i < NODES) {
            start[i] = run; cursor[i] = run;
            deg_dis[i] = rsqrtf((float)v[j]);
        }
        run += v[j];
    }
}

__global__ __launch_bounds__(256) void k_csr(
    const int* __restrict__ eidx, const float* __restrict__ eattr,
    int* __restrict__ cursor,
    int* __restrict__ row_sorted, float* __restrict__ ea_sorted) {
    int e = blockIdx.x * blockDim.x + threadIdx.x;
    if (e >= ETOT) return;
    int r, ci; float ea;
    if (e < NEDGES) { r = eidx[e]; ci = eidx[NEDGES + e]; ea = eattr[e]; }
    else            { r = ci = e - NEDGES; ea = 0.0f; }
    int slot = atomicAdd(&cursor[ci], 1);
    row_sorted[slot] = r;
    ea_sorted[slot] = ea;
}

// fragment-ordered f16 weight buffers.
// WcatF: K=256, 24 col-tiles [z0,z1,r0,r1,p0,p1] per wave; WhtopF: K=128 -> 128;
// Wg1F: K=128 -> 64 (A|B); Wf1F: K=256 -> 128; WpreF: K=32(pad) -> 32; WinitF: K=32 -> 128
__global__ __launch_bounds__(256) void k_prep_w(
    const float* __restrict__ Wz, const float* __restrict__ Wr, const float* __restrict__ Wh,
    const float* __restrict__ Wg1, const float* __restrict__ Wf1,
    const float* __restrict__ Wpre, const float* __restrict__ Winit,
    f16* __restrict__ WcatF, f16* __restrict__ WhtopF, f16* __restrict__ Wg1F,
    f16* __restrict__ Wf1F, f16* __restrict__ WpreF, f16* __restrict__ WinitF) {
    int t = blockIdx.x * 256 + threadIdx.x;
    int l = t & 63;
    int lr = l & 15, lh = l >> 4;
    if (t < 24 * 8 * 64) {
        int idx = t >> 6; int nt = idx >> 3, ks = idx & 7;
        int wv = nt / 6, ntl = nt % 6;
        int grp = ntl >> 1, pr = ntl & 1;
        int ncol = (2 * wv + pr) * 16 + lr;
        f16x8 v;
#pragma unroll
        for (int j = 0; j < 8; j++) {
            int k = ks * 32 + lh * 8 + j;
            float x;
            if (grp == 0)      x = Wz[k * 128 + ncol];
            else if (grp == 1) x = Wr[k * 128 + ncol];
            else               x = (k >= 128) ? Wh[k * 128 + ncol] : 0.0f;
            v[j] = (f16)x;
        }
        *(f16x8*)(WcatF + (size_t)t * 8) = v;
    } else if (t < 24 * 8 * 64 + 8 * 4 * 64) {
        int t2 = t - 24 * 8 * 64;
        int idx = t2 >> 6; int nt = idx >> 2, ks = idx & 3;
        int n = nt * 16 + lr;
        f16x8 v;
#pragma unroll
        for (int j = 0; j < 8; j++) {
            int k = ks * 32 + lh * 8 + j;
            v[j] = (f16)Wh[k * 128 + n];
        }
        *(f16x8*)(WhtopF + (size_t)t2 * 8) = v;
    } else if (t < 24 * 8 * 64 + 8 * 4 * 64 + 4 * 4 * 64) {
        int t3 = t - (24 * 8 * 64 + 8 * 4 * 64);
        int idx = t3 >> 6; int nt = idx >> 2, ks = idx & 3;
        int cg = nt * 16 + lr;
        f16x8 v;
#pragma unroll
        for (int j = 0; j < 8; j++) {
            int k = ks * 32 + lh * 8 + j;
            v[j] = (f16)((cg < 32) ? Wg1[k * GH + cg] : Wg1[(128 + k) * GH + (cg - 32)]);
        }
        *(f16x8*)(Wg1F + (size_t)t3 * 8) = v;
    } else if (t < 24 * 8 * 64 + 8 * 4 * 64 + 4 * 4 * 64 + 8 * 8 * 64) {
        int t4 = t - (24 * 8 * 64 + 8 * 4 * 64 + 4 * 4 * 64);
        int idx = t4 >> 6; int nt = idx >> 3, ks = idx & 7;
        int n = nt * 16 + lr;
        f16x8 v;
#pragma unroll
        for (int j = 0; j < 8; j++) {
            int k = ks * 32 + lh * 8 + j;
            v[j] = (f16)Wf1[k * 128 + n];
        }
        *(f16x8*)(Wf1F + (size_t)t4 * 8) = v;
    } else if (t < 19456 + 2 * 64) {
        int t5 = t - 19456;
        int nt = t5 >> 6;
        f16x8 v;
#pragma unroll
        for (int j = 0; j < 8; j++) {
            int k = lh * 8 + j;           // K padded 16->32
            v[j] = (k < FIN) ? (f16)Wpre[k * PRE + nt * 16 + lr] : (f16)0.0f;
        }
        *(f16x8*)(WpreF + (size_t)t5 * 8) = v;
    } else if (t < 19456 + 128 + 8 * 64) {
        int t6 = t - 19456 - 128;
        int nt = t6 >> 6;
        f16x8 v;
#pragma unroll
        for (int j = 0; j < 8; j++) {
            int k = lh * 8 + j;
            v[j] = (f16)Winit[k * C + nt * 16 + lr];
        }
        *(f16x8*)(WinitF + (size_t)t6 * 8) = v;
    }
}

// fused preproc + layer-0 gate, all MFMA. 32 nodes/block.
// pre = relu(x@Wpre+bpre); h = relu(pre@Winit+binit) -> h0_16,h16,rec.hd16,za;
// A|B16 = h @ Wg1F (+bg1 on A), permuted.
__global__ __launch_bounds__(256) void k_pre_gate(
    const float* __restrict__ x, const float* __restrict__ bpre, const float* __restrict__ binit,
    const float* __restrict__ dis,
    const f16* __restrict__ WpreF, const f16* __restrict__ WinitF,
    const f16* __restrict__ Wg1F, const float* __restrict__ bg1,
    f16* __restrict__ h0_16, f16* __restrict__ h16, f16* __restrict__ rec,
    float* __restrict__ A) {
    __shared__ f16 ps[32 * 32];     // pre, 64B-stride swizzled
    __shared__ f16 za[32 * 128];    // h, 256B-stride swizzled
    char* psB = (char*)ps;
    char* zaB = (char*)za;
    int tid = threadIdx.x;
    int l = tid & 63, w = tid >> 6;
    int lr = l & 15, lh = l >> 4;
    int n0 = blockIdx.x * 32;
    int rt0 = w >> 1, ct = w & 1;

    // GEMM-A: wave computes tile (rt0, ct) of pre[32][32]; K=16 zero-padded to 32
    f16x8 xa = {};
    {
        int gn = n0 + rt0 * 16 + lr;
        if (gn < NODES && lh < 2) {
            float4 xv0 = *(const float4*)(x + (size_t)gn * FIN + lh * 8);
            float4 xv1 = *(const float4*)(x + (size_t)gn * FIN + lh * 8 + 4);
            xa[0] = (f16)xv0.x; xa[1] = (f16)xv0.y; xa[2] = (f16)xv0.z; xa[3] = (f16)xv0.w;
            xa[4] = (f16)xv1.x; xa[5] = (f16)xv1.y; xa[6] = (f16)xv1.z; xa[7] = (f16)xv1.w;
        }
    }
    f16x8 bA = *(const f16x8*)(WpreF + ((size_t)ct * 64 + l) * 8);
    f32x4 accA; accA[0] = accA[1] = accA[2] = accA[3] = 0.0f;
    accA = __builtin_amdgcn_mfma_f32_16x16x32_f16(xa, bA, accA, 0, 0, 0);
    {
        float bp = bpre[ct * 16 + lr];
#pragma unroll
        for (int j = 0; j < 4; j++) {
            int row = rt0 * 16 + lh * 4 + j;
            float v = fmaxf(accA[j] + bp, 0.0f);
            *(f16*)(psB + ps_off(row, (ct * 16 + lr) * 2)) = (f16)v;
        }
    }
    __syncthreads();

    // GEMM-B: h = relu(pre @ Winit + binit); wave owns col-tiles {2w, 2w+1}
    f16x8 pa0 = *(const f16x8*)(psB + ps_off(lr, lh * 16));
    f16x8 pa1 = *(const f16x8*)(psB + ps_off(lr + 16, lh * 16));
    f32x4 accB[2][2];
#pragma unroll
    for (int rt = 0; rt < 2; rt++)
#pragma unroll
        for (int ntl = 0; ntl < 2; ntl++)
#pragma unroll
            for (int j = 0; j < 4; j++) accB[rt][ntl][j] = 0.0f;
#pragma unroll
    for (int ntl = 0; ntl < 2; ntl++) {
        f16x8 b = *(const f16x8*)(WinitF + ((size_t)((w * 2 + ntl) * 64 + l)) * 8);
        accB[0][ntl] = __builtin_amdgcn_mfma_f32_16x16x32_f16(pa0, b, accB[0][ntl], 0, 0, 0);
        accB[1][ntl] = __builtin_amdgcn_mfma_f32_16x16x32_f16(pa1, b, accB[1][ntl], 0, 0, 0);
    }
#pragma unroll
    for (int rt = 0; rt < 2; rt++)
#pragma unroll
        for (int ntl = 0; ntl < 2; ntl++) {
            int cg = (w * 2 + ntl) * 16 + lr;
            float bi = binit[cg];
#pragma unroll
            for (int j = 0; j < 4; j++) {
                int row = rt * 16 + lh * 4 + j;
                float v = fmaxf(accB[rt][ntl][j] + bi, 0.0f);
                *(f16*)(zaB + swz_off(row, cg * 2, 256)) = (f16)v;
            }
        }
    __syncthreads();

    // coalesced flush of h to h0_16, h16, rec.hd16
    for (int p = tid; p < 32 * 16; p += 256) {
        int row = p >> 4, seg = p & 15;
        int gn = n0 + row;
        if (gn < NODES) {
            f16x8 v = *(const f16x8*)(zaB + swz_off(row, seg * 16, 256));
            *(f16x8*)(h0_16 + (size_t)gn * C + seg * 8) = v;
            *(f16x8*)(h16 + (size_t)gn * C + seg * 8) = v;
            float dn = dis[gn];
            f16x8 od;
#pragma unroll
            for (int j = 0; j < 8; j++) od[j] = (f16)((float)v[j] * dn);
            *(f16x8*)(rec + (size_t)gn * RECS + 32 + seg * 8) = od;
        }
    }

    // GEMM-C: A|B16 = h @ Wg1F
    f32x4 acc3[2];
#pragma unroll
    for (int rt = 0; rt < 2; rt++)
#pragma unroll
        for (int j = 0; j < 4; j++) acc3[rt][j] = 0.0f;
#pragma unroll
    for (int ks = 0; ks < 4; ks++) {
        int kk = ks * 32 + lh * 8;
        f16x8 a0 = *(const f16x8*)(zaB + swz_off(lr,      kk * 2, 256));
        f16x8 a1 = *(const f16x8*)(zaB + swz_off(lr + 16, kk * 2, 256));
        f16x8 b = *(const f16x8*)(Wg1F + ((size_t)(w * 4 + ks) * 64 + l) * 8);
        acc3[0] = __builtin_amdgcn_mfma_f32_16x16x32_f16(a0, b, acc3[0], 0, 0, 0);
        acc3[1] = __builtin_amdgcn_mfma_f32_16x16x32_f16(a1, b, acc3[1], 0, 0, 0);
    }
    int col3 = w * 16 + lr;
#pragma unroll
    for (int rt = 0; rt < 2; rt++)
#pragma unroll
        for (int j = 0; j < 4; j++) {
            int row = rt * 16 + lh * 4 + j;
            int gn = n0 + row;
            if (gn < NODES) {
                float v = acc3[rt][j];
                if (col3 < 32) A[(size_t)gn * GH + bperm(col3)] = v + bg1[col3];
                else           rec[(size_t)gn * RECS + bperm(col3 - 32)] = (f16)v;
            }
        }
}

// fused gate+aggregate: wave per node, EIGHTH-WAVE (8 lanes) per edge, 1-deep prefetch.
__global__ __launch_bounds__(256) void k_msg(
    const int* __restrict__ start, const int* __restrict__ row_sorted,
    const float* __restrict__ ea_sorted, const float* __restrict__ dis,
    const float* __restrict__ A, const f16* __restrict__ rec,
    const float* __restrict__ Wg1, const float* __restrict__ Wg2, const float* __restrict__ bg2,
    f16* __restrict__ aggr16) {
    int wid = (blockIdx.x * blockDim.x + threadIdx.x) >> 6;
    int lane = threadIdx.x & 63;
    if (wid >= NODES) return;
    int k8 = lane & 7;
    int q = lane >> 3;
    int s0 = start[wid], s1 = start[wid + 1];
    float4 a4 = *(const float4*)(A + (size_t)wid * GH + k8 * 4);   // channels {k8,k8+8,k8+16,k8+24}
    const float* wg1e = Wg1 + 2 * C * GH;
    float wea0 = wg1e[k8], wea1 = wg1e[k8 + 8], wea2 = wg1e[k8 + 16], wea3 = wg1e[k8 + 24];
    float w20 = Wg2[k8], w21 = Wg2[k8 + 8], w22 = Wg2[k8 + 16], w23 = Wg2[k8 + 24];
    float b2 = bg2[0];
    float dci = dis[wid];
    float acc[16];
#pragma unroll
    for (int j = 0; j < 16; j++) acc[j] = 0.0f;

    int s = s0 + q;
    f16x8 ha0 = {}, hb0 = {};
    f16x4 bb0 = {};
    float ea0 = 0.0f;
    if (s < s1) {
        int r = row_sorted[s];
        ea0 = ea_sorted[s];
        const f16* rr = rec + (size_t)r * RECS;
        bb0 = *(const f16x4*)(rr + k8 * 4);
        ha0 = *(const f16x8*)(rr + 32 + k8 * 16);
        hb0 = *(const f16x8*)(rr + 32 + k8 * 16 + 8);
    }
    while (s < s1) {
        int s2 = s + 8;
        f16x8 ha1 = {}, hb1 = {};
        f16x4 bb1 = {};
        float ea1 = 0.0f;
        if (s2 < s1) {                       // prefetch next edge's record
            int r = row_sorted[s2];
            ea1 = ea_sorted[s2];
            const f16* rr = rec + (size_t)r * RECS;
            bb1 = *(const f16x4*)(rr + k8 * 4);
            ha1 = *(const f16x8*)(rr + 32 + k8 * 16);
            hb1 = *(const f16x8*)(rr + 32 + k8 * 16 + 8);
        }
        float t0 = fmaxf(a4.x + (float)bb0[0] + ea0 * wea0, 0.0f);
        float t1 = fmaxf(a4.y + (float)bb0[1] + ea0 * wea1, 0.0f);
        float t2 = fmaxf(a4.z + (float)bb0[2] + ea0 * wea2, 0.0f);
        float t3 = fmaxf(a4.w + (float)bb0[3] + ea0 * wea3, 0.0f);
        float p = t0 * w20;
        p = fmaf(t1, w21, p);
        p = fmaf(t2, w22, p);
        p = fmaf(t3, w23, p);
        p += __shfl_xor(p, 4, 8);
        p += __shfl_xor(p, 2, 8);
        p += __shfl_xor(p, 1, 8);
        float coef = sigmoidf_(p + b2);
#pragma unroll
        for (int j = 0; j < 8; j++) {
            acc[j]     = fmaf(coef, (float)ha0[j], acc[j]);
            acc[8 + j] = fmaf(coef, (float)hb0[j], acc[8 + j]);
        }
        ha0 = ha1; hb0 = hb1; bb0 = bb1; ea0 = ea1;
        s = s2;
    }
#pragma unroll
    for (int j = 0; j < 16; j++) {
        acc[j] += __shfl_xor(acc[j], 8, 64);
        acc[j] += __shfl_xor(acc[j], 16, 64);
        acc[j] += __shfl_xor(acc[j], 32, 64);
    }
    if (lane < 8) {
        f16x8 o1, o2;
#pragma unroll
        for (int j = 0; j < 8; j++) { o1[j] = (f16)(acc[j] * dci); o2[j] = (f16)(acc[8 + j] * dci); }
        *(f16x8*)(aggr16 + (size_t)wid * C + k8 * 16) = o1;
        *(f16x8*)(aggr16 + (size_t)wid * C + k8 * 16 + 8) = o2;
    }
}

// GRU update via MFMA; per-wave column-tile ownership keeps z,p in registers.
// Reads h16 + aggr16; writes h16, rec = {B16perm|hd16}, A f32 (permuted).
__global__ __launch_bounds__(256) void k_update_mfma(
    f16* __restrict__ h16, const f16* __restrict__ aggr16, const float* __restrict__ dis,
    f16* __restrict__ rec,
    const f16* __restrict__ WcatF, const f16* __restrict__ WhtopF, const f16* __restrict__ Wg1F,
    const float* __restrict__ bz, const float* __restrict__ br, const float* __restrict__ bh,
    const float* __restrict__ bg1,
    float* __restrict__ A) {
    __shared__ f16 za[32 * 256];    // swizzled, row stride 512B; reused for h_new staging
    __shared__ f16 rhbuf[32 * 128]; // swizzled, row stride 256B
    char* zaB = (char*)za;
    char* rhB = (char*)rhbuf;
    int tid = threadIdx.x;
    int l = tid & 63, w = tid >> 6;
    int lr = l & 15, lh = l >> 4;
    int n0 = blockIdx.x * 32;

    // stage za = [h16 | aggr16], pure f16x8 copies
    for (int p = tid; p < 32 * 16; p += 256) {
        int row = p >> 4, seg = p & 15;
        int gn = n0 + row;
        f16x8 v = {};
        if (gn < NODES) v = *(const f16x8*)(h16 + (size_t)gn * C + seg * 8);
        *(f16x8*)(zaB + swz_off(row, seg * 16, 512)) = v;
    }
    for (int p = tid; p < 32 * 16; p += 256) {
        int row = p >> 4, seg = p & 15;
        int gn = n0 + row;
        f16x8 v = {};
        if (gn < NODES) v = *(const f16x8*)(aggr16 + (size_t)gn * C + seg * 8);
        *(f16x8*)(zaB + swz_off(row, 256 + seg * 16, 512)) = v;
    }
    __syncthreads();

    // GEMM1: tiles [z0,z1,r0,r1,p0,p1] per wave
    f32x4 acc[2][6];
#pragma unroll
    for (int rt = 0; rt < 2; rt++)
#pragma unroll
        for (int n = 0; n < 6; n++)
#pragma unroll
            for (int j = 0; j < 4; j++) acc[rt][n][j] = 0.0f;
#pragma unroll
    for (int ks = 0; ks < 8; ks++) {
        int kk = ks * 32 + lh * 8;
        f16x8 a0 = *(const f16x8*)(zaB + swz_off(lr,      kk * 2, 512));
        f16x8 a1 = *(const f16x8*)(zaB + swz_off(lr + 16, kk * 2, 512));
#pragma unroll
        for (int ntl = 0; ntl < 6; ntl++) {
            f16x8 b = *(const f16x8*)(WcatF + ((size_t)((w * 6 + ntl) * 8 + ks) * 64 + l) * 8);
            acc[0][ntl] = __builtin_amdgcn_mfma_f32_16x16x32_f16(a0, b, acc[0][ntl], 0, 0, 0);
            acc[1][ntl] = __builtin_amdgcn_mfma_f32_16x16x32_f16(a1, b, acc[1][ntl], 0, 0, 0);
        }
    }

    // epilogue1: z->reg (sigmoid), r*h -> rhbuf (h from za), p stays in acc[rt][4/5]
    float zreg[2][2][4];
#pragma unroll
    for (int rt = 0; rt < 2; rt++)
#pragma unroll
        for (int pr = 0; pr < 2; pr++) {
            int cg = (2 * w + pr) * 16 + lr;
#pragma unroll
            for (int j = 0; j < 4; j++) {
                int row = rt * 16 + lh * 4 + j;
                zreg[rt][pr][j] = sigmoidf_(acc[rt][pr][j] + bz[cg]);
                float rv = sigmoidf_(acc[rt][2 + pr][j] + br[cg]);
                float hv = (float)*(const f16*)(zaB + swz_off(row, cg * 2, 512));
                *(f16*)(rhB + swz_off(row, cg * 2, 256)) = (f16)(rv * hv);
            }
        }
    __syncthreads();

    // GEMM2: hc_pre = p + bh + (r*h) @ Wh_top
    f32x4 acc2[2][2];
#pragma unroll
    for (int rt = 0; rt < 2; rt++)
#pragma unroll
        for (int pr = 0; pr < 2; pr++) {
            int cg = (2 * w + pr) * 16 + lr;
#pragma unroll
            for (int j = 0; j < 4; j++)
                acc2[rt][pr][j] = acc[rt][4 + pr][j] + bh[cg];
        }
#pragma unroll
    for (int ks = 0; ks < 4; ks++) {
        int kk = ks * 32 + lh * 8;
        f16x8 a0 = *(const f16x8*)(rhB + swz_off(lr,      kk * 2, 256));
        f16x8 a1 = *(const f16x8*)(rhB + swz_off(lr + 16, kk * 2, 256));
#pragma unroll
        for (int pr = 0; pr < 2; pr++) {
            f16x8 b = *(const f16x8*)(WhtopF + ((size_t)((w * 2 + pr) * 4 + ks) * 64 + l) * 8);
            acc2[0][pr] = __builtin_amdgcn_mfma_f32_16x16x32_f16(a0, b, acc2[0][pr], 0, 0, 0);
            acc2[1][pr] = __builtin_amdgcn_mfma_f32_16x16x32_f16(a1, b, acc2[1][pr], 0, 0, 0);
        }
    }

    // epilogue2: h_new = (1-z)*hold(za) + z*relu(hc); write h16 + rec hd16; stage into za
#pragma unroll
    for (int rt = 0; rt < 2; rt++)
#pragma unroll
        for (int pr = 0; pr < 2; pr++) {
            int cg = (2 * w + pr) * 16 + lr;
#pragma unroll
            for (int j = 0; j < 4; j++) {
                int row = rt * 16 + lh * 4 + j;
                int gn = n0 + row;
                float hc = fmaxf(acc2[rt][pr][j], 0.0f);
                float z = zreg[rt][pr][j];
                float hold = (float)*(const f16*)(zaB + swz_off(row, cg * 2, 512));
                float hn = (1.0f - z) * hold + z * hc;
                if (gn < NODES) {
                    h16[(size_t)gn * C + cg] = (f16)hn;
                    rec[(size_t)gn * RECS + 32 + cg] = (f16)(hn * dis[gn]);
                }
                *(f16*)(zaB + swz_off(row, cg * 2, 512)) = (f16)hn;
            }
        }
    __syncthreads();

    // GEMM3: A|B16 = h_new @ Wg1F (both outputs permuted)
    f32x4 acc3[2];
#pragma unroll
    for (int rt = 0; rt < 2; rt++)
#pragma unroll
        for (int j = 0; j < 4; j++) acc3[rt][j] = 0.0f;
#pragma unroll
    for (int ks = 0; ks < 4; ks++) {
        int kk = ks * 32 + lh * 8;
        f16x8 a0 = *(const f16x8*)(zaB + swz_off(lr,      kk * 2, 512));
        f16x8 a1 = *(const f16x8*)(zaB + swz_off(lr + 16, kk * 2, 512));
        f16x8 b = *(const f16x8*)(Wg1F + ((size_t)(w * 4 + ks) * 64 + l) * 8);
        acc3[0] = __builtin_amdgcn_mfma_f32_16x16x32_f16(a0, b, acc3[0], 0, 0, 0);
        acc3[1] = __builtin_amdgcn_mfma_f32_16x16x32_f16(a1, b, acc3[1], 0, 0, 0);
    }
    int col3 = w * 16 + lr;
#pragma unroll
    for (int rt = 0; rt < 2; rt++)
#pragma unroll
        for (int j = 0; j < 4; j++) {
            int row = rt * 16 + lh * 4 + j;
            int gn = n0 + row;
            if (gn < NODES) {
                float v = acc3[rt][j];
                if (col3 < 32) A[(size_t)gn * GH + bperm(col3)] = v + bg1[col3];
                else           rec[(size_t)gn * RECS + bperm(col3 - 32)] = (f16)v;
            }
        }
}

// final head via MFMA: f = relu([h0_16|h16]@Wf1+bf1); out = f@Wf2+bf2
__global__ __launch_bounds__(256) void k_final_mfma(
    const f16* __restrict__ h0_16, const f16* __restrict__ h16,
    const f16* __restrict__ Wf1F, const float* __restrict__ bf1,
    const float* __restrict__ Wf2, const float* __restrict__ bf2,
    float* __restrict__ out) {
    __shared__ float fs[32][132];   // aliased during stage/GEMM as f16 za [32][256] swizzled
    char* zaB = (char*)&fs[0][0];
    int tid = threadIdx.x;
    int l = tid & 63, w = tid >> 6;
    int lr = l & 15, lh = l >> 4;
    int n0 = blockIdx.x * 32;

    for (int p = tid; p < 32 * 16; p += 256) {
        int row = p >> 4, seg = p & 15;
        int gn = n0 + row;
        f16x8 v = {};
        if (gn < NODES) v = *(const f16x8*)(h0_16 + (size_t)gn * C + seg * 8);
        *(f16x8*)(zaB + swz_off(row, seg * 16, 512)) = v;
    }
    for (int p = tid; p < 32 * 16; p += 256) {
        int row = p >> 4, seg = p & 15;
        int gn = n0 + row;
        f16x8 v = {};
        if (gn < NODES) v = *(const f16x8*)(h16 + (size_t)gn * C + seg * 8);
        *(f16x8*)(zaB + swz_off(row, 256 + seg * 16, 512)) = v;
    }
    __syncthreads();

    f32x4 acc[2][2];
#pragma unroll
    for (int rt = 0; rt < 2; rt++)
#pragma unroll
        for (int n = 0; n < 2; n++)
#pragma unroll
            for (int j = 0; j < 4; j++) acc[rt][n][j] = 0.0f;
#pragma unroll
    for (int ks = 0; ks < 8; ks++) {
        int kk = ks * 32 + lh * 8;
        f16x8 a0 = *(const f16x8*)(zaB + swz_off(lr,      kk * 2, 512));
        f16x8 a1 = *(const f16x8*)(zaB + swz_off(lr + 16, kk * 2, 512));
#pragma unroll
        for (int ntl = 0; ntl < 2; ntl++) {
            f16x8 b = *(const f16x8*)(Wf1F + ((size_t)((w * 2 + ntl) * 8 + ks) * 64 + l) * 8);
            acc[0][ntl] = __builtin_amdgcn_mfma_f32_16x16x32_f16(a0, b, acc[0][ntl], 0, 0, 0);
            acc[1][ntl] = __builtin_amdgcn_mfma_f32_16x16x32_f16(a1, b, acc[1][ntl], 0, 0, 0);
        }
    }
    __syncthreads();  // za reads done before fs overwrite

#pragma unroll
    for (int rt = 0; rt < 2; rt++)
#pragma unroll
        for (int ntl = 0; ntl < 2; ntl++) {
            int cg = (w * 2 + ntl) * 16 + lr;
#pragma unroll
            for (int j = 0; j < 4; j++) {
                int row = rt * 16 + lh * 4 + j;
                fs[row][cg] = fmaxf(acc[rt][ntl][j] + bf1[cg], 0.0f);
            }
        }
    __syncthreads();

    if (tid < 64) {
        int n = tid >> 1, o = tid & 1;
        int gn = n0 + n;
        if (gn < NODES) {
            float a = bf2[o];
#pragma unroll 16
            for (int c = 0; c < C; c++) a = fmaf(fs[n][c], Wf2[c * 2 + o], a);
            out[(size_t)gn * 2 + o] = a;
        }
    }
}

extern "C" void kernel_launch(void* const* d_in, const int* in_sizes, int n_in,
                              void* d_out, int out_size, void* d_ws, size_t ws_size,
                              hipStream_t stream) {
    const float* x    = (const float*)d_in[0];
    const int*   eidx = (const int*)d_in[1];
    const float* eattr= (const float*)d_in[2];
    const float* Wpre = (const float*)d_in[3];  const float* bpre = (const float*)d_in[4];
    const float* Winit= (const float*)d_in[5];  const float* binit= (const float*)d_in[6];
    const float* Wg1  = (const float*)d_in[7];  const float* bg1  = (const float*)d_in[8];
    const float* Wg2  = (const float*)d_in[9];  const float* bg2  = (const float*)d_in[10];
    const float* Wz   = (const float*)d_in[11]; const float* bz   = (const float*)d_in[12];
    const float* Wr   = (const float*)d_in[13]; const float* br   = (const float*)d_in[14];
    const float* Wh   = (const float*)d_in[15]; const float* bh   = (const float*)d_in[16];
    const float* Wf1  = (const float*)d_in[17]; const float* bf1  = (const float*)d_in[18];
    const float* Wf2  = (const float*)d_in[19]; const float* bf2  = (const float*)d_in[20];
    float* out = (float*)d_out;

    float* ws  = (float*)d_ws;
    float* dis = ws;                               // N (deg during preamble, then rsqrt)
    float* A   = dis + NODES;                      // N*GH f32 (permuted)
    int*   start = (int*)(A + (size_t)NODES * GH);     // N+1
    int*   cursor = start + NODES + 1;                 // N+1
    int*   bsum  = cursor + NODES + 1;                 // SCB
    int*   bscan = bsum + SCB;                         // SCB
    int*   row_sorted = bscan + SCB;                   // ETOT
    float* ea_sorted  = (float*)(row_sorted + ETOT);   // ETOT
    size_t f16_base = (size_t)((ea_sorted + ETOT) - ws);
    f16_base = (f16_base + 3) & ~(size_t)3;            // 16B align
    f16* h0_16  = (f16*)(ws + f16_base);               // N*C f16
    f16* h16    = h0_16 + (size_t)NODES * C;           // N*C f16
    f16* rec    = h16 + (size_t)NODES * C;             // N*RECS f16
    f16* aggr16 = rec + (size_t)NODES * RECS;          // N*C f16
    f16* WcatF  = aggr16 + (size_t)NODES * C;          // 24*8*64*8 f16
    f16* WhtopF = WcatF + 24 * 8 * 64 * 8;
    f16* Wg1F   = WhtopF + 8 * 4 * 64 * 8;
    f16* Wf1F   = Wg1F + 4 * 4 * 64 * 8;
    f16* WpreF  = Wf1F + 8 * 8 * 64 * 8;               // 2*64*8 f16
    f16* WinitF = WpreF + 2 * 64 * 8;                  // 8*64*8 f16
    size_t f16_total = (size_t)NODES * (C + C + RECS + C)
                     + (24 * 8 + 8 * 4 + 4 * 4 + 8 * 8 + 2 + 8) * 64 * 8;
    const size_t REQ = (f16_base + (f16_total + 1) / 2) * sizeof(float);
    if (ws_size < REQ) return;

    hipMemsetAsync(dis, 0, NODES * sizeof(float), stream);
    k_degree<<<(NEDGES + 255) / 256, 256, 0, stream>>>(eidx + NEDGES, dis);
    k_scan1<<<SCB, SCT, 0, stream>>>(dis, bsum);
    k_scan2<<<1, 64, 0, stream>>>(bsum, bscan, start);
    k_scan3<<<SCB, SCT, 0, stream>>>(dis, bscan, start, cursor);   // also writes dis
    k_csr<<<(ETOT + 255) / 256, 256, 0, stream>>>(eidx, eattr, cursor, row_sorted, ea_sorted);
    k_prep_w<<<(19456 + 128 + 512 + 255) / 256, 256, 0, stream>>>(
        Wz, Wr, Wh, Wg1, Wf1, Wpre, Winit, WcatF, WhtopF, Wg1F, Wf1F, WpreF, WinitF);
    k_pre_gate<<<(NODES + 31) / 32, 256, 0, stream>>>(
        x, bpre, binit, dis, WpreF, WinitF, Wg1F, bg1, h0_16, h16, rec, A);

    for (int l = 0; l < LAYERS; l++) {
        k_msg<<<(NODES * 64 + 255) / 256, 256, 0, stream>>>(
            start, row_sorted, ea_sorted, dis, A, rec, Wg1, Wg2, bg2, aggr16);
        k_update_mfma<<<(NODES + 31) / 32, 256, 0, stream>>>(
            h16, aggr16, dis, rec, WcatF, WhtopF, Wg1F, bz, br, bh, bg1, A);
    }
    k_final_mfma<<<(NODES + 31) / 32, 256, 0, stream>>>(h0_16, h16, Wf1F, bf1, Wf2, bf2, out);
}

// Round 14
// 567.783 us; speedup vs baseline: 16.1009x; 1.0217x over previous
//
#include <hip/hip_runtime.h>
#include <math.h>

#define NODES 50000
#define NEDGES 800000
#define ETOT (NEDGES + NODES)
#define FIN 16
#define PRE 32
#define C 128
#define GH 32
#define LAYERS 5
#define RECS 160   // f16 per node record: [B16perm:32 | hd16:128] where hd = dis[n]*h[n]
#define SCB 64     // scan blocks
#define SCT 256    // scan threads/block
#define SCCH ((NODES + SCB*SCT - 1) / (SCB*SCT))   // elems per thread (=4)

typedef _Float16 f16;
typedef f16 f16x8 __attribute__((ext_vector_type(8)));
typedef f16 f16x4 __attribute__((ext_vector_type(4)));
typedef f16 f16x2 __attribute__((ext_vector_type(2)));
typedef float f32x4 __attribute__((ext_vector_type(4)));

__device__ __forceinline__ float sigmoidf_(float x) { return 1.0f / (1.0f + __expf(-x)); }

// XOR-swizzled LDS byte offset: 16B-block index ^= (row&7)  (stride >= 128B)
__device__ __forceinline__ int swz_off(int row, int bytecol, int stride) {
    return row * stride + ((((bytecol) >> 4) ^ (row & 7)) << 4) + (bytecol & 15);
}
// 64B-stride variant: block index ^= (row&3)
__device__ __forceinline__ int ps_off(int row, int bytecol) {
    return row * 64 + ((((bytecol) >> 4) ^ (row & 3)) << 4) + (bytecol & 15);
}

// gate channel c (0..31) -> permuted position, so msg lane k8 reads one vector
__device__ __forceinline__ int bperm(int c) { return 4 * (c & 7) + (c >> 3); }

__global__ void k_degree(const int* __restrict__ col, float* __restrict__ deg) {
    int e = blockIdx.x * blockDim.x + threadIdx.x;
    if (e < NEDGES) atomicAdd(&deg[col[e]], 1.0f);
}

// parallel scan, stage 1: per-block sums of (deg+1)
__global__ __launch_bounds__(SCT) void k_scan1(const float* __restrict__ deg, int* __restrict__ bsum) {
    __shared__ int ws4[SCT / 64];
    int b = blockIdx.x, t = threadIdx.x;
    int lane = t & 63, wv = t >> 6;
    int base = (b * SCT + t) * SCCH;
    int sum = 0;
#pragma unroll
    for (int j = 0; j < SCCH; j++) {
        int i = base + j;
        if (i < NODES) sum += (int)deg[i] + 1;
    }
#pragma unroll
    for (int off = 32; off > 0; off >>= 1) sum += __shfl_xor(sum, off, 64);
    if (lane == 0) ws4[wv] = sum;
    __syncthreads();
    if (t == 0) {
        int tot = 0;
#pragma unroll
        for (int j = 0; j < SCT / 64; j++) tot += ws4[j];
        bsum[b] = tot;
    }
}

// stage 2: exclusive scan of SCB block sums (single wave)
__global__ __launch_bounds__(64) void k_scan2(const int* __restrict__ bsum, int* __restrict__ bscan,
                                              int* __restrict__ start) {
    int t = threadIdx.x;
    int v = (t < SCB) ? bsum[t] : 0;
    int x = v;
#pragma unroll
    for (int off = 1; off < 64; off <<= 1) {
        int tt = __shfl_up(x, off, 64);
        if (t >= off) x += tt;
    }
    if (t < SCB) bscan[t] = x - v;
    if (t == SCB - 1) start[NODES] = x;
}

// stage 3: per-element exclusive prefix -> start/cursor; dis=rsqrt(deg+1), rdis=sqrt(deg+1)
__global__ __launch_bounds__(SCT) void k_scan3(
    float* __restrict__ deg_dis, float* __restrict__ rdis, const int* __restrict__ bscan,
    int* __restrict__ start, int* __restrict__ cursor) {
    __shared__ int woff[SCT / 64];
    int b = blockIdx.x, t = threadIdx.x;
    int lane = t & 63, wv = t >> 6;
    int base = (b * SCT + t) * SCCH;
    int v[SCCH]; int sum = 0;
#pragma unroll
    for (int j = 0; j < SCCH; j++) {
        int i = base + j;
        v[j] = (i < NODES) ? (int)deg_dis[i] + 1 : 0;
        sum += v[j];
    }
    int x = sum;
#pragma unroll
    for (int off = 1; off < 64; off <<= 1) {
        int tt = __shfl_up(x, off, 64);
        if (lane >= off) x += tt;
    }
    int texcl = x - sum;
    if (lane == 63) woff[wv] = x;
    __syncthreads();
    int wbase = 0;
    for (int j = 0; j < wv; j++) wbase += woff[j];
    int run = bscan[b] + wbase + texcl;
#pragma unroll
    for (int j = 0; j < SCCH; j++) {
        int i = base + j;
        if (i < NODES) {
            start[i] = run; cursor[i] = run;
            float fv = (float)v[j];
            deg_dis[i] = rsqrtf(fv);
            rdis[i] = sqrtf(fv);
        }
        run += v[j];
    }
}

// packed CSR scatter: one 8B store per edge
__global__ __launch_bounds__(256) void k_csr(
    const int* __restrict__ eidx, const float* __restrict__ eattr,
    int* __restrict__ cursor, int2* __restrict__ esort) {
    int e = blockIdx.x * blockDim.x + threadIdx.x;
    if (e >= ETOT) return;
    int r, ci; float ea;
    if (e < NEDGES) { r = eidx[e]; ci = eidx[NEDGES + e]; ea = eattr[e]; }
    else            { r = ci = e - NEDGES; ea = 0.0f; }
    int slot = atomicAdd(&cursor[ci], 1);
    esort[slot] = make_int2(r, __float_as_int(ea));
}

// fragment-ordered f16 weight buffers.
// WcatF: K=256, 24 col-tiles [z0,z1,r0,r1,p0,p1] per wave; WhtopF: K=128 -> 128;
// Wg1F: K=128 -> 64 (A|B); Wf1F: K=256 -> 128; WpreF: K=32(pad) -> 32; WinitF: K=32 -> 128
__global__ __launch_bounds__(256) void k_prep_w(
    const float* __restrict__ Wz, const float* __restrict__ Wr, const float* __restrict__ Wh,
    const float* __restrict__ Wg1, const float* __restrict__ Wf1,
    const float* __restrict__ Wpre, const float* __restrict__ Winit,
    f16* __restrict__ WcatF, f16* __restrict__ WhtopF, f16* __restrict__ Wg1F,
    f16* __restrict__ Wf1F, f16* __restrict__ WpreF, f16* __restrict__ WinitF) {
    int t = blockIdx.x * 256 + threadIdx.x;
    int l = t & 63;
    int lr = l & 15, lh = l >> 4;
    if (t < 24 * 8 * 64) {
        int idx = t >> 6; int nt = idx >> 3, ks = idx & 7;
        int wv = nt / 6, ntl = nt % 6;
        int grp = ntl >> 1, pr = ntl & 1;
        int ncol = (2 * wv + pr) * 16 + lr;
        f16x8 v;
#pragma unroll
        for (int j = 0; j < 8; j++) {
            int k = ks * 32 + lh * 8 + j;
            float x;
            if (grp == 0)      x = Wz[k * 128 + ncol];
            else if (grp == 1) x = Wr[k * 128 + ncol];
            else               x = (k >= 128) ? Wh[k * 128 + ncol] : 0.0f;
            v[j] = (f16)x;
        }
        *(f16x8*)(WcatF + (size_t)t * 8) = v;
    } else if (t < 24 * 8 * 64 + 8 * 4 * 64) {
        int t2 = t - 24 * 8 * 64;
        int idx = t2 >> 6; int nt = idx >> 2, ks = idx & 3;
        int n = nt * 16 + lr;
        f16x8 v;
#pragma unroll
        for (int j = 0; j < 8; j++) {
            int k = ks * 32 + lh * 8 + j;
            v[j] = (f16)Wh[k * 128 + n];
        }
        *(f16x8*)(WhtopF + (size_t)t2 * 8) = v;
    } else if (t < 24 * 8 * 64 + 8 * 4 * 64 + 4 * 4 * 64) {
        int t3 = t - (24 * 8 * 64 + 8 * 4 * 64);
        int idx = t3 >> 6; int nt = idx >> 2, ks = idx & 3;
        int cg = nt * 16 + lr;
        f16x8 v;
#pragma unroll
        for (int j = 0; j < 8; j++) {
            int k = ks * 32 + lh * 8 + j;
            v[j] = (f16)((cg < 32) ? Wg1[k * GH + cg] : Wg1[(128 + k) * GH + (cg - 32)]);
        }
        *(f16x8*)(Wg1F + (size_t)t3 * 8) = v;
    } else if (t < 24 * 8 * 64 + 8 * 4 * 64 + 4 * 4 * 64 + 8 * 8 * 64) {
        int t4 = t - (24 * 8 * 64 + 8 * 4 * 64 + 4 * 4 * 64);
        int idx = t4 >> 6; int nt = idx >> 3, ks = idx & 7;
        int n = nt * 16 + lr;
        f16x8 v;
#pragma unroll
        for (int j = 0; j < 8; j++) {
            int k = ks * 32 + lh * 8 + j;
            v[j] = (f16)Wf1[k * 128 + n];
        }
        *(f16x8*)(Wf1F + (size_t)t4 * 8) = v;
    } else if (t < 19456 + 2 * 64) {
        int t5 = t - 19456;
        int nt = t5 >> 6;
        f16x8 v;
#pragma unroll
        for (int j = 0; j < 8; j++) {
            int k = lh * 8 + j;           // K padded 16->32
            v[j] = (k < FIN) ? (f16)Wpre[k * PRE + nt * 16 + lr] : (f16)0.0f;
        }
        *(f16x8*)(WpreF + (size_t)t5 * 8) = v;
    } else if (t < 19456 + 128 + 8 * 64) {
        int t6 = t - 19456 - 128;
        int nt = t6 >> 6;
        f16x8 v;
#pragma unroll
        for (int j = 0; j < 8; j++) {
            int k = lh * 8 + j;
            v[j] = (f16)Winit[k * C + nt * 16 + lr];
        }
        *(f16x8*)(WinitF + (size_t)t6 * 8) = v;
    }
}

// fused preproc + layer-0 gate, all MFMA. 32 nodes/block.
// pre = relu(x@Wpre+bpre); h = relu(pre@Winit+binit) -> h0_16, rec.hd16, za;
// A|B16 = h @ Wg1F (+bg1 on A), permuted.
__global__ __launch_bounds__(256) void k_pre_gate(
    const float* __restrict__ x, const float* __restrict__ bpre, const float* __restrict__ binit,
    const float* __restrict__ dis,
    const f16* __restrict__ WpreF, const f16* __restrict__ WinitF,
    const f16* __restrict__ Wg1F, const float* __restrict__ bg1,
    f16* __restrict__ h0_16, f16* __restrict__ rec,
    float* __restrict__ A) {
    __shared__ f16 ps[32 * 32];     // pre, 64B-stride swizzled
    __shared__ f16 za[32 * 128];    // h, 256B-stride swizzled
    char* psB = (char*)ps;
    char* zaB = (char*)za;
    int tid = threadIdx.x;
    int l = tid & 63, w = tid >> 6;
    int lr = l & 15, lh = l >> 4;
    int n0 = blockIdx.x * 32;
    int rt0 = w >> 1, ct = w & 1;

    // GEMM-A: wave computes tile (rt0, ct) of pre[32][32]; K=16 zero-padded to 32
    f16x8 xa = {};
    {
        int gn = n0 + rt0 * 16 + lr;
        if (gn < NODES && lh < 2) {
            float4 xv0 = *(const float4*)(x + (size_t)gn * FIN + lh * 8);
            float4 xv1 = *(const float4*)(x + (size_t)gn * FIN + lh * 8 + 4);
            xa[0] = (f16)xv0.x; xa[1] = (f16)xv0.y; xa[2] = (f16)xv0.z; xa[3] = (f16)xv0.w;
            xa[4] = (f16)xv1.x; xa[5] = (f16)xv1.y; xa[6] = (f16)xv1.z; xa[7] = (f16)xv1.w;
        }
    }
    f16x8 bA = *(const f16x8*)(WpreF + ((size_t)ct * 64 + l) * 8);
    f32x4 accA; accA[0] = accA[1] = accA[2] = accA[3] = 0.0f;
    accA = __builtin_amdgcn_mfma_f32_16x16x32_f16(xa, bA, accA, 0, 0, 0);
    {
        float bp = bpre[ct * 16 + lr];
#pragma unroll
        for (int j = 0; j < 4; j++) {
            int row = rt0 * 16 + lh * 4 + j;
            float v = fmaxf(accA[j] + bp, 0.0f);
            *(f16*)(psB + ps_off(row, (ct * 16 + lr) * 2)) = (f16)v;
        }
    }
    __syncthreads();

    // GEMM-B: h = relu(pre @ Winit + binit); wave owns col-tiles {2w, 2w+1}
    f16x8 pa0 = *(const f16x8*)(psB + ps_off(lr, lh * 16));
    f16x8 pa1 = *(const f16x8*)(psB + ps_off(lr + 16, lh * 16));
    f32x4 accB[2][2];
#pragma unroll
    for (int rt = 0; rt < 2; rt++)
#pragma unroll
        for (int ntl = 0; ntl < 2; ntl++)
#pragma unroll
            for (int j = 0; j < 4; j++) accB[rt][ntl][j] = 0.0f;
#pragma unroll
    for (int ntl = 0; ntl < 2; ntl++) {
        f16x8 b = *(const f16x8*)(WinitF + ((size_t)((w * 2 + ntl) * 64 + l)) * 8);
        accB[0][ntl] = __builtin_amdgcn_mfma_f32_16x16x32_f16(pa0, b, accB[0][ntl], 0, 0, 0);
        accB[1][ntl] = __builtin_amdgcn_mfma_f32_16x16x32_f16(pa1, b, accB[1][ntl], 0, 0, 0);
    }
#pragma unroll
    for (int rt = 0; rt < 2; rt++)
#pragma unroll
        for (int ntl = 0; ntl < 2; ntl++) {
            int cg = (w * 2 + ntl) * 16 + lr;
            float bi = binit[cg];
#pragma unroll
            for (int j = 0; j < 4; j++) {
                int row = rt * 16 + lh * 4 + j;
                float v = fmaxf(accB[rt][ntl][j] + bi, 0.0f);
                *(f16*)(zaB + swz_off(row, cg * 2, 256)) = (f16)v;
            }
        }
    __syncthreads();

    // coalesced flush of h to h0_16 and rec.hd16
    for (int p = tid; p < 32 * 16; p += 256) {
        int row = p >> 4, seg = p & 15;
        int gn = n0 + row;
        if (gn < NODES) {
            f16x8 v = *(const f16x8*)(zaB + swz_off(row, seg * 16, 256));
            *(f16x8*)(h0_16 + (size_t)gn * C + seg * 8) = v;
            float dn = dis[gn];
            f16x8 od;
#pragma unroll
            for (int j = 0; j < 8; j++) od[j] = (f16)((float)v[j] * dn);
            *(f16x8*)(rec + (size_t)gn * RECS + 32 + seg * 8) = od;
        }
    }

    // GEMM-C: A|B16 = h @ Wg1F
    f32x4 acc3[2];
#pragma unroll
    for (int rt = 0; rt < 2; rt++)
#pragma unroll
        for (int j = 0; j < 4; j++) acc3[rt][j] = 0.0f;
#pragma unroll
    for (int ks = 0; ks < 4; ks++) {
        int kk = ks * 32 + lh * 8;
        f16x8 a0 = *(const f16x8*)(zaB + swz_off(lr,      kk * 2, 256));
        f16x8 a1 = *(const f16x8*)(zaB + swz_off(lr + 16, kk * 2, 256));
        f16x8 b = *(const f16x8*)(Wg1F + ((size_t)(w * 4 + ks) * 64 + l) * 8);
        acc3[0] = __builtin_amdgcn_mfma_f32_16x16x32_f16(a0, b, acc3[0], 0, 0, 0);
        acc3[1] = __builtin_amdgcn_mfma_f32_16x16x32_f16(a1, b, acc3[1], 0, 0, 0);
    }
    int col3 = w * 16 + lr;
#pragma unroll
    for (int rt = 0; rt < 2; rt++)
#pragma unroll
        for (int j = 0; j < 4; j++) {
            int row = rt * 16 + lh * 4 + j;
            int gn = n0 + row;
            if (gn < NODES) {
                float v = acc3[rt][j];
                if (col3 < 32) A[(size_t)gn * GH + bperm(col3)] = v + bg1[col3];
                else           rec[(size_t)gn * RECS + bperm(col3 - 32)] = (f16)v;
            }
        }
}

// fused gate+aggregate: wave per node, EIGHTH-WAVE (8 lanes) per edge, 1-deep prefetch.
__global__ __launch_bounds__(256) void k_msg(
    const int* __restrict__ start, const int2* __restrict__ esort,
    const float* __restrict__ dis,
    const float* __restrict__ A, const f16* __restrict__ rec,
    const float* __restrict__ Wg1, const float* __restrict__ Wg2, const float* __restrict__ bg2,
    f16* __restrict__ aggr16) {
    int wid = (blockIdx.x * blockDim.x + threadIdx.x) >> 6;
    int lane = threadIdx.x & 63;
    if (wid >= NODES) return;
    int k8 = lane & 7;
    int q = lane >> 3;
    int s0 = start[wid], s1 = start[wid + 1];
    float4 a4 = *(const float4*)(A + (size_t)wid * GH + k8 * 4);   // channels {k8,k8+8,k8+16,k8+24}
    const float* wg1e = Wg1 + 2 * C * GH;
    float wea0 = wg1e[k8], wea1 = wg1e[k8 + 8], wea2 = wg1e[k8 + 16], wea3 = wg1e[k8 + 24];
    float w20 = Wg2[k8], w21 = Wg2[k8 + 8], w22 = Wg2[k8 + 16], w23 = Wg2[k8 + 24];
    float b2 = bg2[0];
    float dci = dis[wid];
    float acc[16];
#pragma unroll
    for (int j = 0; j < 16; j++) acc[j] = 0.0f;

    int s = s0 + q;
    f16x8 ha0 = {}, hb0 = {};
    f16x4 bb0 = {};
    float ea0 = 0.0f;
    if (s < s1) {
        int2 e0 = esort[s];
        ea0 = __int_as_float(e0.y);
        const f16* rr = rec + (size_t)e0.x * RECS;
        bb0 = *(const f16x4*)(rr + k8 * 4);
        ha0 = *(const f16x8*)(rr + 32 + k8 * 16);
        hb0 = *(const f16x8*)(rr + 32 + k8 * 16 + 8);
    }
    while (s < s1) {
        int s2 = s + 8;
        f16x8 ha1 = {}, hb1 = {};
        f16x4 bb1 = {};
        float ea1 = 0.0f;
        if (s2 < s1) {                       // prefetch next edge's record
            int2 e1 = esort[s2];
            ea1 = __int_as_float(e1.y);
            const f16* rr = rec + (size_t)e1.x * RECS;
            bb1 = *(const f16x4*)(rr + k8 * 4);
            ha1 = *(const f16x8*)(rr + 32 + k8 * 16);
            hb1 = *(const f16x8*)(rr + 32 + k8 * 16 + 8);
        }
        float t0 = fmaxf(a4.x + (float)bb0[0] + ea0 * wea0, 0.0f);
        float t1 = fmaxf(a4.y + (float)bb0[1] + ea0 * wea1, 0.0f);
        float t2 = fmaxf(a4.z + (float)bb0[2] + ea0 * wea2, 0.0f);
        float t3 = fmaxf(a4.w + (float)bb0[3] + ea0 * wea3, 0.0f);
        float p = t0 * w20;
        p = fmaf(t1, w21, p);
        p = fmaf(t2, w22, p);
        p = fmaf(t3, w23, p);
        p += __shfl_xor(p, 4, 8);
        p += __shfl_xor(p, 2, 8);
        p += __shfl_xor(p, 1, 8);
        float coef = sigmoidf_(p + b2);
#pragma unroll
        for (int j = 0; j < 8; j++) {
            acc[j]     = fmaf(coef, (float)ha0[j], acc[j]);
            acc[8 + j] = fmaf(coef, (float)hb0[j], acc[8 + j]);
        }
        ha0 = ha1; hb0 = hb1; bb0 = bb1; ea0 = ea1;
        s = s2;
    }
#pragma unroll
    for (int j = 0; j < 16; j++) {
        acc[j] += __shfl_xor(acc[j], 8, 64);
        acc[j] += __shfl_xor(acc[j], 16, 64);
        acc[j] += __shfl_xor(acc[j], 32, 64);
    }
    if (lane < 8) {
        f16x8 o1, o2;
#pragma unroll
        for (int j = 0; j < 8; j++) { o1[j] = (f16)(acc[j] * dci); o2[j] = (f16)(acc[8 + j] * dci); }
        *(f16x8*)(aggr16 + (size_t)wid * C + k8 * 16) = o1;
        *(f16x8*)(aggr16 + (size_t)wid * C + k8 * 16 + 8) = o2;
    }
}

// GRU update via MFMA; per-wave column-tile ownership keeps z,p in registers.
// Reads rec.hd (h = hd*rdis) + aggr16; writes rec = {B16perm|hd16}, A f32 (permuted).
__global__ __launch_bounds__(256) void k_update_mfma(
    f16* __restrict__ rec, const f16* __restrict__ aggr16,
    const float* __restrict__ dis, const float* __restrict__ rdis,
    const f16* __restrict__ WcatF, const f16* __restrict__ WhtopF, const f16* __restrict__ Wg1F,
    const float* __restrict__ bz, const float* __restrict__ br, const float* __restrict__ bh,
    const float* __restrict__ bg1,
    float* __restrict__ A) {
    __shared__ f16 za[32 * 256];    // swizzled, row stride 512B; reused for h_new staging
    __shared__ f16 rhbuf[32 * 128]; // swizzled, row stride 256B
    char* zaB = (char*)za;
    char* rhB = (char*)rhbuf;
    int tid = threadIdx.x;
    int l = tid & 63, w = tid >> 6;
    int lr = l & 15, lh = l >> 4;
    int n0 = blockIdx.x * 32;

    // stage za = [h (=hd*rdis) | aggr16]
    for (int p = tid; p < 32 * 16; p += 256) {
        int row = p >> 4, seg = p & 15;
        int gn = n0 + row;
        f16x8 v = {};
        if (gn < NODES) {
            v = *(const f16x8*)(rec + (size_t)gn * RECS + 32 + seg * 8);
            float rd = rdis[gn];
#pragma unroll
            for (int j = 0; j < 8; j++) v[j] = (f16)((float)v[j] * rd);
        }
        *(f16x8*)(zaB + swz_off(row, seg * 16, 512)) = v;
    }
    for (int p = tid; p < 32 * 16; p += 256) {
        int row = p >> 4, seg = p & 15;
        int gn = n0 + row;
        f16x8 v = {};
        if (gn < NODES) v = *(const f16x8*)(aggr16 + (size_t)gn * C + seg * 8);
        *(f16x8*)(zaB + swz_off(row, 256 + seg * 16, 512)) = v;
    }
    __syncthreads();

    // GEMM1: tiles [z0,z1,r0,r1,p0,p1] per wave
    f32x4 acc[2][6];
#pragma unroll
    for (int rt = 0; rt < 2; rt++)
#pragma unroll
        for (int n = 0; n < 6; n++)
#pragma unroll
            for (int j = 0; j < 4; j++) acc[rt][n][j] = 0.0f;
#pragma unroll
    for (int ks = 0; ks < 8; ks++) {
        int kk = ks * 32 + lh * 8;
        f16x8 a0 = *(const f16x8*)(zaB + swz_off(lr,      kk * 2, 512));
        f16x8 a1 = *(const f16x8*)(zaB + swz_off(lr + 16, kk * 2, 512));
#pragma unroll
        for (int ntl = 0; ntl < 6; ntl++) {
            f16x8 b = *(const f16x8*)(WcatF + ((size_t)((w * 6 + ntl) * 8 + ks) * 64 + l) * 8);
            acc[0][ntl] = __builtin_amdgcn_mfma_f32_16x16x32_f16(a0, b, acc[0][ntl], 0, 0, 0);
            acc[1][ntl] = __builtin_amdgcn_mfma_f32_16x16x32_f16(a1, b, acc[1][ntl], 0, 0, 0);
        }
    }

    // epilogue1: z->reg (sigmoid), r*h -> rhbuf (h from za), p stays in acc[rt][4/5]
    float zreg[2][2][4];
#pragma unroll
    for (int rt = 0; rt < 2; rt++)
#pragma unroll
        for (int pr = 0; pr < 2; pr++) {
            int cg = (2 * w + pr) * 16 + lr;
#pragma unroll
            for (int j = 0; j < 4; j++) {
                int row = rt * 16 + lh * 4 + j;
                zreg[rt][pr][j] = sigmoidf_(acc[rt][pr][j] + bz[cg]);
                float rv = sigmoidf_(acc[rt][2 + pr][j] + br[cg]);
                float hv = (float)*(const f16*)(zaB + swz_off(row, cg * 2, 512));
                *(f16*)(rhB + swz_off(row, cg * 2, 256)) = (f16)(rv * hv);
            }
        }
    __syncthreads();

    // GEMM2: hc_pre = p + bh + (r*h) @ Wh_top
    f32x4 acc2[2][2];
#pragma unroll
    for (int rt = 0; rt < 2; rt++)
#pragma unroll
        for (int pr = 0; pr < 2; pr++) {
            int cg = (2 * w + pr) * 16 + lr;
#pragma unroll
            for (int j = 0; j < 4; j++)
                acc2[rt][pr][j] = acc[rt][4 + pr][j] + bh[cg];
        }
#pragma unroll
    for (int ks = 0; ks < 4; ks++) {
        int kk = ks * 32 + lh * 8;
        f16x8 a0 = *(const f16x8*)(rhB + swz_off(lr,      kk * 2, 256));
        f16x8 a1 = *(const f16x8*)(rhB + swz_off(lr + 16, kk * 2, 256));
#pragma unroll
        for (int pr = 0; pr < 2; pr++) {
            f16x8 b = *(const f16x8*)(WhtopF + ((size_t)((w * 2 + pr) * 4 + ks) * 64 + l) * 8);
            acc2[0][pr] = __builtin_amdgcn_mfma_f32_16x16x32_f16(a0, b, acc2[0][pr], 0, 0, 0);
            acc2[1][pr] = __builtin_amdgcn_mfma_f32_16x16x32_f16(a1, b, acc2[1][pr], 0, 0, 0);
        }
    }

    // epilogue2: h_new = (1-z)*hold(za) + z*relu(hc); write rec hd16; stage h_new into za
#pragma unroll
    for (int rt = 0; rt < 2; rt++)
#pragma unroll
        for (int pr = 0; pr < 2; pr++) {
            int cg = (2 * w + pr) * 16 + lr;
#pragma unroll
            for (int j = 0; j < 4; j++) {
                int row = rt * 16 + lh * 4 + j;
                int gn = n0 + row;
                float hc = fmaxf(acc2[rt][pr][j], 0.0f);
                float z = zreg[rt][pr][j];
                float hold = (float)*(const f16*)(zaB + swz_off(row, cg * 2, 512));
                float hn = (1.0f - z) * hold + z * hc;
                if (gn < NODES) {
                    rec[(size_t)gn * RECS + 32 + cg] = (f16)(hn * dis[gn]);
                }
                *(f16*)(zaB + swz_off(row, cg * 2, 512)) = (f16)hn;
            }
        }
    __syncthreads();

    // GEMM3: A|B16 = h_new @ Wg1F (both outputs permuted)
    f32x4 acc3[2];
#pragma unroll
    for (int rt = 0; rt < 2; rt++)
#pragma unroll
        for (int j = 0; j < 4; j++) acc3[rt][j] = 0.0f;
#pragma unroll
    for (int ks = 0; ks < 4; ks++) {
        int kk = ks * 32 + lh * 8;
        f16x8 a0 = *(const f16x8*)(zaB + swz_off(lr,      kk * 2, 512));
        f16x8 a1 = *(const f16x8*)(zaB + swz_off(lr + 16, kk * 2, 512));
        f16x8 b = *(const f16x8*)(Wg1F + ((size_t)(w * 4 + ks) * 64 + l) * 8);
        acc3[0] = __builtin_amdgcn_mfma_f32_16x16x32_f16(a0, b, acc3[0], 0, 0, 0);
        acc3[1] = __builtin_amdgcn_mfma_f32_16x16x32_f16(a1, b, acc3[1], 0, 0, 0);
    }
    int col3 = w * 16 + lr;
#pragma unroll
    for (int rt = 0; rt < 2; rt++)
#pragma unroll
        for (int j = 0; j < 4; j++) {
            int row = rt * 16 + lh * 4 + j;
            int gn = n0 + row;
            if (gn < NODES) {
                float v = acc3[rt][j];
                if (col3 < 32) A[(size_t)gn * GH + bperm(col3)] = v + bg1[col3];
                else           rec[(size_t)gn * RECS + bperm(col3 - 32)] = (f16)v;
            }
        }
}

// final head via MFMA: f = relu([h0_16 | h(=hd*rdis)]@Wf1+bf1); out = f@Wf2+bf2
__global__ __launch_bounds__(256) void k_final_mfma(
    const f16* __restrict__ h0_16, const f16* __restrict__ rec, const float* __restrict__ rdis,
    const f16* __restrict__ Wf1F, const float* __restrict__ bf1,
    const float* __restrict__ Wf2, const float* __restrict__ bf2,
    float* __restrict__ out) {
    __shared__ float fs[32][132];   // aliased during stage/GEMM as f16 za [32][256] swizzled
    char* zaB = (char*)&fs[0][0];
    int tid = threadIdx.x;
    int l = tid & 63, w = tid >> 6;
    int lr = l & 15, lh = l >> 4;
    int n0 = blockIdx.x * 32;

    for (int p = tid; p < 32 * 16; p += 256) {
        int row = p >> 4, seg = p & 15;
        int gn = n0 + row;
        f16x8 v = {};
        if (gn < NODES) v = *(const f16x8*)(h0_16 + (size_t)gn * C + seg * 8);
        *(f16x8*)(zaB + swz_off(row, seg * 16, 512)) = v;
    }
    for (int p = tid; p < 32 * 16; p += 256) {
        int row = p >> 4, seg = p & 15;
        int gn = n0 + row;
        f16x8 v = {};
        if (gn < NODES) {
            v = *(const f16x8*)(rec + (size_t)gn * RECS + 32 + seg * 8);
            float rd = rdis[gn];
#pragma unroll
            for (int j = 0; j < 8; j++) v[j] = (f16)((float)v[j] * rd);
        }
        *(f16x8*)(zaB + swz_off(row, 256 + seg * 16, 512)) = v;
    }
    __syncthreads();

    f32x4 acc[2][2];
#pragma unroll
    for (int rt = 0; rt < 2; rt++)
#pragma unroll
        for (int n = 0; n < 2; n++)
#pragma unroll
            for (int j = 0; j < 4; j++) acc[rt][n][j] = 0.0f;
#pragma unroll
    for (int ks = 0; ks < 8; ks++) {
        int kk = ks * 32 + lh * 8;
        f16x8 a0 = *(const f16x8*)(zaB + swz_off(lr,      kk * 2, 512));
        f16x8 a1 = *(const f16x8*)(zaB + swz_off(lr + 16, kk * 2, 512));
#pragma unroll
        for (int ntl = 0; ntl < 2; ntl++) {
            f16x8 b = *(const f16x8*)(Wf1F + ((size_t)((w * 2 + ntl) * 8 + ks) * 64 + l) * 8);
            acc[0][ntl] = __builtin_amdgcn_mfma_f32_16x16x32_f16(a0, b, acc[0][ntl], 0, 0, 0);
            acc[1][ntl] = __builtin_amdgcn_mfma_f32_16x16x32_f16(a1, b, acc[1][ntl], 0, 0, 0);
        }
    }
    __syncthreads();  // za reads done before fs overwrite

#pragma unroll
    for (int rt = 0; rt < 2; rt++)
#pragma unroll
        for (int ntl = 0; ntl < 2; ntl++) {
            int cg = (w * 2 + ntl) * 16 + lr;
#pragma unroll
            for (int j = 0; j < 4; j++) {
                int row = rt * 16 + lh * 4 + j;
                fs[row][cg] = fmaxf(acc[rt][ntl][j] + bf1[cg], 0.0f);
            }
        }
    __syncthreads();

    if (tid < 64) {
        int n = tid >> 1, o = tid & 1;
        int gn = n0 + n;
        if (gn < NODES) {
            float a = bf2[o];
#pragma unroll 16
            for (int c = 0; c < C; c++) a = fmaf(fs[n][c], Wf2[c * 2 + o], a);
            out[(size_t)gn * 2 + o] = a;
        }
    }
}

extern "C" void kernel_launch(void* const* d_in, const int* in_sizes, int n_in,
                              void* d_out, int out_size, void* d_ws, size_t ws_size,
                              hipStream_t stream) {
    const float* x    = (const float*)d_in[0];
    const int*   eidx = (const int*)d_in[1];
    const float* eattr= (const float*)d_in[2];
    const float* Wpre = (const float*)d_in[3];  const float* bpre = (const float*)d_in[4];
    const float* Winit= (const float*)d_in[5];  const float* binit= (const float*)d_in[6];
    const float* Wg1  = (const float*)d_in[7];  const float* bg1  = (const float*)d_in[8];
    const float* Wg2  = (const float*)d_in[9];  const float* bg2  = (const float*)d_in[10];
    const float* Wz   = (const float*)d_in[11]; const float* bz   = (const float*)d_in[12];
    const float* Wr   = (const float*)d_in[13]; const float* br   = (const float*)d_in[14];
    const float* Wh   = (const float*)d_in[15]; const float* bh   = (const float*)d_in[16];
    const float* Wf1  = (const float*)d_in[17]; const float* bf1  = (const float*)d_in[18];
    const float* Wf2  = (const float*)d_in[19]; const float* bf2  = (const float*)d_in[20];
    float* out = (float*)d_out;

    float* ws  = (float*)d_ws;
    float* dis = ws;                               // N (deg during preamble, then rsqrt)
    float* rdis= dis + NODES;                      // N (sqrt(deg+1))
    float* A   = rdis + NODES;                     // N*GH f32 (permuted)
    int*   start = (int*)(A + (size_t)NODES * GH);     // N+1
    int*   cursor = start + NODES + 1;                 // N+1
    int*   bsum  = cursor + NODES + 1;                 // SCB
    int*   bscan = bsum + SCB;                         // SCB
    int2*  esort = (int2*)(bscan + SCB);               // ETOT int2 (8B each)
    size_t f16_base = (size_t)((int*)(esort + ETOT) - (int*)ws);
    f16_base = (f16_base + 3) & ~(size_t)3;            // 16B align
    f16* h0_16  = (f16*)(ws + f16_base);               // N*C f16
    f16* rec    = h0_16 + (size_t)NODES * C;           // N*RECS f16
    f16* aggr16 = rec + (size_t)NODES * RECS;          // N*C f16
    f16* WcatF  = aggr16 + (size_t)NODES * C;          // 24*8*64*8 f16
    f16* WhtopF = WcatF + 24 * 8 * 64 * 8;
    f16* Wg1F   = WhtopF + 8 * 4 * 64 * 8;
    f16* Wf1F   = Wg1F + 4 * 4 * 64 * 8;
    f16* WpreF  = Wf1F + 8 * 8 * 64 * 8;               // 2*64*8 f16
    f16* WinitF = WpreF + 2 * 64 * 8;                  // 8*64*8 f16
    size_t f16_total = (size_t)NODES * (C + RECS + C)
                     + (24 * 8 + 8 * 4 + 4 * 4 + 8 * 8 + 2 + 8) * 64 * 8;
    const size_t REQ = (f16_base + (f16_total + 1) / 2) * sizeof(float);
    if (ws_size < REQ) return;

    hipMemsetAsync(dis, 0, NODES * sizeof(float), stream);
    k_degree<<<(NEDGES + 255) / 256, 256, 0, stream>>>(eidx + NEDGES, dis);
    k_scan1<<<SCB, SCT, 0, stream>>>(dis, bsum);
    k_scan2<<<1, 64, 0, stream>>>(bsum, bscan, start);
    k_scan3<<<SCB, SCT, 0, stream>>>(dis, rdis, bscan, start, cursor);   // writes dis + rdis
    k_csr<<<(ETOT + 255) / 256, 256, 0, stream>>>(eidx, eattr, cursor, esort);
    k_prep_w<<<(19456 + 128 + 512 + 255) / 256, 256, 0, stream>>>(
        Wz, Wr, Wh, Wg1, Wf1, Wpre, Winit, WcatF, WhtopF, Wg1F, Wf1F, WpreF, WinitF);
    k_pre_gate<<<(NODES + 31) / 32, 256, 0, stream>>>(
        x, bpre, binit, dis, WpreF, WinitF, Wg1F, bg1, h0_16, rec, A);

    for (int l = 0; l < LAYERS; l++) {
        k_msg<<<(NODES * 64 + 255) / 256, 256, 0, stream>>>(
            start, esort, dis, A, rec, Wg1, Wg2, bg2, aggr16);
        k_update_mfma<<<(NODES + 31) / 32, 256, 0, stream>>>(
            rec, aggr16, dis, rdis, WcatF, WhtopF, Wg1F, bz, br, bh, bg1, A);
    }
    k_final_mfma<<<(NODES + 31) / 32, 256, 0, stream>>>(h0_16, rec, rdis, Wf1F, bf1, Wf2, bf2, out);
}